// Round 2
// baseline (5458.002 us; speedup 1.0000x reference)
//
#include <hip/hip_runtime.h>
#include <math.h>

#define D_MODEL 768
#define D_INNER 1536
#define D_STATE 16
#define DCONV 4
#define DT_RANK 48
#define BATCH 8
#define SEQ 2048
#define NROWS (BATCH * SEQ)          // 16384
#define NXZ (2 * D_INNER)            // 3072
#define NDBC (DT_RANK + 2 * D_STATE) // 80

// bf16 <-> fp32 helpers (bit ops; storage type = unsigned short)
__device__ __forceinline__ float bf2f(unsigned short u) {
    return __uint_as_float(((unsigned int)u) << 16);
}
__device__ __forceinline__ unsigned short f2bf(float f) {
    unsigned int x = __float_as_uint(f);
    return (unsigned short)((x + 0x7fffu + ((x >> 16) & 1u)) >> 16);
}

// ---------------------------------------------------------------------------
// fp32-accumulate GEMM: C(M x N) = act(A(M x K) @ W(N x K)^T [+ bias]) [+ C]
// A: fp32 or bf16 (TA_BF). C: fp32 or bf16 (TC_BF). W,bias: fp32.
// ACT: 0 none, 1 softplus(x+bias). ACC: C += result (fp32 C only).
// 64x64 tile, 256 threads, 4x4 per thread, LDS staged transposed.
// ---------------------------------------------------------------------------
template <int TA_BF, int ACT, int ACC, int TC_BF>
__global__ __launch_bounds__(256) void gemm_nt(
    const void* __restrict__ Av, int lda,
    const float* __restrict__ W, int ldw,
    const float* __restrict__ bias,
    void* __restrict__ Cv, int ldc,
    int M, int N, int K)
{
    __shared__ float As[16][68];
    __shared__ float Ws[16][68];
    const int tid = threadIdx.x;
    const int tx = tid & 15;
    const int ty = tid >> 4;
    const int tm0 = blockIdx.y * 64;
    const int tn0 = blockIdx.x * 64;
    const int r  = tid >> 2;
    const int kq = tid & 3;

    float acc[4][4];
#pragma unroll
    for (int i = 0; i < 4; ++i)
#pragma unroll
        for (int j = 0; j < 4; ++j) acc[i][j] = 0.f;

    for (int k0 = 0; k0 < K; k0 += 16) {
        float4 av = make_float4(0.f, 0.f, 0.f, 0.f);
        if (tm0 + r < M) {
            if (TA_BF) {
                const unsigned short* A = (const unsigned short*)Av;
                ushort4 t = *(const ushort4*)&A[(size_t)(tm0 + r) * lda + k0 + kq * 4];
                av = make_float4(bf2f(t.x), bf2f(t.y), bf2f(t.z), bf2f(t.w));
            } else {
                const float* A = (const float*)Av;
                av = *(const float4*)&A[(size_t)(tm0 + r) * lda + k0 + kq * 4];
            }
        }
        As[kq * 4 + 0][r] = av.x;
        As[kq * 4 + 1][r] = av.y;
        As[kq * 4 + 2][r] = av.z;
        As[kq * 4 + 3][r] = av.w;

        float4 wv = make_float4(0.f, 0.f, 0.f, 0.f);
        if (tn0 + r < N)
            wv = *(const float4*)&W[(size_t)(tn0 + r) * ldw + k0 + kq * 4];
        Ws[kq * 4 + 0][r] = wv.x;
        Ws[kq * 4 + 1][r] = wv.y;
        Ws[kq * 4 + 2][r] = wv.z;
        Ws[kq * 4 + 3][r] = wv.w;

        __syncthreads();
#pragma unroll
        for (int kk = 0; kk < 16; ++kk) {
            const float4 a = *(const float4*)&As[kk][ty * 4];
            const float4 b = *(const float4*)&Ws[kk][tx * 4];
            acc[0][0] += a.x * b.x; acc[0][1] += a.x * b.y; acc[0][2] += a.x * b.z; acc[0][3] += a.x * b.w;
            acc[1][0] += a.y * b.x; acc[1][1] += a.y * b.y; acc[1][2] += a.y * b.z; acc[1][3] += a.y * b.w;
            acc[2][0] += a.z * b.x; acc[2][1] += a.z * b.y; acc[2][2] += a.z * b.z; acc[2][3] += a.z * b.w;
            acc[3][0] += a.w * b.x; acc[3][1] += a.w * b.y; acc[3][2] += a.w * b.z; acc[3][3] += a.w * b.w;
        }
        __syncthreads();
    }

#pragma unroll
    for (int i = 0; i < 4; ++i) {
        const int m = tm0 + ty * 4 + i;
        if (m >= M) continue;
#pragma unroll
        for (int j = 0; j < 4; ++j) {
            const int n = tn0 + tx * 4 + j;
            if (n >= N) continue;
            float v = acc[i][j];
            if (ACT == 1) {
                v += bias[n];
                v = (v > 20.f) ? v : log1pf(expf(v));
            }
            const size_t idx = (size_t)m * ldc + n;
            if (TC_BF) {
                ((unsigned short*)Cv)[idx] = f2bf(v);
            } else {
                float* C = (float*)Cv;
                if (ACC) v += C[idx];
                C[idx] = v;
            }
        }
    }
}

// ---------------------------------------------------------------------------
// Causal depthwise conv1d + SiLU on bf16. dir=0: taps l-j; dir=1: taps l+j
// (time-reversed mamba expressed in original order); weight w[3-j] both ways.
// ---------------------------------------------------------------------------
__global__ __launch_bounds__(256) void conv_silu(
    const unsigned short* __restrict__ xz, const float* __restrict__ conv_w,
    const float* __restrict__ conv_b, unsigned short* __restrict__ uc, int dir)
{
    const int idx = blockIdx.x * 256 + threadIdx.x;
    if (idx >= NROWS * D_INNER) return;
    const int d = idx % D_INNER;
    const int row = idx / D_INNER;
    const int l = row % SEQ;

    float acc = conv_b[d];
#pragma unroll
    for (int j = 0; j < 4; ++j) {
        const int ll = dir ? (l + j) : (l - j);
        if (ll >= 0 && ll < SEQ)
            acc += bf2f(xz[(size_t)(row - l + ll) * NXZ + d]) * conv_w[d * 4 + (3 - j)];
    }
    uc[idx] = f2bf(acc / (1.f + expf(-acc)));
}

// ---------------------------------------------------------------------------
// Selective scan. 16 lanes per (b,d) channel, one state n per lane.
// dt lives overlaid in xz u-half (bf16); output y*silu(z) overwrites it
// (read-before-write per element; prefetch only reads future rows).
// ---------------------------------------------------------------------------
struct SBatch {
    float dtv[8], uv[8], Bv[8], Cv[8], zv[8];
};

__device__ __forceinline__ void scan_load(
    SBatch& s, int t0, int dir, size_t base, int d, int n,
    const unsigned short* __restrict__ uc, const float* __restrict__ dtBC,
    const unsigned short* __restrict__ xz)
{
#pragma unroll
    for (int j = 0; j < 8; ++j) {
        const int t = t0 + j;
        const int l = dir ? (SEQ - 1 - t) : t;
        const size_t row = base + l;
        s.dtv[j] = bf2f(xz[row * NXZ + d]);               // dt overlay
        s.uv[j]  = bf2f(uc[row * D_INNER + d]);
        s.Bv[j]  = dtBC[row * NDBC + DT_RANK + n];
        s.Cv[j]  = dtBC[row * NDBC + DT_RANK + D_STATE + n];
        s.zv[j]  = bf2f(xz[row * NXZ + D_INNER + d]);
    }
}

__device__ __forceinline__ void scan_compute(
    const SBatch& s, int t0, int dir, size_t base, int d, int n,
    float& h, float A, float Dv, unsigned short* __restrict__ xz)
{
#pragma unroll
    for (int j = 0; j < 8; ++j) {
        const float dtv = s.dtv[j];
        h = expf(dtv * A) * h + dtv * s.uv[j] * s.Bv[j];
        float p = h * s.Cv[j];
        p += __shfl_xor(p, 1, 16);
        p += __shfl_xor(p, 2, 16);
        p += __shfl_xor(p, 4, 16);
        p += __shfl_xor(p, 8, 16);
        if (n == 0) {
            const int t = t0 + j;
            const int l = dir ? (SEQ - 1 - t) : t;
            const size_t row = base + l;
            const float y = p + s.uv[j] * Dv;
            const float zv = s.zv[j];
            const float sz = zv / (1.f + expf(-zv));
            xz[row * NXZ + d] = f2bf(y * sz);
        }
    }
}

__global__ __launch_bounds__(256) void scan_kernel(
    const float* __restrict__ dtBC, const unsigned short* __restrict__ uc,
    const float* __restrict__ A_log, const float* __restrict__ D_skip,
    unsigned short* __restrict__ xz, int dir)
{
    const int tid = threadIdx.x;
    const int n = tid & 15;
    const int g = tid >> 4;
    const int ch = blockIdx.x * 16 + g;   // 0 .. BATCH*D_INNER-1
    const int b = ch / D_INNER;
    const int d = ch % D_INNER;

    const float A  = -expf(A_log[d * D_STATE + n]);
    const float Dv = D_skip[d];
    const size_t base = (size_t)b * SEQ;
    float h = 0.f;

    SBatch sa, sb;
    scan_load(sa, 0, dir, base, d, n, uc, dtBC, xz);
    for (int t0 = 0; t0 < SEQ; t0 += 16) {
        scan_load(sb, t0 + 8, dir, base, d, n, uc, dtBC, xz);
        scan_compute(sa, t0, dir, base, d, n, h, A, Dv, xz);
        if (t0 + 16 < SEQ)
            scan_load(sa, t0 + 16, dir, base, d, n, uc, dtBC, xz);
        scan_compute(sb, t0 + 8, dir, base, d, n, h, A, Dv, xz);
    }
}

// ---------------------------------------------------------------------------
// In-place: out = LN(out + x) * g + b   (out already holds out_f + out_b)
// ---------------------------------------------------------------------------
__global__ __launch_bounds__(256) void fuse_ln(
    float* __restrict__ out, const float* __restrict__ x,
    const float* __restrict__ g, const float* __restrict__ bta)
{
    const int row = blockIdx.x;
    const size_t base = (size_t)row * D_MODEL;
    float vals[3];
    float s = 0.f, s2 = 0.f;
#pragma unroll
    for (int i = 0; i < 3; ++i) {
        const int c = threadIdx.x + i * 256;
        const float v = out[base + c] + x[base + c];
        vals[i] = v;
        s += v;
        s2 += v * v;
    }
#pragma unroll
    for (int o = 32; o >= 1; o >>= 1) {
        s  += __shfl_xor(s, o, 64);
        s2 += __shfl_xor(s2, o, 64);
    }
    __shared__ float ls[4], ls2[4];
    const int wid = threadIdx.x >> 6;
    if ((threadIdx.x & 63) == 0) { ls[wid] = s; ls2[wid] = s2; }
    __syncthreads();
    s  = ls[0] + ls[1] + ls[2] + ls[3];
    s2 = ls2[0] + ls2[1] + ls2[2] + ls2[3];
    const float mu  = s * (1.f / D_MODEL);
    const float var = s2 * (1.f / D_MODEL) - mu * mu;
    const float inv = 1.f / sqrtf(var + 1e-12f);
#pragma unroll
    for (int i = 0; i < 3; ++i) {
        const int c = threadIdx.x + i * 256;
        out[base + c] = (vals[i] - mu) * inv * g[c] + bta[c];
    }
}

// ---------------------------------------------------------------------------
extern "C" void kernel_launch(void* const* d_in, const int* in_sizes, int n_in,
                              void* d_out, int out_size, void* d_ws, size_t ws_size,
                              hipStream_t stream)
{
    const float* x = (const float*)d_in[0];
    const float* ln_g = (const float*)d_in[19];
    const float* ln_b = (const float*)d_in[20];

    // workspace layout (149 MB total):
    //   dtBC fp32  NROWS*NDBC           =  5.0 MB
    //   xz   bf16  NROWS*NXZ            = 96.0 MB  (u-half reused for dt, then y*silu(z))
    //   uc   bf16  NROWS*D_INNER        = 48.0 MB
    float* dtBC = (float*)d_ws;
    unsigned short* xz = (unsigned short*)(dtBC + (size_t)NROWS * NDBC);
    unsigned short* uc = xz + (size_t)NROWS * NXZ;
    const size_t needed = (size_t)NROWS * NDBC * 4
                        + (size_t)NROWS * NXZ * 2
                        + (size_t)NROWS * D_INNER * 2;
    if (ws_size < needed) return;  // fail absmax cleanly instead of faulting

    float* outp = (float*)d_out;   // fp32 accumulator for out_f + out_b

    for (int dir = 0; dir < 2; ++dir) {
        const float* in_w    = (const float*)d_in[1 + dir * 9 + 0];
        const float* conv_w  = (const float*)d_in[1 + dir * 9 + 1];
        const float* conv_b  = (const float*)d_in[1 + dir * 9 + 2];
        const float* xproj_w = (const float*)d_in[1 + dir * 9 + 3];
        const float* dt_w    = (const float*)d_in[1 + dir * 9 + 4];
        const float* dt_b    = (const float*)d_in[1 + dir * 9 + 5];
        const float* A_log   = (const float*)d_in[1 + dir * 9 + 6];
        const float* D_skip  = (const float*)d_in[1 + dir * 9 + 7];
        const float* out_w   = (const float*)d_in[1 + dir * 9 + 8];

        // xz = x @ in_w^T      (16384 x 3072, K=768)  fp32 A -> bf16 C
        gemm_nt<0, 0, 0, 1><<<dim3(NXZ / 64, NROWS / 64), 256, 0, stream>>>(
            x, D_MODEL, in_w, D_MODEL, nullptr, xz, NXZ, NROWS, NXZ, D_MODEL);

        // uc = silu(conv(u) + b)
        conv_silu<<<(NROWS * D_INNER + 255) / 256, 256, 0, stream>>>(
            xz, conv_w, conv_b, uc, dir);

        // dtBC = uc @ xproj_w^T   (16384 x 80, K=1536)  bf16 A -> fp32 C
        gemm_nt<1, 0, 0, 0><<<dim3((NDBC + 63) / 64, NROWS / 64), 256, 0, stream>>>(
            uc, D_INNER, xproj_w, D_INNER, nullptr, dtBC, NDBC, NROWS, NDBC, D_INNER);

        // dt = softplus(dtBC[:, :48] @ dt_w^T + dt_b) -> overlay in xz u-half
        gemm_nt<0, 1, 0, 1><<<dim3(D_INNER / 64, NROWS / 64), 256, 0, stream>>>(
            dtBC, NDBC, dt_w, DT_RANK, dt_b, xz, NXZ, NROWS, D_INNER, DT_RANK);

        // selective scan -> writes y*silu(z) into xz u-half (over dt)
        scan_kernel<<<(BATCH * D_INNER) / 16, 256, 0, stream>>>(
            dtBC, uc, A_log, D_skip, xz, dir);

        // outp (+)= y' @ out_w^T   (16384 x 768, K=1536)  bf16 A -> fp32 C
        if (dir == 0)
            gemm_nt<1, 0, 0, 0><<<dim3(D_MODEL / 64, NROWS / 64), 256, 0, stream>>>(
                xz, NXZ, out_w, D_INNER, nullptr, outp, D_MODEL, NROWS, D_MODEL, D_INNER);
        else
            gemm_nt<1, 0, 1, 0><<<dim3(D_MODEL / 64, NROWS / 64), 256, 0, stream>>>(
                xz, NXZ, out_w, D_INNER, nullptr, outp, D_MODEL, NROWS, D_MODEL, D_INNER);
    }

    fuse_ln<<<NROWS, 256, 0, stream>>>(outp, x, ln_g, ln_b);
}

// Round 3
// 2736.112 us; speedup vs baseline: 1.9948x; 1.9948x over previous
//
#include <hip/hip_runtime.h>
#include <math.h>

#define D_MODEL 768
#define D_INNER 1536
#define D_STATE 16
#define DCONV 4
#define DT_RANK 48
#define BATCH 8
#define SEQ 2048
#define NROWS (BATCH * SEQ)          // 16384
#define NXZ (2 * D_INNER)            // 3072
#define NDBC (DT_RANK + 2 * D_STATE) // 80

typedef __attribute__((ext_vector_type(8))) short bh8;   // 8 bf16 in 4 VGPRs
typedef __attribute__((ext_vector_type(4))) float f4;    // MFMA accumulator

// bf16 <-> fp32 helpers (bit ops; storage type = unsigned short)
__device__ __forceinline__ float bf2f(unsigned short u) {
    return __uint_as_float(((unsigned int)u) << 16);
}
__device__ __forceinline__ unsigned short f2bf(float f) {
    unsigned int x = __float_as_uint(f);
    return (unsigned short)((x + 0x7fffu + ((x >> 16) & 1u)) >> 16);
}

// async global(16B/lane) -> LDS (wave-uniform base + lane*16)
#define GLL16(gp, lp) __builtin_amdgcn_global_load_lds( \
    (const __attribute__((address_space(1))) void*)(gp), \
    (__attribute__((address_space(3))) void*)(lp), 16, 0, 0)

// ---------------------------------------------------------------------------
// bf16 MFMA GEMM, m97 structure: C(MxN) = A(MxK) @ W(NxK)^T  [+C if ACC]
// 128x128 tile, BK=32, 256 thr = 4 waves (2x2), each wave 64x64 = 4x4 frags
// of mfma_f32_16x16x32_bf16. M,N div 128; K div 32. A,W bf16; C fp32 or bf16.
// ---------------------------------------------------------------------------
template <int TC_BF, int ACC>
__global__ __launch_bounds__(256) void gemm_mfma(
    const unsigned short* __restrict__ A, int lda,
    const unsigned short* __restrict__ W, int ldw,
    void* __restrict__ Cv, int ldc,
    int N, int K)
{
    __shared__ unsigned short As[128 * 32];
    __shared__ unsigned short Bs[128 * 32];
    const int tid = threadIdx.x;
    const int w = tid >> 6;          // wave 0..3
    const int l = tid & 63;
    const int wr = w >> 1, wc = w & 1;
    const int tm0 = blockIdx.y * 128;
    const int tn0 = blockIdx.x * 128;

    // staging: issue i covers tile rows [i*64, i*64+64); wave w owns 16 rows
    const int srow = (w << 4) + (l >> 2);      // 0..63
    const int scol = (l & 3) * 8;              // bf16 col offset (8 per 16B)
    unsigned short* ldsA0 = &As[(w << 4) * 32];
    unsigned short* ldsA1 = &As[(64 + (w << 4)) * 32];
    unsigned short* ldsB0 = &Bs[(w << 4) * 32];
    unsigned short* ldsB1 = &Bs[(64 + (w << 4)) * 32];
    const unsigned short* gA0 = A + (size_t)(tm0 + srow) * lda + scol;
    const unsigned short* gA1 = A + (size_t)(tm0 + 64 + srow) * lda + scol;
    const unsigned short* gB0 = W + (size_t)(tn0 + srow) * ldw + scol;
    const unsigned short* gB1 = W + (size_t)(tn0 + 64 + srow) * ldw + scol;

    // fragment read offsets (elements) in LDS
    const int aoff = ((wr << 6) + (l & 15)) * 32 + ((l >> 4) << 3);
    const int boff = ((wc << 6) + (l & 15)) * 32 + ((l >> 4) << 3);

    f4 acc[4][4];
#pragma unroll
    for (int i = 0; i < 4; ++i)
#pragma unroll
        for (int j = 0; j < 4; ++j) acc[i][j] = 0.f;

    for (int k0 = 0; k0 < K; k0 += 32) {
        GLL16(gA0 + k0, ldsA0);
        GLL16(gA1 + k0, ldsA1);
        GLL16(gB0 + k0, ldsB0);
        GLL16(gB1 + k0, ldsB1);
        __syncthreads();           // drains vmcnt -> LDS tiles valid

        bh8 af[4], bf[4];
#pragma unroll
        for (int mi = 0; mi < 4; ++mi)
            af[mi] = *(const bh8*)&As[aoff + mi * 512];
#pragma unroll
        for (int ni = 0; ni < 4; ++ni)
            bf[ni] = *(const bh8*)&Bs[boff + ni * 512];
#pragma unroll
        for (int mi = 0; mi < 4; ++mi)
#pragma unroll
            for (int ni = 0; ni < 4; ++ni)
                acc[mi][ni] = __builtin_amdgcn_mfma_f32_16x16x32_bf16(
                    af[mi], bf[ni], acc[mi][ni], 0, 0, 0);
        __syncthreads();           // LDS free for next stage
    }

    const int crow0 = tm0 + (wr << 6) + ((l >> 4) << 2);
    const int ccol0 = tn0 + (wc << 6) + (l & 15);
#pragma unroll
    for (int mi = 0; mi < 4; ++mi)
#pragma unroll
        for (int ni = 0; ni < 4; ++ni)
#pragma unroll
            for (int r = 0; r < 4; ++r) {
                const size_t idx = (size_t)(crow0 + mi * 16 + r) * ldc
                                 + (ccol0 + ni * 16);
                const float v = acc[mi][ni][r];
                if (TC_BF) {
                    ((unsigned short*)Cv)[idx] = f2bf(v);
                } else {
                    float* C = (float*)Cv;
                    C[idx] = ACC ? (C[idx] + v) : v;
                }
            }
}

// ---------------------------------------------------------------------------
// fp32-accumulate vector GEMM (small shapes): C = act(A @ W^T [+bias])
// TA_BF: A bf16. ACT 1 = softplus(x+bias). TC_BF: C bf16.
// ---------------------------------------------------------------------------
template <int TA_BF, int ACT, int TC_BF>
__global__ __launch_bounds__(256) void gemm_nt(
    const void* __restrict__ Av, int lda,
    const float* __restrict__ W, int ldw,
    const float* __restrict__ bias,
    void* __restrict__ Cv, int ldc,
    int M, int N, int K)
{
    __shared__ float As[16][68];
    __shared__ float Ws[16][68];
    const int tid = threadIdx.x;
    const int tx = tid & 15;
    const int ty = tid >> 4;
    const int tm0 = blockIdx.y * 64;
    const int tn0 = blockIdx.x * 64;
    const int r  = tid >> 2;
    const int kq = tid & 3;

    float acc[4][4];
#pragma unroll
    for (int i = 0; i < 4; ++i)
#pragma unroll
        for (int j = 0; j < 4; ++j) acc[i][j] = 0.f;

    for (int k0 = 0; k0 < K; k0 += 16) {
        float4 av = make_float4(0.f, 0.f, 0.f, 0.f);
        if (tm0 + r < M) {
            if (TA_BF) {
                const unsigned short* A = (const unsigned short*)Av;
                ushort4 t = *(const ushort4*)&A[(size_t)(tm0 + r) * lda + k0 + kq * 4];
                av = make_float4(bf2f(t.x), bf2f(t.y), bf2f(t.z), bf2f(t.w));
            } else {
                const float* A = (const float*)Av;
                av = *(const float4*)&A[(size_t)(tm0 + r) * lda + k0 + kq * 4];
            }
        }
        As[kq * 4 + 0][r] = av.x;
        As[kq * 4 + 1][r] = av.y;
        As[kq * 4 + 2][r] = av.z;
        As[kq * 4 + 3][r] = av.w;

        float4 wv = make_float4(0.f, 0.f, 0.f, 0.f);
        if (tn0 + r < N)
            wv = *(const float4*)&W[(size_t)(tn0 + r) * ldw + k0 + kq * 4];
        Ws[kq * 4 + 0][r] = wv.x;
        Ws[kq * 4 + 1][r] = wv.y;
        Ws[kq * 4 + 2][r] = wv.z;
        Ws[kq * 4 + 3][r] = wv.w;

        __syncthreads();
#pragma unroll
        for (int kk = 0; kk < 16; ++kk) {
            const float4 a = *(const float4*)&As[kk][ty * 4];
            const float4 b = *(const float4*)&Ws[kk][tx * 4];
            acc[0][0] += a.x * b.x; acc[0][1] += a.x * b.y; acc[0][2] += a.x * b.z; acc[0][3] += a.x * b.w;
            acc[1][0] += a.y * b.x; acc[1][1] += a.y * b.y; acc[1][2] += a.y * b.z; acc[1][3] += a.y * b.w;
            acc[2][0] += a.z * b.x; acc[2][1] += a.z * b.y; acc[2][2] += a.z * b.z; acc[2][3] += a.z * b.w;
            acc[3][0] += a.w * b.x; acc[3][1] += a.w * b.y; acc[3][2] += a.w * b.z; acc[3][3] += a.w * b.w;
        }
        __syncthreads();
    }

#pragma unroll
    for (int i = 0; i < 4; ++i) {
        const int m = tm0 + ty * 4 + i;
        if (m >= M) continue;
#pragma unroll
        for (int j = 0; j < 4; ++j) {
            const int n = tn0 + tx * 4 + j;
            if (n >= N) continue;
            float v = acc[i][j];
            if (ACT == 1) {
                v += bias[n];
                v = (v > 20.f) ? v : log1pf(expf(v));
            }
            const size_t idx = (size_t)m * ldc + n;
            if (TC_BF) ((unsigned short*)Cv)[idx] = f2bf(v);
            else       ((float*)Cv)[idx] = v;
        }
    }
}

// ---------------------------------------------------------------------------
__global__ __launch_bounds__(256) void cast_f32_bf16(
    const float* __restrict__ in, unsigned short* __restrict__ out, int n4)
{
    const int i = blockIdx.x * 256 + threadIdx.x;
    if (i >= n4) return;
    const float4 v = ((const float4*)in)[i];
    ushort4 o;
    o.x = f2bf(v.x); o.y = f2bf(v.y); o.z = f2bf(v.z); o.w = f2bf(v.w);
    ((ushort4*)out)[i] = o;
}

// ---------------------------------------------------------------------------
// Causal depthwise conv1d + SiLU on bf16. dir=0: taps l-j; dir=1: taps l+j.
// ---------------------------------------------------------------------------
__global__ __launch_bounds__(256) void conv_silu(
    const unsigned short* __restrict__ xz, const float* __restrict__ conv_w,
    const float* __restrict__ conv_b, unsigned short* __restrict__ uc, int dir)
{
    const int idx = blockIdx.x * 256 + threadIdx.x;
    if (idx >= NROWS * D_INNER) return;
    const int d = idx % D_INNER;
    const int row = idx / D_INNER;
    const int l = row % SEQ;

    float acc = conv_b[d];
#pragma unroll
    for (int j = 0; j < 4; ++j) {
        const int ll = dir ? (l + j) : (l - j);
        if (ll >= 0 && ll < SEQ)
            acc += bf2f(xz[(size_t)(row - l + ll) * NXZ + d]) * conv_w[d * 4 + (3 - j)];
    }
    uc[idx] = f2bf(acc / (1.f + expf(-acc)));
}

// ---------------------------------------------------------------------------
// Selective scan. 16 lanes per (b,d) channel, one state n per lane.
// dt overlaid in xz u-half; output y*silu(z) overwrites it in place.
// ---------------------------------------------------------------------------
struct SBatch {
    float dtv[8], uv[8], Bv[8], Cv[8], zv[8];
};

__device__ __forceinline__ void scan_load(
    SBatch& s, int t0, int dir, size_t base, int d, int n,
    const unsigned short* __restrict__ uc, const float* __restrict__ dtBC,
    const unsigned short* __restrict__ xz)
{
#pragma unroll
    for (int j = 0; j < 8; ++j) {
        const int t = t0 + j;
        const int l = dir ? (SEQ - 1 - t) : t;
        const size_t row = base + l;
        s.dtv[j] = bf2f(xz[row * NXZ + d]);               // dt overlay
        s.uv[j]  = bf2f(uc[row * D_INNER + d]);
        s.Bv[j]  = dtBC[row * NDBC + DT_RANK + n];
        s.Cv[j]  = dtBC[row * NDBC + DT_RANK + D_STATE + n];
        s.zv[j]  = bf2f(xz[row * NXZ + D_INNER + d]);
    }
}

__device__ __forceinline__ void scan_compute(
    const SBatch& s, int t0, int dir, size_t base, int d, int n,
    float& h, float A, float Dv, unsigned short* __restrict__ xz)
{
#pragma unroll
    for (int j = 0; j < 8; ++j) {
        const float dtv = s.dtv[j];
        h = expf(dtv * A) * h + dtv * s.uv[j] * s.Bv[j];
        float p = h * s.Cv[j];
        p += __shfl_xor(p, 1, 16);
        p += __shfl_xor(p, 2, 16);
        p += __shfl_xor(p, 4, 16);
        p += __shfl_xor(p, 8, 16);
        if (n == 0) {
            const int t = t0 + j;
            const int l = dir ? (SEQ - 1 - t) : t;
            const size_t row = base + l;
            const float y = p + s.uv[j] * Dv;
            const float zv = s.zv[j];
            const float sz = zv / (1.f + expf(-zv));
            xz[row * NXZ + d] = f2bf(y * sz);
        }
    }
}

__global__ __launch_bounds__(256) void scan_kernel(
    const float* __restrict__ dtBC, const unsigned short* __restrict__ uc,
    const float* __restrict__ A_log, const float* __restrict__ D_skip,
    unsigned short* __restrict__ xz, int dir)
{
    const int tid = threadIdx.x;
    const int n = tid & 15;
    const int g = tid >> 4;
    const int ch = blockIdx.x * 16 + g;   // 0 .. BATCH*D_INNER-1
    const int b = ch / D_INNER;
    const int d = ch % D_INNER;

    const float A  = -expf(A_log[d * D_STATE + n]);
    const float Dv = D_skip[d];
    const size_t base = (size_t)b * SEQ;
    float h = 0.f;

    SBatch sa, sb;
    scan_load(sa, 0, dir, base, d, n, uc, dtBC, xz);
    for (int t0 = 0; t0 < SEQ; t0 += 16) {
        scan_load(sb, t0 + 8, dir, base, d, n, uc, dtBC, xz);
        scan_compute(sa, t0, dir, base, d, n, h, A, Dv, xz);
        if (t0 + 16 < SEQ)
            scan_load(sa, t0 + 16, dir, base, d, n, uc, dtBC, xz);
        scan_compute(sb, t0 + 8, dir, base, d, n, h, A, Dv, xz);
    }
}

// ---------------------------------------------------------------------------
// In-place: out = LN(out + x) * g + b   (out already holds out_f + out_b)
// ---------------------------------------------------------------------------
__global__ __launch_bounds__(256) void fuse_ln(
    float* __restrict__ out, const float* __restrict__ x,
    const float* __restrict__ g, const float* __restrict__ bta)
{
    const int row = blockIdx.x;
    const size_t base = (size_t)row * D_MODEL;
    float vals[3];
    float s = 0.f, s2 = 0.f;
#pragma unroll
    for (int i = 0; i < 3; ++i) {
        const int c = threadIdx.x + i * 256;
        const float v = out[base + c] + x[base + c];
        vals[i] = v;
        s += v;
        s2 += v * v;
    }
#pragma unroll
    for (int o = 32; o >= 1; o >>= 1) {
        s  += __shfl_xor(s, o, 64);
        s2 += __shfl_xor(s2, o, 64);
    }
    __shared__ float ls[4], ls2[4];
    const int wid = threadIdx.x >> 6;
    if ((threadIdx.x & 63) == 0) { ls[wid] = s; ls2[wid] = s2; }
    __syncthreads();
    s  = ls[0] + ls[1] + ls[2] + ls[3];
    s2 = ls2[0] + ls2[1] + ls2[2] + ls2[3];
    const float mu  = s * (1.f / D_MODEL);
    const float var = s2 * (1.f / D_MODEL) - mu * mu;
    const float inv = 1.f / sqrtf(var + 1e-12f);
#pragma unroll
    for (int i = 0; i < 3; ++i) {
        const int c = threadIdx.x + i * 256;
        out[base + c] = (vals[i] - mu) * inv * g[c] + bta[c];
    }
}

// ---------------------------------------------------------------------------
extern "C" void kernel_launch(void* const* d_in, const int* in_sizes, int n_in,
                              void* d_out, int out_size, void* d_ws, size_t ws_size,
                              hipStream_t stream)
{
    const float* x = (const float*)d_in[0];
    const float* ln_g = (const float*)d_in[19];
    const float* ln_b = (const float*)d_in[20];

    // workspace layout (188.5 MB total)
    float* dtBC = (float*)d_ws;                                   //  5.24 MB fp32
    unsigned short* xz  = (unsigned short*)(dtBC + (size_t)NROWS * NDBC);  // 100.7 MB bf16
    unsigned short* uc  = xz + (size_t)NROWS * NXZ;               // 50.3 MB bf16
    unsigned short* xbf = uc + (size_t)NROWS * D_INNER;           // 25.2 MB bf16
    unsigned short* wbf_in  = xbf + (size_t)NROWS * D_MODEL;      //  4.7 MB bf16
    unsigned short* wbf_out = wbf_in + (size_t)NXZ * D_MODEL;     //  2.4 MB bf16
    const size_t needed = ((size_t)NROWS * NDBC) * 4
        + ((size_t)NROWS * NXZ + (size_t)NROWS * D_INNER + (size_t)NROWS * D_MODEL
           + (size_t)NXZ * D_MODEL + (size_t)D_MODEL * D_INNER) * 2;
    if (ws_size < needed) return;  // fail absmax cleanly instead of faulting

    float* outp = (float*)d_out;   // fp32 accumulator for out_f + out_b

    // x -> bf16 once
    cast_f32_bf16<<<(NROWS * D_MODEL / 4 + 255) / 256, 256, 0, stream>>>(
        x, xbf, NROWS * D_MODEL / 4);

    for (int dir = 0; dir < 2; ++dir) {
        const float* in_w    = (const float*)d_in[1 + dir * 9 + 0];
        const float* conv_w  = (const float*)d_in[1 + dir * 9 + 1];
        const float* conv_b  = (const float*)d_in[1 + dir * 9 + 2];
        const float* xproj_w = (const float*)d_in[1 + dir * 9 + 3];
        const float* dt_w    = (const float*)d_in[1 + dir * 9 + 4];
        const float* dt_b    = (const float*)d_in[1 + dir * 9 + 5];
        const float* A_log   = (const float*)d_in[1 + dir * 9 + 6];
        const float* D_skip  = (const float*)d_in[1 + dir * 9 + 7];
        const float* out_w   = (const float*)d_in[1 + dir * 9 + 8];

        // weights -> bf16
        cast_f32_bf16<<<(NXZ * D_MODEL / 4 + 255) / 256, 256, 0, stream>>>(
            in_w, wbf_in, NXZ * D_MODEL / 4);
        cast_f32_bf16<<<(D_MODEL * D_INNER / 4 + 255) / 256, 256, 0, stream>>>(
            out_w, wbf_out, D_MODEL * D_INNER / 4);

        // xz = x @ in_w^T  (16384 x 3072, K=768)  MFMA -> bf16
        gemm_mfma<1, 0><<<dim3(NXZ / 128, NROWS / 128), 256, 0, stream>>>(
            xbf, D_MODEL, wbf_in, D_MODEL, xz, NXZ, NXZ, D_MODEL);

        // uc = silu(conv(u) + b)
        conv_silu<<<(NROWS * D_INNER + 255) / 256, 256, 0, stream>>>(
            xz, conv_w, conv_b, uc, dir);

        // dtBC = uc @ xproj_w^T   (16384 x 80, K=1536)  bf16 A -> fp32 C
        gemm_nt<1, 0, 0><<<dim3((NDBC + 63) / 64, NROWS / 64), 256, 0, stream>>>(
            uc, D_INNER, xproj_w, D_INNER, nullptr, dtBC, NDBC, NROWS, NDBC, D_INNER);

        // dt = softplus(dtBC[:, :48] @ dt_w^T + dt_b) -> overlay in xz u-half
        gemm_nt<0, 1, 1><<<dim3(D_INNER / 64, NROWS / 64), 256, 0, stream>>>(
            dtBC, NDBC, dt_w, DT_RANK, dt_b, xz, NXZ, NROWS, D_INNER, DT_RANK);

        // selective scan -> writes y*silu(z) into xz u-half (over dt)
        scan_kernel<<<(BATCH * D_INNER) / 16, 256, 0, stream>>>(
            dtBC, uc, A_log, D_skip, xz, dir);

        // outp (+)= y' @ out_w^T   (16384 x 768, K=1536)  MFMA -> fp32
        if (dir == 0)
            gemm_mfma<0, 0><<<dim3(D_MODEL / 128, NROWS / 128), 256, 0, stream>>>(
                xz, NXZ, wbf_out, D_INNER, outp, D_MODEL, D_MODEL, D_INNER);
        else
            gemm_mfma<0, 1><<<dim3(D_MODEL / 128, NROWS / 128), 256, 0, stream>>>(
                xz, NXZ, wbf_out, D_INNER, outp, D_MODEL, D_MODEL, D_INNER);
    }

    fuse_ln<<<NROWS, 256, 0, stream>>>(outp, x, ln_g, ln_b);
}

// Round 4
// 2059.602 us; speedup vs baseline: 2.6500x; 1.3285x over previous
//
#include <hip/hip_runtime.h>
#include <math.h>

#define D_MODEL 768
#define D_INNER 1536
#define D_STATE 16
#define DCONV 4
#define DT_RANK 48
#define BATCH 8
#define SEQ 2048
#define NROWS (BATCH * SEQ)          // 16384
#define NXZ (2 * D_INNER)            // 3072
#define NDBC (DT_RANK + 2 * D_STATE) // 80

#define LOG2E 1.4426950408889634f
#define LN2   0.6931471805599453f

typedef __attribute__((ext_vector_type(8))) short bh8;   // 8 bf16 in 4 VGPRs
typedef __attribute__((ext_vector_type(4))) float f4;    // MFMA accumulator

// bf16 <-> fp32 helpers (bit ops; storage type = unsigned short)
__device__ __forceinline__ float bf2f(unsigned short u) {
    return __uint_as_float(((unsigned int)u) << 16);
}
__device__ __forceinline__ unsigned short f2bf(float f) {
    unsigned int x = __float_as_uint(f);
    return (unsigned short)((x + 0x7fffu + ((x >> 16) & 1u)) >> 16);
}
// fast sigmoid: 1/(1+e^-x) via v_exp_f32 + v_rcp_f32
__device__ __forceinline__ float fsigm(float x) {
    return __builtin_amdgcn_rcpf(1.f + __builtin_amdgcn_exp2f(-x * LOG2E));
}

// async global(16B/lane) -> LDS (wave-uniform base + lane*16)
#define GLL16(gp, lp) __builtin_amdgcn_global_load_lds( \
    (const __attribute__((address_space(1))) void*)(gp), \
    (__attribute__((address_space(3))) void*)(lp), 16, 0, 0)

// ---------------------------------------------------------------------------
// bf16 MFMA GEMM, m97 structure: C(MxN) = A(MxK) @ W(NxK)^T  [+C if ACC]
// 128x128 tile, BK=32, 256 thr = 4 waves (2x2), each wave 64x64 = 4x4 frags
// of mfma_f32_16x16x32_bf16. M,N div 128; K div 32. A,W bf16; C fp32 or bf16.
// ---------------------------------------------------------------------------
template <int TC_BF, int ACC>
__global__ __launch_bounds__(256) void gemm_mfma(
    const unsigned short* __restrict__ A, int lda,
    const unsigned short* __restrict__ W, int ldw,
    void* __restrict__ Cv, int ldc,
    int N, int K)
{
    __shared__ unsigned short As[128 * 32];
    __shared__ unsigned short Bs[128 * 32];
    const int tid = threadIdx.x;
    const int w = tid >> 6;          // wave 0..3
    const int l = tid & 63;
    const int wr = w >> 1, wc = w & 1;
    const int tm0 = blockIdx.y * 128;
    const int tn0 = blockIdx.x * 128;

    const int srow = (w << 4) + (l >> 2);      // 0..63
    const int scol = (l & 3) * 8;              // bf16 col offset (8 per 16B)
    unsigned short* ldsA0 = &As[(w << 4) * 32];
    unsigned short* ldsA1 = &As[(64 + (w << 4)) * 32];
    unsigned short* ldsB0 = &Bs[(w << 4) * 32];
    unsigned short* ldsB1 = &Bs[(64 + (w << 4)) * 32];
    const unsigned short* gA0 = A + (size_t)(tm0 + srow) * lda + scol;
    const unsigned short* gA1 = A + (size_t)(tm0 + 64 + srow) * lda + scol;
    const unsigned short* gB0 = W + (size_t)(tn0 + srow) * ldw + scol;
    const unsigned short* gB1 = W + (size_t)(tn0 + 64 + srow) * ldw + scol;

    const int aoff = ((wr << 6) + (l & 15)) * 32 + ((l >> 4) << 3);
    const int boff = ((wc << 6) + (l & 15)) * 32 + ((l >> 4) << 3);

    f4 acc[4][4];
#pragma unroll
    for (int i = 0; i < 4; ++i)
#pragma unroll
        for (int j = 0; j < 4; ++j) acc[i][j] = 0.f;

    for (int k0 = 0; k0 < K; k0 += 32) {
        GLL16(gA0 + k0, ldsA0);
        GLL16(gA1 + k0, ldsA1);
        GLL16(gB0 + k0, ldsB0);
        GLL16(gB1 + k0, ldsB1);
        __syncthreads();

        bh8 af[4], bf[4];
#pragma unroll
        for (int mi = 0; mi < 4; ++mi)
            af[mi] = *(const bh8*)&As[aoff + mi * 512];
#pragma unroll
        for (int ni = 0; ni < 4; ++ni)
            bf[ni] = *(const bh8*)&Bs[boff + ni * 512];
#pragma unroll
        for (int mi = 0; mi < 4; ++mi)
#pragma unroll
            for (int ni = 0; ni < 4; ++ni)
                acc[mi][ni] = __builtin_amdgcn_mfma_f32_16x16x32_bf16(
                    af[mi], bf[ni], acc[mi][ni], 0, 0, 0);
        __syncthreads();
    }

    const int crow0 = tm0 + (wr << 6) + ((l >> 4) << 2);
    const int ccol0 = tn0 + (wc << 6) + (l & 15);
#pragma unroll
    for (int mi = 0; mi < 4; ++mi)
#pragma unroll
        for (int ni = 0; ni < 4; ++ni)
#pragma unroll
            for (int r = 0; r < 4; ++r) {
                const size_t idx = (size_t)(crow0 + mi * 16 + r) * ldc
                                 + (ccol0 + ni * 16);
                const float v = acc[mi][ni][r];
                if (TC_BF) {
                    ((unsigned short*)Cv)[idx] = f2bf(v);
                } else {
                    float* C = (float*)Cv;
                    C[idx] = ACC ? (C[idx] + v) : v;
                }
            }
}

// ---------------------------------------------------------------------------
// fp32-accumulate vector GEMM (small shapes): C = act(A @ W^T [+bias])
// TA_BF: A bf16. ACT 1 = softplus(x+bias). TC_BF: C bf16.
// ---------------------------------------------------------------------------
template <int TA_BF, int ACT, int TC_BF>
__global__ __launch_bounds__(256) void gemm_nt(
    const void* __restrict__ Av, int lda,
    const float* __restrict__ W, int ldw,
    const float* __restrict__ bias,
    void* __restrict__ Cv, int ldc,
    int M, int N, int K)
{
    __shared__ float As[16][68];
    __shared__ float Ws[16][68];
    const int tid = threadIdx.x;
    const int tx = tid & 15;
    const int ty = tid >> 4;
    const int tm0 = blockIdx.y * 64;
    const int tn0 = blockIdx.x * 64;
    const int r  = tid >> 2;
    const int kq = tid & 3;

    float acc[4][4];
#pragma unroll
    for (int i = 0; i < 4; ++i)
#pragma unroll
        for (int j = 0; j < 4; ++j) acc[i][j] = 0.f;

    for (int k0 = 0; k0 < K; k0 += 16) {
        float4 av = make_float4(0.f, 0.f, 0.f, 0.f);
        if (tm0 + r < M) {
            if (TA_BF) {
                const unsigned short* A = (const unsigned short*)Av;
                ushort4 t = *(const ushort4*)&A[(size_t)(tm0 + r) * lda + k0 + kq * 4];
                av = make_float4(bf2f(t.x), bf2f(t.y), bf2f(t.z), bf2f(t.w));
            } else {
                const float* A = (const float*)Av;
                av = *(const float4*)&A[(size_t)(tm0 + r) * lda + k0 + kq * 4];
            }
        }
        As[kq * 4 + 0][r] = av.x;
        As[kq * 4 + 1][r] = av.y;
        As[kq * 4 + 2][r] = av.z;
        As[kq * 4 + 3][r] = av.w;

        float4 wv = make_float4(0.f, 0.f, 0.f, 0.f);
        if (tn0 + r < N)
            wv = *(const float4*)&W[(size_t)(tn0 + r) * ldw + k0 + kq * 4];
        Ws[kq * 4 + 0][r] = wv.x;
        Ws[kq * 4 + 1][r] = wv.y;
        Ws[kq * 4 + 2][r] = wv.z;
        Ws[kq * 4 + 3][r] = wv.w;

        __syncthreads();
#pragma unroll
        for (int kk = 0; kk < 16; ++kk) {
            const float4 a = *(const float4*)&As[kk][ty * 4];
            const float4 b = *(const float4*)&Ws[kk][tx * 4];
            acc[0][0] += a.x * b.x; acc[0][1] += a.x * b.y; acc[0][2] += a.x * b.z; acc[0][3] += a.x * b.w;
            acc[1][0] += a.y * b.x; acc[1][1] += a.y * b.y; acc[1][2] += a.y * b.z; acc[1][3] += a.y * b.w;
            acc[2][0] += a.z * b.x; acc[2][1] += a.z * b.y; acc[2][2] += a.z * b.z; acc[2][3] += a.z * b.w;
            acc[3][0] += a.w * b.x; acc[3][1] += a.w * b.y; acc[3][2] += a.w * b.z; acc[3][3] += a.w * b.w;
        }
        __syncthreads();
    }

#pragma unroll
    for (int i = 0; i < 4; ++i) {
        const int m = tm0 + ty * 4 + i;
        if (m >= M) continue;
#pragma unroll
        for (int j = 0; j < 4; ++j) {
            const int n = tn0 + tx * 4 + j;
            if (n >= N) continue;
            float v = acc[i][j];
            if (ACT == 1) {
                v += bias[n];
                // softplus via v_exp/v_log (log2-domain)
                if (v <= 20.f)
                    v = __builtin_amdgcn_logf(1.f + __builtin_amdgcn_exp2f(v * LOG2E)) * LN2;
            }
            const size_t idx = (size_t)m * ldc + n;
            if (TC_BF) ((unsigned short*)Cv)[idx] = f2bf(v);
            else       ((float*)Cv)[idx] = v;
        }
    }
}

// ---------------------------------------------------------------------------
__global__ __launch_bounds__(256) void cast_f32_bf16(
    const float* __restrict__ in, unsigned short* __restrict__ out, int n4)
{
    const int i = blockIdx.x * 256 + threadIdx.x;
    if (i >= n4) return;
    const float4 v = ((const float4*)in)[i];
    ushort4 o;
    o.x = f2bf(v.x); o.y = f2bf(v.y); o.z = f2bf(v.z); o.w = f2bf(v.w);
    ((ushort4*)out)[i] = o;
}

// ---------------------------------------------------------------------------
// Causal depthwise conv1d + SiLU on bf16. DIR=0: taps l-j; DIR=1: taps l+j.
// ---------------------------------------------------------------------------
template <int DIR>
__global__ __launch_bounds__(256) void conv_silu(
    const unsigned short* __restrict__ xz, const float* __restrict__ conv_w,
    const float* __restrict__ conv_b, unsigned short* __restrict__ uc)
{
    const int idx = blockIdx.x * 256 + threadIdx.x;
    if (idx >= NROWS * D_INNER) return;
    const int d = idx % D_INNER;
    const int row = idx / D_INNER;
    const int l = row % SEQ;

    float acc = conv_b[d];
#pragma unroll
    for (int j = 0; j < 4; ++j) {
        const int ll = DIR ? (l + j) : (l - j);
        if (ll >= 0 && ll < SEQ)
            acc = fmaf(bf2f(xz[(size_t)(row - l + ll) * NXZ + d]),
                       conv_w[d * 4 + (3 - j)], acc);
    }
    uc[idx] = f2bf(acc * fsigm(acc));
}

// ---------------------------------------------------------------------------
// Selective scan. 16 lanes per (b,d) channel, one state n per lane.
// dt overlaid in xz u-half; output y*silu(z) overwrites it in place.
// DIR template -> compile-time strides. Fast exp2/rcp math.
// ---------------------------------------------------------------------------
struct SBatch {
    float dtv[8], uv[8], Bv[8], Cv[8], zv[8];
};

template <int ST>
struct ScanPtrs {
    const unsigned short *pdt, *pu, *pz;
    const float *pB, *pC;
    unsigned short *pout;
};

template <int ST>
__device__ __forceinline__ void scan_load(
    SBatch& s, const ScanPtrs<ST>& p, int t0)
{
#pragma unroll
    for (int j = 0; j < 8; ++j) {
        const int t = t0 + j;
        s.dtv[j] = bf2f(p.pdt[(long)t * (ST * NXZ)]);
        s.uv[j]  = bf2f(p.pu [(long)t * (ST * D_INNER)]);
        s.Bv[j]  =      p.pB [(long)t * (ST * NDBC)];
        s.Cv[j]  =      p.pC [(long)t * (ST * NDBC)];
        s.zv[j]  = bf2f(p.pz [(long)t * (ST * NXZ)]);
    }
}

template <int ST>
__device__ __forceinline__ void scan_compute(
    const SBatch& s, const ScanPtrs<ST>& p, int t0, int n,
    float& h, float A2, float Dv)
{
#pragma unroll
    for (int j = 0; j < 8; ++j) {
        const float dtv = s.dtv[j];
        const float dA = __builtin_amdgcn_exp2f(dtv * A2);   // exp(dt*A)
        h = fmaf(dA, h, dtv * s.uv[j] * s.Bv[j]);
        float pp = h * s.Cv[j];
        pp += __shfl_xor(pp, 1, 16);
        pp += __shfl_xor(pp, 2, 16);
        pp += __shfl_xor(pp, 4, 16);
        pp += __shfl_xor(pp, 8, 16);
        if (n == 0) {
            const float y = fmaf(s.uv[j], Dv, pp);
            p.pout[(long)(t0 + j) * (ST * NXZ)] = f2bf(y * (s.zv[j] * fsigm(s.zv[j])));
        }
    }
}

template <int DIR>
__global__ __launch_bounds__(256) void scan_kernel(
    const float* __restrict__ dtBC, const unsigned short* __restrict__ uc,
    const float* __restrict__ A_log, const float* __restrict__ D_skip,
    unsigned short* __restrict__ xz)
{
    const int tid = threadIdx.x;
    const int n = tid & 15;
    const int g = tid >> 4;
    const int ch = blockIdx.x * 16 + g;   // 0 .. BATCH*D_INNER-1
    const int b = ch / D_INNER;
    const int d = ch % D_INNER;

    const float A2 = -expf(A_log[d * D_STATE + n]) * LOG2E;
    const float Dv = D_skip[d];
    const int l0 = DIR ? (SEQ - 1) : 0;
    const size_t row0 = (size_t)b * SEQ + l0;
    constexpr int ST = DIR ? -1 : 1;

    ScanPtrs<ST> p;
    p.pdt  = xz + row0 * NXZ + d;
    p.pz   = xz + row0 * NXZ + D_INNER + d;
    p.pu   = uc + row0 * D_INNER + d;
    p.pB   = dtBC + row0 * NDBC + DT_RANK + n;
    p.pC   = p.pB + D_STATE;
    p.pout = xz + row0 * NXZ + d;

    float h = 0.f;
    SBatch sa, sb;
    scan_load<ST>(sa, p, 0);
    for (int t0 = 0; t0 < SEQ; t0 += 16) {
        scan_load<ST>(sb, p, t0 + 8);
        scan_compute<ST>(sa, p, t0, n, h, A2, Dv);
        if (t0 + 16 < SEQ)
            scan_load<ST>(sa, p, t0 + 16);
        scan_compute<ST>(sb, p, t0 + 8, n, h, A2, Dv);
    }
}

// ---------------------------------------------------------------------------
// In-place: out = LN(out + x) * g + b   (out already holds out_f + out_b)
// ---------------------------------------------------------------------------
__global__ __launch_bounds__(256) void fuse_ln(
    float* __restrict__ out, const float* __restrict__ x,
    const float* __restrict__ g, const float* __restrict__ bta)
{
    const int row = blockIdx.x;
    const size_t base = (size_t)row * D_MODEL;
    float vals[3];
    float s = 0.f, s2 = 0.f;
#pragma unroll
    for (int i = 0; i < 3; ++i) {
        const int c = threadIdx.x + i * 256;
        const float v = out[base + c] + x[base + c];
        vals[i] = v;
        s += v;
        s2 += v * v;
    }
#pragma unroll
    for (int o = 32; o >= 1; o >>= 1) {
        s  += __shfl_xor(s, o, 64);
        s2 += __shfl_xor(s2, o, 64);
    }
    __shared__ float ls[4], ls2[4];
    const int wid = threadIdx.x >> 6;
    if ((threadIdx.x & 63) == 0) { ls[wid] = s; ls2[wid] = s2; }
    __syncthreads();
    s  = ls[0] + ls[1] + ls[2] + ls[3];
    s2 = ls2[0] + ls2[1] + ls2[2] + ls2[3];
    const float mu  = s * (1.f / D_MODEL);
    const float var = s2 * (1.f / D_MODEL) - mu * mu;
    const float inv = 1.f / sqrtf(var + 1e-12f);
#pragma unroll
    for (int i = 0; i < 3; ++i) {
        const int c = threadIdx.x + i * 256;
        out[base + c] = (vals[i] - mu) * inv * g[c] + bta[c];
    }
}

// ---------------------------------------------------------------------------
extern "C" void kernel_launch(void* const* d_in, const int* in_sizes, int n_in,
                              void* d_out, int out_size, void* d_ws, size_t ws_size,
                              hipStream_t stream)
{
    const float* x = (const float*)d_in[0];
    const float* ln_g = (const float*)d_in[19];
    const float* ln_b = (const float*)d_in[20];

    // workspace layout (188.5 MB total)
    float* dtBC = (float*)d_ws;                                   //  5.24 MB fp32
    unsigned short* xz  = (unsigned short*)(dtBC + (size_t)NROWS * NDBC);  // 100.7 MB bf16
    unsigned short* uc  = xz + (size_t)NROWS * NXZ;               // 50.3 MB bf16
    unsigned short* xbf = uc + (size_t)NROWS * D_INNER;           // 25.2 MB bf16
    unsigned short* wbf_in  = xbf + (size_t)NROWS * D_MODEL;      //  4.7 MB bf16
    unsigned short* wbf_out = wbf_in + (size_t)NXZ * D_MODEL;     //  2.4 MB bf16
    const size_t needed = ((size_t)NROWS * NDBC) * 4
        + ((size_t)NROWS * NXZ + (size_t)NROWS * D_INNER + (size_t)NROWS * D_MODEL
           + (size_t)NXZ * D_MODEL + (size_t)D_MODEL * D_INNER) * 2;
    if (ws_size < needed) return;  // fail absmax cleanly instead of faulting

    float* outp = (float*)d_out;   // fp32 accumulator for out_f + out_b

    // x -> bf16 once
    cast_f32_bf16<<<(NROWS * D_MODEL / 4 + 255) / 256, 256, 0, stream>>>(
        x, xbf, NROWS * D_MODEL / 4);

    for (int dir = 0; dir < 2; ++dir) {
        const float* in_w    = (const float*)d_in[1 + dir * 9 + 0];
        const float* conv_w  = (const float*)d_in[1 + dir * 9 + 1];
        const float* conv_b  = (const float*)d_in[1 + dir * 9 + 2];
        const float* xproj_w = (const float*)d_in[1 + dir * 9 + 3];
        const float* dt_w    = (const float*)d_in[1 + dir * 9 + 4];
        const float* dt_b    = (const float*)d_in[1 + dir * 9 + 5];
        const float* A_log   = (const float*)d_in[1 + dir * 9 + 6];
        const float* D_skip  = (const float*)d_in[1 + dir * 9 + 7];
        const float* out_w   = (const float*)d_in[1 + dir * 9 + 8];

        // weights -> bf16
        cast_f32_bf16<<<(NXZ * D_MODEL / 4 + 255) / 256, 256, 0, stream>>>(
            in_w, wbf_in, NXZ * D_MODEL / 4);
        cast_f32_bf16<<<(D_MODEL * D_INNER / 4 + 255) / 256, 256, 0, stream>>>(
            out_w, wbf_out, D_MODEL * D_INNER / 4);

        // xz = x @ in_w^T  (16384 x 3072, K=768)  MFMA -> bf16
        gemm_mfma<1, 0><<<dim3(NXZ / 128, NROWS / 128), 256, 0, stream>>>(
            xbf, D_MODEL, wbf_in, D_MODEL, xz, NXZ, NXZ, D_MODEL);

        // uc = silu(conv(u) + b)
        if (dir == 0)
            conv_silu<0><<<(NROWS * D_INNER + 255) / 256, 256, 0, stream>>>(
                xz, conv_w, conv_b, uc);
        else
            conv_silu<1><<<(NROWS * D_INNER + 255) / 256, 256, 0, stream>>>(
                xz, conv_w, conv_b, uc);

        // dtBC = uc @ xproj_w^T   (16384 x 80, K=1536)  bf16 A -> fp32 C
        gemm_nt<1, 0, 0><<<dim3((NDBC + 63) / 64, NROWS / 64), 256, 0, stream>>>(
            uc, D_INNER, xproj_w, D_INNER, nullptr, dtBC, NDBC, NROWS, NDBC, D_INNER);

        // dt = softplus(dtBC[:, :48] @ dt_w^T + dt_b) -> overlay in xz u-half
        gemm_nt<0, 1, 1><<<dim3(D_INNER / 64, NROWS / 64), 256, 0, stream>>>(
            dtBC, NDBC, dt_w, DT_RANK, dt_b, xz, NXZ, NROWS, D_INNER, DT_RANK);

        // selective scan -> writes y*silu(z) into xz u-half (over dt)
        if (dir == 0)
            scan_kernel<0><<<(BATCH * D_INNER) / 16, 256, 0, stream>>>(
                dtBC, uc, A_log, D_skip, xz);
        else
            scan_kernel<1><<<(BATCH * D_INNER) / 16, 256, 0, stream>>>(
                dtBC, uc, A_log, D_skip, xz);

        // outp (+)= y' @ out_w^T   (16384 x 768, K=1536)  MFMA -> fp32
        if (dir == 0)
            gemm_mfma<0, 0><<<dim3(D_MODEL / 128, NROWS / 128), 256, 0, stream>>>(
                xz, NXZ, wbf_out, D_INNER, outp, D_MODEL, D_MODEL, D_INNER);
        else
            gemm_mfma<0, 1><<<dim3(D_MODEL / 128, NROWS / 128), 256, 0, stream>>>(
                xz, NXZ, wbf_out, D_INNER, outp, D_MODEL, D_MODEL, D_INNER);
    }

    fuse_ln<<<NROWS, 256, 0, stream>>>(outp, x, ln_g, ln_b);
}

// Round 5
// 1889.790 us; speedup vs baseline: 2.8882x; 1.0899x over previous
//
#include <hip/hip_runtime.h>
#include <math.h>

#define D_MODEL 768
#define D_INNER 1536
#define D_STATE 16
#define DCONV 4
#define DT_RANK 48
#define BATCH 8
#define SEQ 2048
#define NROWS (BATCH * SEQ)          // 16384
#define NXZ (2 * D_INNER)            // 3072
#define NDBC (DT_RANK + 2 * D_STATE) // 80

#define NCHUNK 4
#define CL (SEQ / NCHUNK)            // 512
#define NCH (BATCH * D_INNER)        // 12288 channels
#define NGRP (NCH / 16)              // 768 channel-groups (16 ch/block)

#define LOG2E 1.4426950408889634f
#define LN2   0.6931471805599453f

typedef __attribute__((ext_vector_type(8))) short bh8;   // 8 bf16 in 4 VGPRs
typedef __attribute__((ext_vector_type(4))) float f4;    // MFMA accumulator

// bf16 <-> fp32 helpers (bit ops; storage type = unsigned short)
__device__ __forceinline__ float bf2f(unsigned short u) {
    return __uint_as_float(((unsigned int)u) << 16);
}
__device__ __forceinline__ unsigned short f2bf(float f) {
    unsigned int x = __float_as_uint(f);
    return (unsigned short)((x + 0x7fffu + ((x >> 16) & 1u)) >> 16);
}
// fast sigmoid: 1/(1+e^-x) via v_exp_f32 + v_rcp_f32
__device__ __forceinline__ float fsigm(float x) {
    return __builtin_amdgcn_rcpf(1.f + __builtin_amdgcn_exp2f(-x * LOG2E));
}

// async global(16B/lane) -> LDS (wave-uniform base + lane*16)
#define GLL16(gp, lp) __builtin_amdgcn_global_load_lds( \
    (const __attribute__((address_space(1))) void*)(gp), \
    (__attribute__((address_space(3))) void*)(lp), 16, 0, 0)

// ---------------------------------------------------------------------------
// bf16 MFMA GEMM, m97 structure: C(MxN) = A(MxK) @ W(NxK)^T  [+C if ACC]
// 128x128 tile, BK=32, 256 thr = 4 waves (2x2), each wave 64x64 = 4x4 frags
// of mfma_f32_16x16x32_bf16. M,N div 128; K div 32. A,W bf16; C fp32 or bf16.
// ---------------------------------------------------------------------------
template <int TC_BF, int ACC>
__global__ __launch_bounds__(256) void gemm_mfma(
    const unsigned short* __restrict__ A, int lda,
    const unsigned short* __restrict__ W, int ldw,
    void* __restrict__ Cv, int ldc,
    int N, int K)
{
    __shared__ unsigned short As[128 * 32];
    __shared__ unsigned short Bs[128 * 32];
    const int tid = threadIdx.x;
    const int w = tid >> 6;          // wave 0..3
    const int l = tid & 63;
    const int wr = w >> 1, wc = w & 1;
    const int tm0 = blockIdx.y * 128;
    const int tn0 = blockIdx.x * 128;

    const int srow = (w << 4) + (l >> 2);      // 0..63
    const int scol = (l & 3) * 8;              // bf16 col offset (8 per 16B)
    unsigned short* ldsA0 = &As[(w << 4) * 32];
    unsigned short* ldsA1 = &As[(64 + (w << 4)) * 32];
    unsigned short* ldsB0 = &Bs[(w << 4) * 32];
    unsigned short* ldsB1 = &Bs[(64 + (w << 4)) * 32];
    const unsigned short* gA0 = A + (size_t)(tm0 + srow) * lda + scol;
    const unsigned short* gA1 = A + (size_t)(tm0 + 64 + srow) * lda + scol;
    const unsigned short* gB0 = W + (size_t)(tn0 + srow) * ldw + scol;
    const unsigned short* gB1 = W + (size_t)(tn0 + 64 + srow) * ldw + scol;

    const int aoff = ((wr << 6) + (l & 15)) * 32 + ((l >> 4) << 3);
    const int boff = ((wc << 6) + (l & 15)) * 32 + ((l >> 4) << 3);

    f4 acc[4][4];
#pragma unroll
    for (int i = 0; i < 4; ++i)
#pragma unroll
        for (int j = 0; j < 4; ++j) acc[i][j] = 0.f;

    for (int k0 = 0; k0 < K; k0 += 32) {
        GLL16(gA0 + k0, ldsA0);
        GLL16(gA1 + k0, ldsA1);
        GLL16(gB0 + k0, ldsB0);
        GLL16(gB1 + k0, ldsB1);
        __syncthreads();

        bh8 af[4], bf[4];
#pragma unroll
        for (int mi = 0; mi < 4; ++mi)
            af[mi] = *(const bh8*)&As[aoff + mi * 512];
#pragma unroll
        for (int ni = 0; ni < 4; ++ni)
            bf[ni] = *(const bh8*)&Bs[boff + ni * 512];
#pragma unroll
        for (int mi = 0; mi < 4; ++mi)
#pragma unroll
            for (int ni = 0; ni < 4; ++ni)
                acc[mi][ni] = __builtin_amdgcn_mfma_f32_16x16x32_bf16(
                    af[mi], bf[ni], acc[mi][ni], 0, 0, 0);
        __syncthreads();
    }

    const int crow0 = tm0 + (wr << 6) + ((l >> 4) << 2);
    const int ccol0 = tn0 + (wc << 6) + (l & 15);
#pragma unroll
    for (int mi = 0; mi < 4; ++mi)
#pragma unroll
        for (int ni = 0; ni < 4; ++ni)
#pragma unroll
            for (int r = 0; r < 4; ++r) {
                const size_t idx = (size_t)(crow0 + mi * 16 + r) * ldc
                                 + (ccol0 + ni * 16);
                const float v = acc[mi][ni][r];
                if (TC_BF) {
                    ((unsigned short*)Cv)[idx] = f2bf(v);
                } else {
                    float* C = (float*)Cv;
                    C[idx] = ACC ? (C[idx] + v) : v;
                }
            }
}

// ---------------------------------------------------------------------------
// fp32-accumulate vector GEMM (small shapes): C = act(A @ W^T [+bias])
// TA_BF: A bf16. ACT 1 = softplus(x+bias). TC_BF: C bf16.
// ---------------------------------------------------------------------------
template <int TA_BF, int ACT, int TC_BF>
__global__ __launch_bounds__(256) void gemm_nt(
    const void* __restrict__ Av, int lda,
    const float* __restrict__ W, int ldw,
    const float* __restrict__ bias,
    void* __restrict__ Cv, int ldc,
    int M, int N, int K)
{
    __shared__ float As[16][68];
    __shared__ float Ws[16][68];
    const int tid = threadIdx.x;
    const int tx = tid & 15;
    const int ty = tid >> 4;
    const int tm0 = blockIdx.y * 64;
    const int tn0 = blockIdx.x * 64;
    const int r  = tid >> 2;
    const int kq = tid & 3;

    float acc[4][4];
#pragma unroll
    for (int i = 0; i < 4; ++i)
#pragma unroll
        for (int j = 0; j < 4; ++j) acc[i][j] = 0.f;

    for (int k0 = 0; k0 < K; k0 += 16) {
        float4 av = make_float4(0.f, 0.f, 0.f, 0.f);
        if (tm0 + r < M) {
            if (TA_BF) {
                const unsigned short* A = (const unsigned short*)Av;
                ushort4 t = *(const ushort4*)&A[(size_t)(tm0 + r) * lda + k0 + kq * 4];
                av = make_float4(bf2f(t.x), bf2f(t.y), bf2f(t.z), bf2f(t.w));
            } else {
                const float* A = (const float*)Av;
                av = *(const float4*)&A[(size_t)(tm0 + r) * lda + k0 + kq * 4];
            }
        }
        As[kq * 4 + 0][r] = av.x;
        As[kq * 4 + 1][r] = av.y;
        As[kq * 4 + 2][r] = av.z;
        As[kq * 4 + 3][r] = av.w;

        float4 wv = make_float4(0.f, 0.f, 0.f, 0.f);
        if (tn0 + r < N)
            wv = *(const float4*)&W[(size_t)(tn0 + r) * ldw + k0 + kq * 4];
        Ws[kq * 4 + 0][r] = wv.x;
        Ws[kq * 4 + 1][r] = wv.y;
        Ws[kq * 4 + 2][r] = wv.z;
        Ws[kq * 4 + 3][r] = wv.w;

        __syncthreads();
#pragma unroll
        for (int kk = 0; kk < 16; ++kk) {
            const float4 a = *(const float4*)&As[kk][ty * 4];
            const float4 b = *(const float4*)&Ws[kk][tx * 4];
            acc[0][0] += a.x * b.x; acc[0][1] += a.x * b.y; acc[0][2] += a.x * b.z; acc[0][3] += a.x * b.w;
            acc[1][0] += a.y * b.x; acc[1][1] += a.y * b.y; acc[1][2] += a.y * b.z; acc[1][3] += a.y * b.w;
            acc[2][0] += a.z * b.x; acc[2][1] += a.z * b.y; acc[2][2] += a.z * b.z; acc[2][3] += a.z * b.w;
            acc[3][0] += a.w * b.x; acc[3][1] += a.w * b.y; acc[3][2] += a.w * b.z; acc[3][3] += a.w * b.w;
        }
        __syncthreads();
    }

#pragma unroll
    for (int i = 0; i < 4; ++i) {
        const int m = tm0 + ty * 4 + i;
        if (m >= M) continue;
#pragma unroll
        for (int j = 0; j < 4; ++j) {
            const int n = tn0 + tx * 4 + j;
            if (n >= N) continue;
            float v = acc[i][j];
            if (ACT == 1) {
                v += bias[n];
                if (v <= 20.f)
                    v = __builtin_amdgcn_logf(1.f + __builtin_amdgcn_exp2f(v * LOG2E)) * LN2;
            }
            const size_t idx = (size_t)m * ldc + n;
            if (TC_BF) ((unsigned short*)Cv)[idx] = f2bf(v);
            else       ((float*)Cv)[idx] = v;
        }
    }
}

// ---------------------------------------------------------------------------
__global__ __launch_bounds__(256) void cast_f32_bf16(
    const float* __restrict__ in, unsigned short* __restrict__ out, int n4)
{
    const int i = blockIdx.x * 256 + threadIdx.x;
    if (i >= n4) return;
    const float4 v = ((const float4*)in)[i];
    ushort4 o;
    o.x = f2bf(v.x); o.y = f2bf(v.y); o.z = f2bf(v.z); o.w = f2bf(v.w);
    ((ushort4*)out)[i] = o;
}

// ---------------------------------------------------------------------------
// Causal depthwise conv1d + SiLU on bf16. DIR=0: taps l-j; DIR=1: taps l+j.
// ---------------------------------------------------------------------------
template <int DIR>
__global__ __launch_bounds__(256) void conv_silu(
    const unsigned short* __restrict__ xz, const float* __restrict__ conv_w,
    const float* __restrict__ conv_b, unsigned short* __restrict__ uc)
{
    const int idx = blockIdx.x * 256 + threadIdx.x;
    if (idx >= NROWS * D_INNER) return;
    const int d = idx % D_INNER;
    const int row = idx / D_INNER;
    const int l = row % SEQ;

    float acc = conv_b[d];
#pragma unroll
    for (int j = 0; j < 4; ++j) {
        const int ll = DIR ? (l + j) : (l - j);
        if (ll >= 0 && ll < SEQ)
            acc = fmaf(bf2f(xz[(size_t)(row - l + ll) * NXZ + d]),
                       conv_w[d * 4 + (3 - j)], acc);
    }
    uc[idx] = f2bf(acc * fsigm(acc));
}

// ---------------------------------------------------------------------------
// Chunked selective scan. 16 lanes per channel, one state n per lane.
// Chunk c covers scan-steps [c*CL, (c+1)*CL).  Scan step t -> row
// l = DIR ? SEQ-1-t : t.  dt overlaid in xz u-half; pass2 overwrites it
// with y*silu(z) in place (read-before-write, own chunk rows only).
//
// pass1 (chunks 0..NCHUNK-2): h0=0, record F = local final state and
//        P = prod(dA) over the chunk.   (lean: no C/z, no shuffles)
// pass2 (all chunks): h0 = fold of (P,F) of preceding chunks, full scan.
// ---------------------------------------------------------------------------
struct SB1 { float dtv[8], uv[8], Bv[8]; };
struct SB2 { float dtv[8], uv[8], Bv[8], Cv[8]; };

template <long ST>
__device__ __forceinline__ void load1(
    SB1& s, const unsigned short* pdt, const unsigned short* pu,
    const float* pB, int t0)
{
#pragma unroll
    for (int j = 0; j < 8; ++j) {
        const long t = t0 + j;
        s.dtv[j] = bf2f(pdt[t * (ST * NXZ)]);
        s.uv[j]  = bf2f(pu [t * (ST * D_INNER)]);
        s.Bv[j]  =      pB [t * (ST * NDBC)];
    }
}

__device__ __forceinline__ void comp1(const SB1& s, float& h, float& P, float A2)
{
#pragma unroll
    for (int j = 0; j < 8; ++j) {
        const float dA = __builtin_amdgcn_exp2f(s.dtv[j] * A2);
        P *= dA;
        h = fmaf(dA, h, s.dtv[j] * s.uv[j] * s.Bv[j]);
    }
}

template <int DIR>
__global__ __launch_bounds__(256) void scan_pass1(
    const float* __restrict__ dtBC, const unsigned short* __restrict__ uc,
    const float* __restrict__ A_log, const unsigned short* __restrict__ xz,
    float* __restrict__ Fb, float* __restrict__ Pb)
{
    const int tid = threadIdx.x;
    const int n = tid & 15, g = tid >> 4;
    const int c   = blockIdx.x / NGRP;          // 0..NCHUNK-2
    const int grp = blockIdx.x - c * NGRP;
    const int ch = grp * 16 + g;
    const int b = ch / D_INNER, d = ch % D_INNER;

    const float A2 = -expf(A_log[d * D_STATE + n]) * LOG2E;
    const int l0 = DIR ? (SEQ - 1 - c * CL) : (c * CL);
    const size_t row0 = (size_t)b * SEQ + l0;
    constexpr long ST = DIR ? -1 : 1;

    const unsigned short* pdt = xz + row0 * NXZ + d;
    const unsigned short* pu  = uc + row0 * D_INNER + d;
    const float* pB = dtBC + row0 * NDBC + DT_RANK + n;

    float h = 0.f, P = 1.f;
    SB1 sa, sb;
    load1<ST>(sa, pdt, pu, pB, 0);
    for (int t0 = 0; t0 < CL; t0 += 16) {
        load1<ST>(sb, pdt, pu, pB, t0 + 8);
        comp1(sa, h, P, A2);
        if (t0 + 16 < CL)
            load1<ST>(sa, pdt, pu, pB, t0 + 16);
        comp1(sb, h, P, A2);
    }
    const size_t fi = ((size_t)c * NCH + ch) * 16 + n;
    Fb[fi] = h;
    Pb[fi] = P;
}

template <long ST>
__device__ __forceinline__ void load2(
    SB2& s, float& zv, const unsigned short* pdt, const unsigned short* pu,
    const float* pB, const float* pC, const unsigned short* pz, int t0, int n)
{
#pragma unroll
    for (int j = 0; j < 8; ++j) {
        const long t = t0 + j;
        s.dtv[j] = bf2f(pdt[t * (ST * NXZ)]);
        s.uv[j]  = bf2f(pu [t * (ST * D_INNER)]);
        s.Bv[j]  =      pB [t * (ST * NDBC)];
        s.Cv[j]  =      pC [t * (ST * NDBC)];
    }
    // lane n (n<8) grabs z for step t0+n (others load a dup, unused)
    zv = bf2f(pz[(long)(t0 + (n & 7)) * (ST * NXZ)]);
}

template <long ST>
__device__ __forceinline__ void comp2(
    const SB2& s, float zv, int t0, int n,
    float& h, float A2, float Dv, unsigned short* pout)
{
    float yk = 0.f;
#pragma unroll
    for (int j = 0; j < 8; ++j) {
        const float dtv = s.dtv[j];
        const float dA = __builtin_amdgcn_exp2f(dtv * A2);
        h = fmaf(dA, h, dtv * s.uv[j] * s.Bv[j]);
        float pp = h * s.Cv[j];
        pp += __shfl_xor(pp, 1, 16);
        pp += __shfl_xor(pp, 2, 16);
        pp += __shfl_xor(pp, 4, 16);
        pp += __shfl_xor(pp, 8, 16);
        const float y = fmaf(s.uv[j], Dv, pp);
        yk = (n == j) ? y : yk;         // lane j latches step j's y
    }
    if (n < 8)
        pout[(long)(t0 + n) * (ST * NXZ)] = f2bf(yk * (zv * fsigm(zv)));
}

template <int DIR>
__global__ __launch_bounds__(256) void scan_pass2(
    const float* __restrict__ dtBC, const unsigned short* __restrict__ uc,
    const float* __restrict__ A_log, const float* __restrict__ D_skip,
    unsigned short* __restrict__ xz,
    const float* __restrict__ Fb, const float* __restrict__ Pb)
{
    const int tid = threadIdx.x;
    const int n = tid & 15, g = tid >> 4;
    const int c   = blockIdx.x / NGRP;          // 0..NCHUNK-1
    const int grp = blockIdx.x - c * NGRP;
    const int ch = grp * 16 + g;
    const int b = ch / D_INNER, d = ch % D_INNER;

    const float A2 = -expf(A_log[d * D_STATE + n]) * LOG2E;
    const float Dv = D_skip[d];
    const int l0 = DIR ? (SEQ - 1 - c * CL) : (c * CL);
    const size_t row0 = (size_t)b * SEQ + l0;
    constexpr long ST = DIR ? -1 : 1;

    const unsigned short* pdt = xz + row0 * NXZ + d;
    const unsigned short* pz  = xz + row0 * NXZ + D_INNER + d;
    const unsigned short* pu  = uc + row0 * D_INNER + d;
    const float* pB = dtBC + row0 * NDBC + DT_RANK + n;
    const float* pC = pB + D_STATE;
    unsigned short* pout = xz + row0 * NXZ + d;

    // fold preceding chunks' (P, F) into the true initial state
    float h = 0.f;
    for (int cc = 0; cc < c; ++cc) {
        const size_t fi = ((size_t)cc * NCH + ch) * 16 + n;
        h = fmaf(Pb[fi], h, Fb[fi]);
    }

    SB2 sa, sb;
    float za, zb;
    load2<ST>(sa, za, pdt, pu, pB, pC, pz, 0, n);
    for (int t0 = 0; t0 < CL; t0 += 16) {
        load2<ST>(sb, zb, pdt, pu, pB, pC, pz, t0 + 8, n);
        comp2<ST>(sa, za, t0, n, h, A2, Dv, pout);
        if (t0 + 16 < CL)
            load2<ST>(sa, za, pdt, pu, pB, pC, pz, t0 + 16, n);
        comp2<ST>(sb, zb, t0 + 8, n, h, A2, Dv, pout);
    }
}

// ---------------------------------------------------------------------------
// In-place: out = LN(out + x) * g + b   (out already holds out_f + out_b)
// ---------------------------------------------------------------------------
__global__ __launch_bounds__(256) void fuse_ln(
    float* __restrict__ out, const float* __restrict__ x,
    const float* __restrict__ g, const float* __restrict__ bta)
{
    const int row = blockIdx.x;
    const size_t base = (size_t)row * D_MODEL;
    float vals[3];
    float s = 0.f, s2 = 0.f;
#pragma unroll
    for (int i = 0; i < 3; ++i) {
        const int c = threadIdx.x + i * 256;
        const float v = out[base + c] + x[base + c];
        vals[i] = v;
        s += v;
        s2 += v * v;
    }
#pragma unroll
    for (int o = 32; o >= 1; o >>= 1) {
        s  += __shfl_xor(s, o, 64);
        s2 += __shfl_xor(s2, o, 64);
    }
    __shared__ float ls[4], ls2[4];
    const int wid = threadIdx.x >> 6;
    if ((threadIdx.x & 63) == 0) { ls[wid] = s; ls2[wid] = s2; }
    __syncthreads();
    s  = ls[0] + ls[1] + ls[2] + ls[3];
    s2 = ls2[0] + ls2[1] + ls2[2] + ls2[3];
    const float mu  = s * (1.f / D_MODEL);
    const float var = s2 * (1.f / D_MODEL) - mu * mu;
    const float inv = 1.f / sqrtf(var + 1e-12f);
#pragma unroll
    for (int i = 0; i < 3; ++i) {
        const int c = threadIdx.x + i * 256;
        out[base + c] = (vals[i] - mu) * inv * g[c] + bta[c];
    }
}

// ---------------------------------------------------------------------------
extern "C" void kernel_launch(void* const* d_in, const int* in_sizes, int n_in,
                              void* d_out, int out_size, void* d_ws, size_t ws_size,
                              hipStream_t stream)
{
    const float* x = (const float*)d_in[0];
    const float* ln_g = (const float*)d_in[19];
    const float* ln_b = (const float*)d_in[20];

    // workspace layout (~193 MB total)
    float* dtBC = (float*)d_ws;                                   //  5.24 MB fp32
    unsigned short* xz  = (unsigned short*)(dtBC + (size_t)NROWS * NDBC);  // 100.7 MB bf16
    unsigned short* uc  = xz + (size_t)NROWS * NXZ;               // 50.3 MB bf16
    unsigned short* xbf = uc + (size_t)NROWS * D_INNER;           // 25.2 MB bf16
    unsigned short* wbf_in  = xbf + (size_t)NROWS * D_MODEL;      //  4.7 MB bf16
    unsigned short* wbf_out = wbf_in + (size_t)NXZ * D_MODEL;     //  2.4 MB bf16
    float* Fb = (float*)(wbf_out + (size_t)D_MODEL * D_INNER);    //  2.36 MB fp32
    float* Pb = Fb + (size_t)(NCHUNK - 1) * NCH * 16;             //  2.36 MB fp32
    const size_t needed = ((size_t)NROWS * NDBC) * 4
        + ((size_t)NROWS * NXZ + (size_t)NROWS * D_INNER + (size_t)NROWS * D_MODEL
           + (size_t)NXZ * D_MODEL + (size_t)D_MODEL * D_INNER) * 2
        + (size_t)(NCHUNK - 1) * NCH * 16 * 4 * 2;
    if (ws_size < needed) return;  // fail absmax cleanly instead of faulting

    float* outp = (float*)d_out;   // fp32 accumulator for out_f + out_b

    // x -> bf16 once
    cast_f32_bf16<<<(NROWS * D_MODEL / 4 + 255) / 256, 256, 0, stream>>>(
        x, xbf, NROWS * D_MODEL / 4);

    for (int dir = 0; dir < 2; ++dir) {
        const float* in_w    = (const float*)d_in[1 + dir * 9 + 0];
        const float* conv_w  = (const float*)d_in[1 + dir * 9 + 1];
        const float* conv_b  = (const float*)d_in[1 + dir * 9 + 2];
        const float* xproj_w = (const float*)d_in[1 + dir * 9 + 3];
        const float* dt_w    = (const float*)d_in[1 + dir * 9 + 4];
        const float* dt_b    = (const float*)d_in[1 + dir * 9 + 5];
        const float* A_log   = (const float*)d_in[1 + dir * 9 + 6];
        const float* D_skip  = (const float*)d_in[1 + dir * 9 + 7];
        const float* out_w   = (const float*)d_in[1 + dir * 9 + 8];

        // weights -> bf16
        cast_f32_bf16<<<(NXZ * D_MODEL / 4 + 255) / 256, 256, 0, stream>>>(
            in_w, wbf_in, NXZ * D_MODEL / 4);
        cast_f32_bf16<<<(D_MODEL * D_INNER / 4 + 255) / 256, 256, 0, stream>>>(
            out_w, wbf_out, D_MODEL * D_INNER / 4);

        // xz = x @ in_w^T  (16384 x 3072, K=768)  MFMA -> bf16
        gemm_mfma<1, 0><<<dim3(NXZ / 128, NROWS / 128), 256, 0, stream>>>(
            xbf, D_MODEL, wbf_in, D_MODEL, xz, NXZ, NXZ, D_MODEL);

        // uc = silu(conv(u) + b)
        if (dir == 0)
            conv_silu<0><<<(NROWS * D_INNER + 255) / 256, 256, 0, stream>>>(
                xz, conv_w, conv_b, uc);
        else
            conv_silu<1><<<(NROWS * D_INNER + 255) / 256, 256, 0, stream>>>(
                xz, conv_w, conv_b, uc);

        // dtBC = uc @ xproj_w^T   (16384 x 80, K=1536)  bf16 A -> fp32 C
        gemm_nt<1, 0, 0><<<dim3((NDBC + 63) / 64, NROWS / 64), 256, 0, stream>>>(
            uc, D_INNER, xproj_w, D_INNER, nullptr, dtBC, NDBC, NROWS, NDBC, D_INNER);

        // dt = softplus(dtBC[:, :48] @ dt_w^T + dt_b) -> overlay in xz u-half
        gemm_nt<0, 1, 1><<<dim3(D_INNER / 64, NROWS / 64), 256, 0, stream>>>(
            dtBC, NDBC, dt_w, DT_RANK, dt_b, xz, NXZ, NROWS, D_INNER, DT_RANK);

        // chunked selective scan
        if (dir == 0) {
            scan_pass1<0><<<(NCHUNK - 1) * NGRP, 256, 0, stream>>>(
                dtBC, uc, A_log, xz, Fb, Pb);
            scan_pass2<0><<<NCHUNK * NGRP, 256, 0, stream>>>(
                dtBC, uc, A_log, D_skip, xz, Fb, Pb);
        } else {
            scan_pass1<1><<<(NCHUNK - 1) * NGRP, 256, 0, stream>>>(
                dtBC, uc, A_log, xz, Fb, Pb);
            scan_pass2<1><<<NCHUNK * NGRP, 256, 0, stream>>>(
                dtBC, uc, A_log, D_skip, xz, Fb, Pb);
        }

        // outp (+)= y' @ out_w^T   (16384 x 768, K=1536)  MFMA -> fp32
        if (dir == 0)
            gemm_mfma<0, 0><<<dim3(D_MODEL / 128, NROWS / 128), 256, 0, stream>>>(
                xz, NXZ, wbf_out, D_INNER, outp, D_MODEL, D_MODEL, D_INNER);
        else
            gemm_mfma<0, 1><<<dim3(D_MODEL / 128, NROWS / 128), 256, 0, stream>>>(
                xz, NXZ, wbf_out, D_INNER, outp, D_MODEL, D_MODEL, D_INNER);
    }

    fuse_ln<<<NROWS, 256, 0, stream>>>(outp, x, ln_g, ln_b);
}

// Round 6
// 1874.137 us; speedup vs baseline: 2.9123x; 1.0084x over previous
//
#include <hip/hip_runtime.h>
#include <math.h>

#define D_MODEL 768
#define D_INNER 1536
#define D_STATE 16
#define DCONV 4
#define DT_RANK 48
#define BATCH 8
#define SEQ 2048
#define NROWS (BATCH * SEQ)          // 16384
#define NXZ (2 * D_INNER)            // 3072
#define NDBC (DT_RANK + 2 * D_STATE) // 80

#define NCHUNK 4
#define CL (SEQ / NCHUNK)            // 512
#define NCH (BATCH * D_INNER)        // 12288 channels
#define NGRP (NCH / 16)              // 768 channel-groups (16 ch/block)

#define LOG2E 1.4426950408889634f
#define LN2   0.6931471805599453f

typedef __attribute__((ext_vector_type(8))) short bh8;            // MFMA A/B frag
typedef __attribute__((ext_vector_type(4))) float f4;             // MFMA acc / f32x4
typedef __attribute__((ext_vector_type(8))) unsigned short us8;   // 8 bf16 = 16B

__device__ __forceinline__ float bf2f(unsigned short u) {
    return __uint_as_float(((unsigned int)u) << 16);
}
__device__ __forceinline__ unsigned short f2bf(float f) {
    unsigned int x = __float_as_uint(f);
    return (unsigned short)((x + 0x7fffu + ((x >> 16) & 1u)) >> 16);
}
__device__ __forceinline__ float fsigm(float x) {
    return __builtin_amdgcn_rcpf(1.f + __builtin_amdgcn_exp2f(-x * LOG2E));
}

#define GLL16(gp, lp) __builtin_amdgcn_global_load_lds( \
    (const __attribute__((address_space(1))) void*)(gp), \
    (__attribute__((address_space(3))) void*)(lp), 16, 0, 0)

// ---------------------------------------------------------------------------
// bf16 MFMA GEMM (NT): C(MxN fp32) = A(MxK) @ W(NxK)^T  [+C if ACC]
// 128x128 tile, BK=32, 4 waves. Used for out_proj.
// ---------------------------------------------------------------------------
template <int ACC>
__global__ __launch_bounds__(256) void gemm_mfma(
    const unsigned short* __restrict__ A, int lda,
    const unsigned short* __restrict__ W, int ldw,
    float* __restrict__ C, int ldc, int K)
{
    __shared__ unsigned short As[128 * 32];
    __shared__ unsigned short Bs[128 * 32];
    const int tid = threadIdx.x;
    const int w = tid >> 6;
    const int l = tid & 63;
    const int wr = w >> 1, wc = w & 1;
    const int tm0 = blockIdx.y * 128;
    const int tn0 = blockIdx.x * 128;

    const int srow = (w << 4) + (l >> 2);
    const int scol = (l & 3) * 8;
    unsigned short* ldsA0 = &As[(w << 4) * 32];
    unsigned short* ldsA1 = &As[(64 + (w << 4)) * 32];
    unsigned short* ldsB0 = &Bs[(w << 4) * 32];
    unsigned short* ldsB1 = &Bs[(64 + (w << 4)) * 32];
    const unsigned short* gA0 = A + (size_t)(tm0 + srow) * lda + scol;
    const unsigned short* gA1 = A + (size_t)(tm0 + 64 + srow) * lda + scol;
    const unsigned short* gB0 = W + (size_t)(tn0 + srow) * ldw + scol;
    const unsigned short* gB1 = W + (size_t)(tn0 + 64 + srow) * ldw + scol;

    const int aoff = ((wr << 6) + (l & 15)) * 32 + ((l >> 4) << 3);
    const int boff = ((wc << 6) + (l & 15)) * 32 + ((l >> 4) << 3);

    f4 acc[4][4];
#pragma unroll
    for (int i = 0; i < 4; ++i)
#pragma unroll
        for (int j = 0; j < 4; ++j) acc[i][j] = 0.f;

    for (int k0 = 0; k0 < K; k0 += 32) {
        GLL16(gA0 + k0, ldsA0);
        GLL16(gA1 + k0, ldsA1);
        GLL16(gB0 + k0, ldsB0);
        GLL16(gB1 + k0, ldsB1);
        __syncthreads();
        bh8 af[4], bf[4];
#pragma unroll
        for (int mi = 0; mi < 4; ++mi) af[mi] = *(const bh8*)&As[aoff + mi * 512];
#pragma unroll
        for (int ni = 0; ni < 4; ++ni) bf[ni] = *(const bh8*)&Bs[boff + ni * 512];
#pragma unroll
        for (int mi = 0; mi < 4; ++mi)
#pragma unroll
            for (int ni = 0; ni < 4; ++ni)
                acc[mi][ni] = __builtin_amdgcn_mfma_f32_16x16x32_bf16(
                    af[mi], bf[ni], acc[mi][ni], 0, 0, 0);
        __syncthreads();
    }

    const int crow0 = tm0 + (wr << 6) + ((l >> 4) << 2);
    const int ccol0 = tn0 + (wc << 6) + (l & 15);
#pragma unroll
    for (int mi = 0; mi < 4; ++mi)
#pragma unroll
        for (int ni = 0; ni < 4; ++ni)
#pragma unroll
            for (int r = 0; r < 4; ++r) {
                const size_t idx = (size_t)(crow0 + mi * 16 + r) * ldc
                                 + (ccol0 + ni * 16);
                C[idx] = ACC ? (C[idx] + acc[mi][ni][r]) : acc[mi][ni][r];
            }
}

// ---------------------------------------------------------------------------
// bf16 MFMA GEMM (NT) with TRANSPOSED bf16 store: Ct[N][NROWS] = (A@W^T)^T.
// LDS bounce in 4 col-windows of 32. Used for in_proj -> xz_T.
// ---------------------------------------------------------------------------
__global__ __launch_bounds__(256) void gemm_mfma_tr(
    const unsigned short* __restrict__ A, int lda,
    const unsigned short* __restrict__ W, int ldw,
    unsigned short* __restrict__ Ct, int K)
{
    __shared__ unsigned short As[128 * 32];
    __shared__ unsigned short Bs[128 * 32];
    __shared__ unsigned short tr[32 * 136];
    const int tid = threadIdx.x;
    const int w = tid >> 6;
    const int l = tid & 63;
    const int wr = w >> 1, wc = w & 1;
    const int tm0 = blockIdx.y * 128;   // row block (M)
    const int tn0 = blockIdx.x * 128;   // col block (N)

    const int srow = (w << 4) + (l >> 2);
    const int scol = (l & 3) * 8;
    unsigned short* ldsA0 = &As[(w << 4) * 32];
    unsigned short* ldsA1 = &As[(64 + (w << 4)) * 32];
    unsigned short* ldsB0 = &Bs[(w << 4) * 32];
    unsigned short* ldsB1 = &Bs[(64 + (w << 4)) * 32];
    const unsigned short* gA0 = A + (size_t)(tm0 + srow) * lda + scol;
    const unsigned short* gA1 = A + (size_t)(tm0 + 64 + srow) * lda + scol;
    const unsigned short* gB0 = W + (size_t)(tn0 + srow) * ldw + scol;
    const unsigned short* gB1 = W + (size_t)(tn0 + 64 + srow) * ldw + scol;

    const int aoff = ((wr << 6) + (l & 15)) * 32 + ((l >> 4) << 3);
    const int boff = ((wc << 6) + (l & 15)) * 32 + ((l >> 4) << 3);

    f4 acc[4][4];
#pragma unroll
    for (int i = 0; i < 4; ++i)
#pragma unroll
        for (int j = 0; j < 4; ++j) acc[i][j] = 0.f;

    for (int k0 = 0; k0 < K; k0 += 32) {
        GLL16(gA0 + k0, ldsA0);
        GLL16(gA1 + k0, ldsA1);
        GLL16(gB0 + k0, ldsB0);
        GLL16(gB1 + k0, ldsB1);
        __syncthreads();
        bh8 af[4], bf[4];
#pragma unroll
        for (int mi = 0; mi < 4; ++mi) af[mi] = *(const bh8*)&As[aoff + mi * 512];
#pragma unroll
        for (int ni = 0; ni < 4; ++ni) bf[ni] = *(const bh8*)&Bs[boff + ni * 512];
#pragma unroll
        for (int mi = 0; mi < 4; ++mi)
#pragma unroll
            for (int ni = 0; ni < 4; ++ni)
                acc[mi][ni] = __builtin_amdgcn_mfma_f32_16x16x32_bf16(
                    af[mi], bf[ni], acc[mi][ni], 0, 0, 0);
        __syncthreads();
    }

    // transposed epilogue: 4 passes over 32-col windows
    const int rowL0 = (wr << 6) + ((l >> 4) << 2);
#pragma unroll
    for (int p = 0; p < 4; ++p) {
        if (wc == (p >> 1)) {
#pragma unroll
            for (int nn = 0; nn < 2; ++nn) {
                const int ni = (p & 1) * 2 + nn;
                const int colW = nn * 16 + (l & 15);
#pragma unroll
                for (int mi = 0; mi < 4; ++mi)
#pragma unroll
                    for (int r = 0; r < 4; ++r)
                        tr[colW * 136 + rowL0 + mi * 16 + r] = f2bf(acc[mi][ni][r]);
            }
        }
        __syncthreads();
        {
            const int col = tid >> 3, seg = tid & 7;
            us8 v0 = *(const us8*)&tr[col * 136 + seg * 16];
            us8 v1 = *(const us8*)&tr[col * 136 + seg * 16 + 8];
            const size_t dst = (size_t)(tn0 + p * 32 + col) * NROWS + tm0 + seg * 16;
            *(us8*)(Ct + dst) = v0;
            *(us8*)(Ct + dst + 8) = v1;
        }
        __syncthreads();
    }
}

// ---------------------------------------------------------------------------
// Vector GEMM (NN over K-major W): C[M][N] = act(A[M][K] @ Wk[K][N] [+bias_m])
// A fp32 row-major. Wk bf16 (WK_BF) or fp32, ldk = row stride of Wk.
// ACT 1: softplus(x + bias[m]). TC_BF: bf16 C. N must be mult of 64.
// ---------------------------------------------------------------------------
template <int WK_BF, int ACT, int TC_BF>
__global__ __launch_bounds__(256) void gemm_nn(
    const float* __restrict__ A, int lda,
    const void* __restrict__ Wkv, size_t ldk,
    const float* __restrict__ bias,
    void* __restrict__ Cv, size_t ldc,
    int M, int K)
{
    __shared__ float As[16][68];
    __shared__ float Ws[16][68];
    const int tid = threadIdx.x;
    const int tx = tid & 15;
    const int ty = tid >> 4;
    const int tn0 = blockIdx.x * 64;
    const int tm0 = blockIdx.y * 64;
    const int r  = tid >> 2;      // A-row to load
    const int kq = tid & 3;       // A k-quad
    const int kk = tid >> 4;      // W k-row
    const int nq = tid & 15;      // W n-quad

    float acc[4][4];
#pragma unroll
    for (int i = 0; i < 4; ++i)
#pragma unroll
        for (int j = 0; j < 4; ++j) acc[i][j] = 0.f;

    for (int k0 = 0; k0 < K; k0 += 16) {
        float4 av = make_float4(0.f, 0.f, 0.f, 0.f);
        if (tm0 + r < M)
            av = *(const float4*)&A[(size_t)(tm0 + r) * lda + k0 + kq * 4];
        As[kq * 4 + 0][r] = av.x;
        As[kq * 4 + 1][r] = av.y;
        As[kq * 4 + 2][r] = av.z;
        As[kq * 4 + 3][r] = av.w;

        if (WK_BF) {
            const unsigned short* Wk = (const unsigned short*)Wkv;
            ushort4 t = *(const ushort4*)&Wk[(size_t)(k0 + kk) * ldk + tn0 + nq * 4];
            Ws[kk][nq * 4 + 0] = bf2f(t.x);
            Ws[kk][nq * 4 + 1] = bf2f(t.y);
            Ws[kk][nq * 4 + 2] = bf2f(t.z);
            Ws[kk][nq * 4 + 3] = bf2f(t.w);
        } else {
            const float* Wk = (const float*)Wkv;
            float4 t = *(const float4*)&Wk[(size_t)(k0 + kk) * ldk + tn0 + nq * 4];
            Ws[kk][nq * 4 + 0] = t.x;
            Ws[kk][nq * 4 + 1] = t.y;
            Ws[kk][nq * 4 + 2] = t.z;
            Ws[kk][nq * 4 + 3] = t.w;
        }

        __syncthreads();
#pragma unroll
        for (int kx = 0; kx < 16; ++kx) {
            const float4 a = *(const float4*)&As[kx][ty * 4];
            const float4 b = *(const float4*)&Ws[kx][tx * 4];
            acc[0][0] += a.x * b.x; acc[0][1] += a.x * b.y; acc[0][2] += a.x * b.z; acc[0][3] += a.x * b.w;
            acc[1][0] += a.y * b.x; acc[1][1] += a.y * b.y; acc[1][2] += a.y * b.z; acc[1][3] += a.y * b.w;
            acc[2][0] += a.z * b.x; acc[2][1] += a.z * b.y; acc[2][2] += a.z * b.z; acc[2][3] += a.z * b.w;
            acc[3][0] += a.w * b.x; acc[3][1] += a.w * b.y; acc[3][2] += a.w * b.z; acc[3][3] += a.w * b.w;
        }
        __syncthreads();
    }

#pragma unroll
    for (int i = 0; i < 4; ++i) {
        const int m = tm0 + ty * 4 + i;
        if (m >= M) continue;
        float v[4];
#pragma unroll
        for (int j = 0; j < 4; ++j) {
            v[j] = acc[i][j];
            if (ACT == 1) {
                v[j] += bias[m];
                if (v[j] <= 20.f)
                    v[j] = __builtin_amdgcn_logf(1.f + __builtin_amdgcn_exp2f(v[j] * LOG2E)) * LN2;
            }
        }
        const size_t idx = (size_t)m * ldc + tn0 + tx * 4;
        if (TC_BF) {
            ushort4 o;
            o.x = f2bf(v[0]); o.y = f2bf(v[1]); o.z = f2bf(v[2]); o.w = f2bf(v[3]);
            *(ushort4*)&((unsigned short*)Cv)[idx] = o;
        } else {
            *(float4*)&((float*)Cv)[idx] = make_float4(v[0], v[1], v[2], v[3]);
        }
    }
}

// ---------------------------------------------------------------------------
__global__ __launch_bounds__(256) void cast_f32_bf16(
    const float* __restrict__ in, unsigned short* __restrict__ out, int n4)
{
    const int i = blockIdx.x * 256 + threadIdx.x;
    if (i >= n4) return;
    const float4 v = ((const float4*)in)[i];
    ushort4 o;
    o.x = f2bf(v.x); o.y = f2bf(v.y); o.z = f2bf(v.z); o.w = f2bf(v.w);
    ((ushort4*)out)[i] = o;
}

// ---------------------------------------------------------------------------
// Depthwise causal conv + SiLU on time-major layout. One block per (d,b),
// thread handles 8 consecutive t. DIR=0: taps t-j; DIR=1: taps t+j (w[3-j]).
// ---------------------------------------------------------------------------
template <int DIR>
__global__ __launch_bounds__(256) void conv_t(
    const unsigned short* __restrict__ xzT, const float* __restrict__ conv_w,
    const float* __restrict__ conv_b, unsigned short* __restrict__ ucT)
{
    const int bd = blockIdx.x;            // 0..NCH-1
    const int d = bd >> 3, b = bd & 7;
    const int t0 = threadIdx.x * 8;
    const size_t base = (size_t)d * NROWS + (size_t)b * SEQ;
    const float w0 = conv_w[d * 4 + 0], w1 = conv_w[d * 4 + 1];
    const float w2 = conv_w[d * 4 + 2], w3 = conv_w[d * 4 + 3];
    const float cb = conv_b[d];

    const us8 cur = *(const us8*)(xzT + base + t0);
    float u[11];
    us8 o;
    if (DIR == 0) {
        us8 prev = (us8)0;
        if (t0 > 0) prev = *(const us8*)(xzT + base + t0 - 8);
        u[0] = bf2f(prev[5]); u[1] = bf2f(prev[6]); u[2] = bf2f(prev[7]);
#pragma unroll
        for (int j = 0; j < 8; ++j) u[3 + j] = bf2f(cur[j]);
#pragma unroll
        for (int j = 0; j < 8; ++j) {
            float a = cb;
            a = fmaf(u[j],     w0, a);
            a = fmaf(u[j + 1], w1, a);
            a = fmaf(u[j + 2], w2, a);
            a = fmaf(u[j + 3], w3, a);
            o[j] = f2bf(a * fsigm(a));
        }
    } else {
        us8 nxt = (us8)0;
        if (t0 + 8 < SEQ) nxt = *(const us8*)(xzT + base + t0 + 8);
#pragma unroll
        for (int j = 0; j < 8; ++j) u[j] = bf2f(cur[j]);
        u[8] = bf2f(nxt[0]); u[9] = bf2f(nxt[1]); u[10] = bf2f(nxt[2]);
#pragma unroll
        for (int j = 0; j < 8; ++j) {
            float a = cb;
            a = fmaf(u[j],     w3, a);
            a = fmaf(u[j + 1], w2, a);
            a = fmaf(u[j + 2], w1, a);
            a = fmaf(u[j + 3], w0, a);
            o[j] = f2bf(a * fsigm(a));
        }
    }
    *(us8*)(ucT + base + t0) = o;
}

// ---------------------------------------------------------------------------
// Chunked selective scan on time-major layout. 16 lanes/channel (state n per
// lane). All streams contiguous in t -> vector loads (reversed for DIR=1).
// ---------------------------------------------------------------------------
struct SB1 { float dtv[8], uv[8], Bv[8]; };
struct SB2 { float dtv[8], uv[8], Bv[8], Cv[8], zv; };

template <int DIR>
__device__ __forceinline__ void load1(
    SB1& s, const unsigned short* pdt, const unsigned short* pu,
    const float* pB, int t0)
{
    if (DIR == 0) {
        const us8 vd = *(const us8*)(pdt + t0);
        const us8 vu = *(const us8*)(pu + t0);
        const f4 b0 = *(const f4*)(pB + t0);
        const f4 b1 = *(const f4*)(pB + t0 + 4);
#pragma unroll
        for (int j = 0; j < 8; ++j) {
            s.dtv[j] = bf2f(vd[j]);
            s.uv[j]  = bf2f(vu[j]);
            s.Bv[j]  = (j < 4) ? b0[j] : b1[j - 4];
        }
    } else {
        const us8 vd = *(const us8*)(pdt - t0 - 7);
        const us8 vu = *(const us8*)(pu - t0 - 7);
        const f4 b0 = *(const f4*)(pB - t0 - 7);
        const f4 b1 = *(const f4*)(pB - t0 - 3);
#pragma unroll
        for (int j = 0; j < 8; ++j) {
            s.dtv[j] = bf2f(vd[7 - j]);
            s.uv[j]  = bf2f(vu[7 - j]);
            s.Bv[j]  = (j < 4) ? b1[3 - j] : b0[7 - j];
        }
    }
}

__device__ __forceinline__ void comp1(const SB1& s, float& h, float& P, float A2)
{
#pragma unroll
    for (int j = 0; j < 8; ++j) {
        const float dA = __builtin_amdgcn_exp2f(s.dtv[j] * A2);
        P *= dA;
        h = fmaf(dA, h, s.dtv[j] * s.uv[j] * s.Bv[j]);
    }
}

template <int DIR>
__global__ __launch_bounds__(256) void scan_pass1(
    const float* __restrict__ dtBCT, const unsigned short* __restrict__ ucT,
    const float* __restrict__ A_log, const unsigned short* __restrict__ xzT,
    float* __restrict__ Fb, float* __restrict__ Pb)
{
    const int tid = threadIdx.x;
    const int n = tid & 15, g = tid >> 4;
    const int c   = blockIdx.x / NGRP;          // 0..NCHUNK-2
    const int grp = blockIdx.x - c * NGRP;
    const int ch = grp * 16 + g;
    const int b = ch / D_INNER, d = ch % D_INNER;

    const float A2 = -expf(A_log[d * D_STATE + n]) * LOG2E;
    const long l0 = DIR ? (SEQ - 1 - c * CL) : (c * CL);
    const size_t base = (size_t)b * SEQ + l0;

    const unsigned short* pdt = xzT + (size_t)d * NROWS + base;
    const unsigned short* pu  = ucT + (size_t)d * NROWS + base;
    const float* pB = dtBCT + (size_t)(DT_RANK + n) * NROWS + base;

    float h = 0.f, P = 1.f;
    SB1 sa, sb;
    load1<DIR>(sa, pdt, pu, pB, 0);
    for (int t0 = 0; t0 < CL; t0 += 16) {
        load1<DIR>(sb, pdt, pu, pB, t0 + 8);
        comp1(sa, h, P, A2);
        if (t0 + 16 < CL)
            load1<DIR>(sa, pdt, pu, pB, t0 + 16);
        comp1(sb, h, P, A2);
    }
    const size_t fi = ((size_t)c * NCH + ch) * 16 + n;
    Fb[fi] = h;
    Pb[fi] = P;
}

template <int DIR>
__device__ __forceinline__ void load2(
    SB2& s, const unsigned short* pdt, const unsigned short* pu,
    const float* pB, const float* pC, const unsigned short* pz, int t0, int n)
{
    if (DIR == 0) {
        const us8 vd = *(const us8*)(pdt + t0);
        const us8 vu = *(const us8*)(pu + t0);
        const f4 b0 = *(const f4*)(pB + t0);
        const f4 b1 = *(const f4*)(pB + t0 + 4);
        const f4 c0 = *(const f4*)(pC + t0);
        const f4 c1 = *(const f4*)(pC + t0 + 4);
#pragma unroll
        for (int j = 0; j < 8; ++j) {
            s.dtv[j] = bf2f(vd[j]);
            s.uv[j]  = bf2f(vu[j]);
            s.Bv[j]  = (j < 4) ? b0[j] : b1[j - 4];
            s.Cv[j]  = (j < 4) ? c0[j] : c1[j - 4];
        }
        s.zv = bf2f(pz[t0 + (n & 7)]);
    } else {
        const us8 vd = *(const us8*)(pdt - t0 - 7);
        const us8 vu = *(const us8*)(pu - t0 - 7);
        const f4 b0 = *(const f4*)(pB - t0 - 7);
        const f4 b1 = *(const f4*)(pB - t0 - 3);
        const f4 c0 = *(const f4*)(pC - t0 - 7);
        const f4 c1 = *(const f4*)(pC - t0 - 3);
#pragma unroll
        for (int j = 0; j < 8; ++j) {
            s.dtv[j] = bf2f(vd[7 - j]);
            s.uv[j]  = bf2f(vu[7 - j]);
            s.Bv[j]  = (j < 4) ? b1[3 - j] : b0[7 - j];
            s.Cv[j]  = (j < 4) ? c1[3 - j] : c0[7 - j];
        }
        s.zv = bf2f(pz[-(t0 + (n & 7))]);
    }
}

template <int DIR>
__device__ __forceinline__ void comp2(
    const SB2& s, int t0, int n,
    float& h, float A2, float Dv, unsigned short* pout)
{
    float yk = 0.f;
#pragma unroll
    for (int j = 0; j < 8; ++j) {
        const float dtv = s.dtv[j];
        const float dA = __builtin_amdgcn_exp2f(dtv * A2);
        h = fmaf(dA, h, dtv * s.uv[j] * s.Bv[j]);
        float pp = h * s.Cv[j];
        pp += __shfl_xor(pp, 1, 16);
        pp += __shfl_xor(pp, 2, 16);
        pp += __shfl_xor(pp, 4, 16);
        pp += __shfl_xor(pp, 8, 16);
        const float y = fmaf(s.uv[j], Dv, pp);
        yk = (n == j) ? y : yk;
    }
    if (n < 8) {
        const float sz = s.zv * fsigm(s.zv);
        const long off = DIR ? -(long)(t0 + n) : (long)(t0 + n);
        pout[off] = f2bf(yk * sz);
    }
}

template <int DIR>
__global__ __launch_bounds__(256) void scan_pass2(
    const float* __restrict__ dtBCT, const unsigned short* __restrict__ ucT,
    const float* __restrict__ A_log, const float* __restrict__ D_skip,
    unsigned short* __restrict__ xzT,
    const float* __restrict__ Fb, const float* __restrict__ Pb)
{
    const int tid = threadIdx.x;
    const int n = tid & 15, g = tid >> 4;
    const int c   = blockIdx.x / NGRP;          // 0..NCHUNK-1
    const int grp = blockIdx.x - c * NGRP;
    const int ch = grp * 16 + g;
    const int b = ch / D_INNER, d = ch % D_INNER;

    const float A2 = -expf(A_log[d * D_STATE + n]) * LOG2E;
    const float Dv = D_skip[d];
    const long l0 = DIR ? (SEQ - 1 - c * CL) : (c * CL);
    const size_t base = (size_t)b * SEQ + l0;

    const unsigned short* pdt = xzT + (size_t)d * NROWS + base;
    const unsigned short* pz  = xzT + (size_t)(D_INNER + d) * NROWS + base;
    const unsigned short* pu  = ucT + (size_t)d * NROWS + base;
    const float* pB = dtBCT + (size_t)(DT_RANK + n) * NROWS + base;
    const float* pC = dtBCT + (size_t)(DT_RANK + D_STATE + n) * NROWS + base;
    unsigned short* pout = xzT + (size_t)d * NROWS + base;

    float h = 0.f;
    for (int cc = 0; cc < c; ++cc) {
        const size_t fi = ((size_t)cc * NCH + ch) * 16 + n;
        h = fmaf(Pb[fi], h, Fb[fi]);
    }

    SB2 sa, sb;
    load2<DIR>(sa, pdt, pu, pB, pC, pz, 0, n);
    for (int t0 = 0; t0 < CL; t0 += 16) {
        load2<DIR>(sb, pdt, pu, pB, pC, pz, t0 + 8, n);
        comp2<DIR>(sa, t0, n, h, A2, Dv, pout);
        if (t0 + 16 < CL)
            load2<DIR>(sa, pdt, pu, pB, pC, pz, t0 + 16, n);
        comp2<DIR>(sb, t0 + 8, n, h, A2, Dv, pout);
    }
}

// ---------------------------------------------------------------------------
// 64x64 LDS tile transpose: in [1536][NROWS] bf16 -> out [NROWS][1536] bf16.
// ---------------------------------------------------------------------------
__global__ __launch_bounds__(256) void transpose_bf16(
    const unsigned short* __restrict__ in, unsigned short* __restrict__ out)
{
    __shared__ unsigned short tile[64][72];
    const int r0 = blockIdx.x * 64;
    const int d0 = blockIdx.y * 64;
    const int tid = threadIdx.x;
    {
        const int dd = tid >> 2;
        const int rq = (tid & 3) * 16;
        const size_t src = (size_t)(d0 + dd) * NROWS + r0 + rq;
        *(us8*)&tile[dd][rq]     = *(const us8*)(in + src);
        *(us8*)&tile[dd][rq + 8] = *(const us8*)(in + src + 8);
    }
    __syncthreads();
    {
        const int rr = tid >> 2;
        const int dq = (tid & 3) * 16;
        us8 o0, o1;
#pragma unroll
        for (int i = 0; i < 8; ++i) {
            o0[i] = tile[dq + i][rr];
            o1[i] = tile[dq + 8 + i][rr];
        }
        const size_t dst = (size_t)(r0 + rr) * D_INNER + d0 + dq;
        *(us8*)(out + dst)     = o0;
        *(us8*)(out + dst + 8) = o1;
    }
}

// ---------------------------------------------------------------------------
// In-place: out = LN(out + x) * g + b
// ---------------------------------------------------------------------------
__global__ __launch_bounds__(256) void fuse_ln(
    float* __restrict__ out, const float* __restrict__ x,
    const float* __restrict__ g, const float* __restrict__ bta)
{
    const int row = blockIdx.x;
    const size_t base = (size_t)row * D_MODEL;
    float vals[3];
    float s = 0.f, s2 = 0.f;
#pragma unroll
    for (int i = 0; i < 3; ++i) {
        const int c = threadIdx.x + i * 256;
        const float v = out[base + c] + x[base + c];
        vals[i] = v;
        s += v;
        s2 += v * v;
    }
#pragma unroll
    for (int o = 32; o >= 1; o >>= 1) {
        s  += __shfl_xor(s, o, 64);
        s2 += __shfl_xor(s2, o, 64);
    }
    __shared__ float ls[4], ls2[4];
    const int wid = threadIdx.x >> 6;
    if ((threadIdx.x & 63) == 0) { ls[wid] = s; ls2[wid] = s2; }
    __syncthreads();
    s  = ls[0] + ls[1] + ls[2] + ls[3];
    s2 = ls2[0] + ls2[1] + ls2[2] + ls2[3];
    const float mu  = s * (1.f / D_MODEL);
    const float var = s2 * (1.f / D_MODEL) - mu * mu;
    const float inv = 1.f / sqrtf(var + 1e-12f);
#pragma unroll
    for (int i = 0; i < 3; ++i) {
        const int c = threadIdx.x + i * 256;
        out[base + c] = (vals[i] - mu) * inv * g[c] + bta[c];
    }
}

// ---------------------------------------------------------------------------
extern "C" void kernel_launch(void* const* d_in, const int* in_sizes, int n_in,
                              void* d_out, int out_size, void* d_ws, size_t ws_size,
                              hipStream_t stream)
{
    const float* x = (const float*)d_in[0];
    const float* ln_g = (const float*)d_in[19];
    const float* ln_b = (const float*)d_in[20];

    // workspace layout (~193 MB; all big buffers time-major "T" = [chan][row])
    float* dtBCT = (float*)d_ws;                                  //  5.24 MB fp32 [80][16384]
    unsigned short* xzT = (unsigned short*)(dtBCT + (size_t)NDBC * NROWS); // 100.7 MB [3072][16384]
    unsigned short* ucT = xzT + (size_t)NXZ * NROWS;              // 50.3 MB [1536][16384]
    unsigned short* xbf = ucT + (size_t)D_INNER * NROWS;          // 25.2 MB [16384][768]
    unsigned short* wbf_in  = xbf + (size_t)NROWS * D_MODEL;      //  4.7 MB
    unsigned short* wbf_out = wbf_in + (size_t)NXZ * D_MODEL;     //  2.4 MB
    float* Fb = (float*)(wbf_out + (size_t)D_MODEL * D_INNER);    //  2.36 MB
    float* Pb = Fb + (size_t)(NCHUNK - 1) * NCH * 16;             //  2.36 MB
    const size_t needed = ((size_t)NDBC * NROWS) * 4
        + ((size_t)NXZ * NROWS + (size_t)D_INNER * NROWS + (size_t)NROWS * D_MODEL
           + (size_t)NXZ * D_MODEL + (size_t)D_MODEL * D_INNER) * 2
        + (size_t)(NCHUNK - 1) * NCH * 16 * 4 * 2;
    if (ws_size < needed) return;

    float* outp = (float*)d_out;

    cast_f32_bf16<<<(NROWS * D_MODEL / 4 + 255) / 256, 256, 0, stream>>>(
        x, xbf, NROWS * D_MODEL / 4);

    for (int dir = 0; dir < 2; ++dir) {
        const float* in_w    = (const float*)d_in[1 + dir * 9 + 0];
        const float* conv_w  = (const float*)d_in[1 + dir * 9 + 1];
        const float* conv_b  = (const float*)d_in[1 + dir * 9 + 2];
        const float* xproj_w = (const float*)d_in[1 + dir * 9 + 3];
        const float* dt_w    = (const float*)d_in[1 + dir * 9 + 4];
        const float* dt_b    = (const float*)d_in[1 + dir * 9 + 5];
        const float* A_log   = (const float*)d_in[1 + dir * 9 + 6];
        const float* D_skip  = (const float*)d_in[1 + dir * 9 + 7];
        const float* out_w   = (const float*)d_in[1 + dir * 9 + 8];

        cast_f32_bf16<<<(NXZ * D_MODEL / 4 + 255) / 256, 256, 0, stream>>>(
            in_w, wbf_in, NXZ * D_MODEL / 4);
        cast_f32_bf16<<<(D_MODEL * D_INNER / 4 + 255) / 256, 256, 0, stream>>>(
            out_w, wbf_out, D_MODEL * D_INNER / 4);

        // xz_T = (x @ in_w^T)^T   [3072][16384] bf16
        gemm_mfma_tr<<<dim3(NXZ / 128, NROWS / 128), 256, 0, stream>>>(
            xbf, D_MODEL, wbf_in, D_MODEL, xzT, D_MODEL);

        // uc_T = silu(conv(u_T))  [1536][16384] bf16
        if (dir == 0)
            conv_t<0><<<NCH, 256, 0, stream>>>(xzT, conv_w, conv_b, ucT);
        else
            conv_t<1><<<NCH, 256, 0, stream>>>(xzT, conv_w, conv_b, ucT);

        // dtBC_T = xproj_w @ uc_T    [80][16384] fp32
        gemm_nn<1, 0, 0><<<dim3(NROWS / 64, 2), 256, 0, stream>>>(
            xproj_w, D_INNER, ucT, (size_t)NROWS, nullptr,
            dtBCT, (size_t)NROWS, NDBC, D_INNER);

        // dt_T = softplus(dt_w @ dtBC_T[0:48] + dt_b)  -> overlay xz_T u-half
        gemm_nn<0, 1, 1><<<dim3(NROWS / 64, D_INNER / 64), 256, 0, stream>>>(
            dt_w, DT_RANK, dtBCT, (size_t)NROWS, dt_b,
            xzT, (size_t)NROWS, D_INNER, DT_RANK);

        // chunked scan
        if (dir == 0) {
            scan_pass1<0><<<(NCHUNK - 1) * NGRP, 256, 0, stream>>>(
                dtBCT, ucT, A_log, xzT, Fb, Pb);
            scan_pass2<0><<<NCHUNK * NGRP, 256, 0, stream>>>(
                dtBCT, ucT, A_log, D_skip, xzT, Fb, Pb);
        } else {
            scan_pass1<1><<<(NCHUNK - 1) * NGRP, 256, 0, stream>>>(
                dtBCT, ucT, A_log, xzT, Fb, Pb);
            scan_pass2<1><<<NCHUNK * NGRP, 256, 0, stream>>>(
                dtBCT, ucT, A_log, D_skip, xzT, Fb, Pb);
        }

        // y_T (xz_T u-half) -> y row-major into ucT buffer [16384][1536]
        transpose_bf16<<<dim3(NROWS / 64, D_INNER / 64), 256, 0, stream>>>(
            xzT, ucT);

        // outp (+)= y @ out_w^T   [16384][768] fp32
        if (dir == 0)
            gemm_mfma<0><<<dim3(D_MODEL / 128, NROWS / 128), 256, 0, stream>>>(
                ucT, D_INNER, wbf_out, D_INNER, outp, D_MODEL, D_INNER);
        else
            gemm_mfma<1><<<dim3(D_MODEL / 128, NROWS / 128), 256, 0, stream>>>(
                ucT, D_INNER, wbf_out, D_INNER, outp, D_MODEL, D_INNER);
    }

    fuse_ln<<<NROWS, 256, 0, stream>>>(outp, x, ln_g, ln_b);
}

// Round 7
// 1844.948 us; speedup vs baseline: 2.9583x; 1.0158x over previous
//
#include <hip/hip_runtime.h>
#include <math.h>

#define D_MODEL 768
#define D_INNER 1536
#define D_STATE 16
#define DCONV 4
#define DT_RANK 48
#define BATCH 8
#define SEQ 2048
#define NROWS (BATCH * SEQ)          // 16384
#define NXZ (2 * D_INNER)            // 3072
#define NDBC (DT_RANK + 2 * D_STATE) // 80
#define LDT 16448                    // padded T-layout row stride (+128B bf16)

#define NCHUNK 4
#define CL (SEQ / NCHUNK)            // 512
#define NCH (BATCH * D_INNER)        // 12288 channels
#define NGRP (NCH / 16)              // 768 channel-groups (16 ch/block)

#define LOG2E 1.4426950408889634f
#define LN2   0.6931471805599453f

typedef __attribute__((ext_vector_type(8))) short bh8;            // MFMA A/B frag
typedef __attribute__((ext_vector_type(4))) float f4;             // MFMA acc / f32x4
typedef __attribute__((ext_vector_type(8))) unsigned short us8;   // 8 bf16 = 16B

__device__ __forceinline__ float bf2f(unsigned short u) {
    return __uint_as_float(((unsigned int)u) << 16);
}
__device__ __forceinline__ unsigned short f2bf(float f) {
    unsigned int x = __float_as_uint(f);
    return (unsigned short)((x + 0x7fffu + ((x >> 16) & 1u)) >> 16);
}
__device__ __forceinline__ float fsigm(float x) {
    return __builtin_amdgcn_rcpf(1.f + __builtin_amdgcn_exp2f(-x * LOG2E));
}

#define GLL16(gp, lp) __builtin_amdgcn_global_load_lds( \
    (const __attribute__((address_space(1))) void*)(gp), \
    (__attribute__((address_space(3))) void*)(lp), 16, 0, 0)

// ---------------------------------------------------------------------------
// bf16 MFMA GEMM (NT): C(MxN fp32) = A(MxK) @ W(NxK)^T  [+C if ACC]
// 128x128 tile, BK=32, 4 waves. Used for out_proj.
// ---------------------------------------------------------------------------
template <int ACC>
__global__ __launch_bounds__(256) void gemm_mfma(
    const unsigned short* __restrict__ A, int lda,
    const unsigned short* __restrict__ W, int ldw,
    float* __restrict__ C, int ldc, int K)
{
    __shared__ unsigned short As[128 * 32];
    __shared__ unsigned short Bs[128 * 32];
    const int tid = threadIdx.x;
    const int w = tid >> 6;
    const int l = tid & 63;
    const int wr = w >> 1, wc = w & 1;
    const int tm0 = blockIdx.y * 128;
    const int tn0 = blockIdx.x * 128;

    const int srow = (w << 4) + (l >> 2);
    const int scol = (l & 3) * 8;
    unsigned short* ldsA0 = &As[(w << 4) * 32];
    unsigned short* ldsA1 = &As[(64 + (w << 4)) * 32];
    unsigned short* ldsB0 = &Bs[(w << 4) * 32];
    unsigned short* ldsB1 = &Bs[(64 + (w << 4)) * 32];
    const unsigned short* gA0 = A + (size_t)(tm0 + srow) * lda + scol;
    const unsigned short* gA1 = A + (size_t)(tm0 + 64 + srow) * lda + scol;
    const unsigned short* gB0 = W + (size_t)(tn0 + srow) * ldw + scol;
    const unsigned short* gB1 = W + (size_t)(tn0 + 64 + srow) * ldw + scol;

    const int aoff = ((wr << 6) + (l & 15)) * 32 + ((l >> 4) << 3);
    const int boff = ((wc << 6) + (l & 15)) * 32 + ((l >> 4) << 3);

    f4 acc[4][4];
#pragma unroll
    for (int i = 0; i < 4; ++i)
#pragma unroll
        for (int j = 0; j < 4; ++j) acc[i][j] = 0.f;

    for (int k0 = 0; k0 < K; k0 += 32) {
        GLL16(gA0 + k0, ldsA0);
        GLL16(gA1 + k0, ldsA1);
        GLL16(gB0 + k0, ldsB0);
        GLL16(gB1 + k0, ldsB1);
        __syncthreads();
        bh8 af[4], bf[4];
#pragma unroll
        for (int mi = 0; mi < 4; ++mi) af[mi] = *(const bh8*)&As[aoff + mi * 512];
#pragma unroll
        for (int ni = 0; ni < 4; ++ni) bf[ni] = *(const bh8*)&Bs[boff + ni * 512];
#pragma unroll
        for (int mi = 0; mi < 4; ++mi)
#pragma unroll
            for (int ni = 0; ni < 4; ++ni)
                acc[mi][ni] = __builtin_amdgcn_mfma_f32_16x16x32_bf16(
                    af[mi], bf[ni], acc[mi][ni], 0, 0, 0);
        __syncthreads();
    }

    const int crow0 = tm0 + (wr << 6) + ((l >> 4) << 2);
    const int ccol0 = tn0 + (wc << 6) + (l & 15);
#pragma unroll
    for (int mi = 0; mi < 4; ++mi)
#pragma unroll
        for (int ni = 0; ni < 4; ++ni)
#pragma unroll
            for (int r = 0; r < 4; ++r) {
                const size_t idx = (size_t)(crow0 + mi * 16 + r) * ldc
                                 + (ccol0 + ni * 16);
                C[idx] = ACC ? (C[idx] + acc[mi][ni][r]) : acc[mi][ni][r];
            }
}

// ---------------------------------------------------------------------------
// bf16 MFMA GEMM (NT) with TRANSPOSED bf16 store: Ct[N][LDT] = (A@W^T)^T.
// LDS bounce in 4 col-windows of 32. Used for in_proj -> xz_T.
// ---------------------------------------------------------------------------
__global__ __launch_bounds__(256) void gemm_mfma_tr(
    const unsigned short* __restrict__ A, int lda,
    const unsigned short* __restrict__ W, int ldw,
    unsigned short* __restrict__ Ct, int K)
{
    __shared__ unsigned short As[128 * 32];
    __shared__ unsigned short Bs[128 * 32];
    __shared__ unsigned short tr[32 * 136];
    const int tid = threadIdx.x;
    const int w = tid >> 6;
    const int l = tid & 63;
    const int wr = w >> 1, wc = w & 1;
    const int tm0 = blockIdx.y * 128;   // row block (M)
    const int tn0 = blockIdx.x * 128;   // col block (N)

    const int srow = (w << 4) + (l >> 2);
    const int scol = (l & 3) * 8;
    unsigned short* ldsA0 = &As[(w << 4) * 32];
    unsigned short* ldsA1 = &As[(64 + (w << 4)) * 32];
    unsigned short* ldsB0 = &Bs[(w << 4) * 32];
    unsigned short* ldsB1 = &Bs[(64 + (w << 4)) * 32];
    const unsigned short* gA0 = A + (size_t)(tm0 + srow) * lda + scol;
    const unsigned short* gA1 = A + (size_t)(tm0 + 64 + srow) * lda + scol;
    const unsigned short* gB0 = W + (size_t)(tn0 + srow) * ldw + scol;
    const unsigned short* gB1 = W + (size_t)(tn0 + 64 + srow) * ldw + scol;

    const int aoff = ((wr << 6) + (l & 15)) * 32 + ((l >> 4) << 3);
    const int boff = ((wc << 6) + (l & 15)) * 32 + ((l >> 4) << 3);

    f4 acc[4][4];
#pragma unroll
    for (int i = 0; i < 4; ++i)
#pragma unroll
        for (int j = 0; j < 4; ++j) acc[i][j] = 0.f;

    for (int k0 = 0; k0 < K; k0 += 32) {
        GLL16(gA0 + k0, ldsA0);
        GLL16(gA1 + k0, ldsA1);
        GLL16(gB0 + k0, ldsB0);
        GLL16(gB1 + k0, ldsB1);
        __syncthreads();
        bh8 af[4], bf[4];
#pragma unroll
        for (int mi = 0; mi < 4; ++mi) af[mi] = *(const bh8*)&As[aoff + mi * 512];
#pragma unroll
        for (int ni = 0; ni < 4; ++ni) bf[ni] = *(const bh8*)&Bs[boff + ni * 512];
#pragma unroll
        for (int mi = 0; mi < 4; ++mi)
#pragma unroll
            for (int ni = 0; ni < 4; ++ni)
                acc[mi][ni] = __builtin_amdgcn_mfma_f32_16x16x32_bf16(
                    af[mi], bf[ni], acc[mi][ni], 0, 0, 0);
        __syncthreads();
    }

    // transposed epilogue: 4 passes over 32-col windows
    const int rowL0 = (wr << 6) + ((l >> 4) << 2);
#pragma unroll
    for (int p = 0; p < 4; ++p) {
        if (wc == (p >> 1)) {
#pragma unroll
            for (int nn = 0; nn < 2; ++nn) {
                const int ni = (p & 1) * 2 + nn;
                const int colW = nn * 16 + (l & 15);
#pragma unroll
                for (int mi = 0; mi < 4; ++mi)
#pragma unroll
                    for (int r = 0; r < 4; ++r)
                        tr[colW * 136 + rowL0 + mi * 16 + r] = f2bf(acc[mi][ni][r]);
            }
        }
        __syncthreads();
        {
            const int col = tid >> 3, seg = tid & 7;
            us8 v0 = *(const us8*)&tr[col * 136 + seg * 16];
            us8 v1 = *(const us8*)&tr[col * 136 + seg * 16 + 8];
            const size_t dst = (size_t)(tn0 + p * 32 + col) * LDT + tm0 + seg * 16;
            *(us8*)(Ct + dst) = v0;
            *(us8*)(Ct + dst + 8) = v1;
        }
        __syncthreads();
    }
}

// ---------------------------------------------------------------------------
// Vector GEMM (NN over K-major W): C[M][N] = act(A[M][K] @ Wk[K][N] [+bias_m])
// A fp32 row-major. Wk bf16 (WK_BF) or fp32, ldk = row stride of Wk.
// ACT 1: softplus(x + bias[m]). TC_BF: bf16 C. N must be mult of 64.
// ---------------------------------------------------------------------------
template <int WK_BF, int ACT, int TC_BF>
__global__ __launch_bounds__(256) void gemm_nn(
    const float* __restrict__ A, int lda,
    const void* __restrict__ Wkv, size_t ldk,
    const float* __restrict__ bias,
    void* __restrict__ Cv, size_t ldc,
    int M, int K)
{
    __shared__ float As[16][68];
    __shared__ float Ws[16][68];
    const int tid = threadIdx.x;
    const int tx = tid & 15;
    const int ty = tid >> 4;
    const int tn0 = blockIdx.x * 64;
    const int tm0 = blockIdx.y * 64;
    const int r  = tid >> 2;      // A-row to load
    const int kq = tid & 3;       // A k-quad
    const int kk = tid >> 4;      // W k-row
    const int nq = tid & 15;      // W n-quad

    float acc[4][4];
#pragma unroll
    for (int i = 0; i < 4; ++i)
#pragma unroll
        for (int j = 0; j < 4; ++j) acc[i][j] = 0.f;

    for (int k0 = 0; k0 < K; k0 += 16) {
        float4 av = make_float4(0.f, 0.f, 0.f, 0.f);
        if (tm0 + r < M)
            av = *(const float4*)&A[(size_t)(tm0 + r) * lda + k0 + kq * 4];
        As[kq * 4 + 0][r] = av.x;
        As[kq * 4 + 1][r] = av.y;
        As[kq * 4 + 2][r] = av.z;
        As[kq * 4 + 3][r] = av.w;

        if (WK_BF) {
            const unsigned short* Wk = (const unsigned short*)Wkv;
            ushort4 t = *(const ushort4*)&Wk[(size_t)(k0 + kk) * ldk + tn0 + nq * 4];
            Ws[kk][nq * 4 + 0] = bf2f(t.x);
            Ws[kk][nq * 4 + 1] = bf2f(t.y);
            Ws[kk][nq * 4 + 2] = bf2f(t.z);
            Ws[kk][nq * 4 + 3] = bf2f(t.w);
        } else {
            const float* Wk = (const float*)Wkv;
            float4 t = *(const float4*)&Wk[(size_t)(k0 + kk) * ldk + tn0 + nq * 4];
            Ws[kk][nq * 4 + 0] = t.x;
            Ws[kk][nq * 4 + 1] = t.y;
            Ws[kk][nq * 4 + 2] = t.z;
            Ws[kk][nq * 4 + 3] = t.w;
        }

        __syncthreads();
#pragma unroll
        for (int kx = 0; kx < 16; ++kx) {
            const float4 a = *(const float4*)&As[kx][ty * 4];
            const float4 b = *(const float4*)&Ws[kx][tx * 4];
            acc[0][0] += a.x * b.x; acc[0][1] += a.x * b.y; acc[0][2] += a.x * b.z; acc[0][3] += a.x * b.w;
            acc[1][0] += a.y * b.x; acc[1][1] += a.y * b.y; acc[1][2] += a.y * b.z; acc[1][3] += a.y * b.w;
            acc[2][0] += a.z * b.x; acc[2][1] += a.z * b.y; acc[2][2] += a.z * b.z; acc[2][3] += a.z * b.w;
            acc[3][0] += a.w * b.x; acc[3][1] += a.w * b.y; acc[3][2] += a.w * b.z; acc[3][3] += a.w * b.w;
        }
        __syncthreads();
    }

#pragma unroll
    for (int i = 0; i < 4; ++i) {
        const int m = tm0 + ty * 4 + i;
        if (m >= M) continue;
        float v[4];
#pragma unroll
        for (int j = 0; j < 4; ++j) {
            v[j] = acc[i][j];
            if (ACT == 1) {
                v[j] += bias[m];
                if (v[j] <= 20.f)
                    v[j] = __builtin_amdgcn_logf(1.f + __builtin_amdgcn_exp2f(v[j] * LOG2E)) * LN2;
            }
        }
        const size_t idx = (size_t)m * ldc + tn0 + tx * 4;
        if (TC_BF) {
            ushort4 o;
            o.x = f2bf(v[0]); o.y = f2bf(v[1]); o.z = f2bf(v[2]); o.w = f2bf(v[3]);
            *(ushort4*)&((unsigned short*)Cv)[idx] = o;
        } else {
            *(float4*)&((float*)Cv)[idx] = make_float4(v[0], v[1], v[2], v[3]);
        }
    }
}

// ---------------------------------------------------------------------------
__global__ __launch_bounds__(256) void cast_f32_bf16(
    const float* __restrict__ in, unsigned short* __restrict__ out, int n4)
{
    const int i = blockIdx.x * 256 + threadIdx.x;
    if (i >= n4) return;
    const float4 v = ((const float4*)in)[i];
    ushort4 o;
    o.x = f2bf(v.x); o.y = f2bf(v.y); o.z = f2bf(v.z); o.w = f2bf(v.w);
    ((ushort4*)out)[i] = o;
}

// ---------------------------------------------------------------------------
// Depthwise causal conv + SiLU on time-major layout. One block per (d,b),
// thread handles 8 consecutive t. DIR=0: taps t-j; DIR=1: taps t+j (w[3-j]).
// ---------------------------------------------------------------------------
template <int DIR>
__global__ __launch_bounds__(256) void conv_t(
    const unsigned short* __restrict__ xzT, const float* __restrict__ conv_w,
    const float* __restrict__ conv_b, unsigned short* __restrict__ ucT)
{
    const int bd = blockIdx.x;            // 0..NCH-1
    const int d = bd >> 3, b = bd & 7;
    const int t0 = threadIdx.x * 8;
    const size_t base = (size_t)d * LDT + (size_t)b * SEQ;
    const float w0 = conv_w[d * 4 + 0], w1 = conv_w[d * 4 + 1];
    const float w2 = conv_w[d * 4 + 2], w3 = conv_w[d * 4 + 3];
    const float cb = conv_b[d];

    const us8 cur = *(const us8*)(xzT + base + t0);
    float u[11];
    us8 o;
    if (DIR == 0) {
        us8 prev = (us8)0;
        if (t0 > 0) prev = *(const us8*)(xzT + base + t0 - 8);
        u[0] = bf2f(prev[5]); u[1] = bf2f(prev[6]); u[2] = bf2f(prev[7]);
#pragma unroll
        for (int j = 0; j < 8; ++j) u[3 + j] = bf2f(cur[j]);
#pragma unroll
        for (int j = 0; j < 8; ++j) {
            float a = cb;
            a = fmaf(u[j],     w0, a);
            a = fmaf(u[j + 1], w1, a);
            a = fmaf(u[j + 2], w2, a);
            a = fmaf(u[j + 3], w3, a);
            o[j] = f2bf(a * fsigm(a));
        }
    } else {
        us8 nxt = (us8)0;
        if (t0 + 8 < SEQ) nxt = *(const us8*)(xzT + base + t0 + 8);
#pragma unroll
        for (int j = 0; j < 8; ++j) u[j] = bf2f(cur[j]);
        u[8] = bf2f(nxt[0]); u[9] = bf2f(nxt[1]); u[10] = bf2f(nxt[2]);
#pragma unroll
        for (int j = 0; j < 8; ++j) {
            float a = cb;
            a = fmaf(u[j],     w3, a);
            a = fmaf(u[j + 1], w2, a);
            a = fmaf(u[j + 2], w1, a);
            a = fmaf(u[j + 3], w0, a);
            o[j] = f2bf(a * fsigm(a));
        }
    }
    *(us8*)(ucT + base + t0) = o;
}

// ---------------------------------------------------------------------------
// Chunked selective scan on time-major layout. 16 lanes/channel (state n per
// lane). All streams contiguous in t -> vector loads (reversed for DIR=1).
// pass2 batches 4x8 steps and flushes the 4 output stores together so each
// 64B output line is fully dirtied within a few cycles (no RMW eviction).
// ---------------------------------------------------------------------------
struct SB1 { float dtv[8], uv[8], Bv[8]; };
struct SB2 { float dtv[8], uv[8], Bv[8], Cv[8], zv; };

template <int DIR>
__device__ __forceinline__ void load1(
    SB1& s, const unsigned short* pdt, const unsigned short* pu,
    const float* pB, int t0)
{
    if (DIR == 0) {
        const us8 vd = *(const us8*)(pdt + t0);
        const us8 vu = *(const us8*)(pu + t0);
        const f4 b0 = *(const f4*)(pB + t0);
        const f4 b1 = *(const f4*)(pB + t0 + 4);
#pragma unroll
        for (int j = 0; j < 8; ++j) {
            s.dtv[j] = bf2f(vd[j]);
            s.uv[j]  = bf2f(vu[j]);
            s.Bv[j]  = (j < 4) ? b0[j] : b1[j - 4];
        }
    } else {
        const us8 vd = *(const us8*)(pdt - t0 - 7);
        const us8 vu = *(const us8*)(pu - t0 - 7);
        const f4 b0 = *(const f4*)(pB - t0 - 7);
        const f4 b1 = *(const f4*)(pB - t0 - 3);
#pragma unroll
        for (int j = 0; j < 8; ++j) {
            s.dtv[j] = bf2f(vd[7 - j]);
            s.uv[j]  = bf2f(vu[7 - j]);
            s.Bv[j]  = (j < 4) ? b1[3 - j] : b0[7 - j];
        }
    }
}

__device__ __forceinline__ void comp1(const SB1& s, float& h, float& P, float A2)
{
#pragma unroll
    for (int j = 0; j < 8; ++j) {
        const float dA = __builtin_amdgcn_exp2f(s.dtv[j] * A2);
        P *= dA;
        h = fmaf(dA, h, s.dtv[j] * s.uv[j] * s.Bv[j]);
    }
}

template <int DIR>
__global__ __launch_bounds__(256) void scan_pass1(
    const float* __restrict__ dtBCT, const unsigned short* __restrict__ ucT,
    const float* __restrict__ A_log, const unsigned short* __restrict__ xzT,
    float* __restrict__ Fb, float* __restrict__ Pb)
{
    const int tid = threadIdx.x;
    const int n = tid & 15, g = tid >> 4;
    const int c   = blockIdx.x / NGRP;          // 0..NCHUNK-2
    const int grp = blockIdx.x - c * NGRP;
    const int ch = grp * 16 + g;
    const int b = ch / D_INNER, d = ch % D_INNER;

    const float A2 = -expf(A_log[d * D_STATE + n]) * LOG2E;
    const long l0 = DIR ? (SEQ - 1 - c * CL) : (c * CL);
    const size_t base = (size_t)b * SEQ + l0;

    const unsigned short* pdt = xzT + (size_t)d * LDT + base;
    const unsigned short* pu  = ucT + (size_t)d * LDT + base;
    const float* pB = dtBCT + (size_t)(DT_RANK + n) * LDT + base;

    float h = 0.f, P = 1.f;
    SB1 sa, sb;
    load1<DIR>(sa, pdt, pu, pB, 0);
    for (int t0 = 0; t0 < CL; t0 += 16) {
        load1<DIR>(sb, pdt, pu, pB, t0 + 8);
        comp1(sa, h, P, A2);
        if (t0 + 16 < CL)
            load1<DIR>(sa, pdt, pu, pB, t0 + 16);
        comp1(sb, h, P, A2);
    }
    const size_t fi = ((size_t)c * NCH + ch) * 16 + n;
    Fb[fi] = h;
    Pb[fi] = P;
}

template <int DIR>
__device__ __forceinline__ void load2(
    SB2& s, const unsigned short* pdt, const unsigned short* pu,
    const float* pB, const float* pC, const unsigned short* pz, int t0, int n)
{
    if (DIR == 0) {
        const us8 vd = *(const us8*)(pdt + t0);
        const us8 vu = *(const us8*)(pu + t0);
        const f4 b0 = *(const f4*)(pB + t0);
        const f4 b1 = *(const f4*)(pB + t0 + 4);
        const f4 c0 = *(const f4*)(pC + t0);
        const f4 c1 = *(const f4*)(pC + t0 + 4);
#pragma unroll
        for (int j = 0; j < 8; ++j) {
            s.dtv[j] = bf2f(vd[j]);
            s.uv[j]  = bf2f(vu[j]);
            s.Bv[j]  = (j < 4) ? b0[j] : b1[j - 4];
            s.Cv[j]  = (j < 4) ? c0[j] : c1[j - 4];
        }
        s.zv = bf2f(pz[t0 + (n & 7)]);
    } else {
        const us8 vd = *(const us8*)(pdt - t0 - 7);
        const us8 vu = *(const us8*)(pu - t0 - 7);
        const f4 b0 = *(const f4*)(pB - t0 - 7);
        const f4 b1 = *(const f4*)(pB - t0 - 3);
        const f4 c0 = *(const f4*)(pC - t0 - 7);
        const f4 c1 = *(const f4*)(pC - t0 - 3);
#pragma unroll
        for (int j = 0; j < 8; ++j) {
            s.dtv[j] = bf2f(vd[7 - j]);
            s.uv[j]  = bf2f(vu[7 - j]);
            s.Bv[j]  = (j < 4) ? b1[3 - j] : b0[7 - j];
            s.Cv[j]  = (j < 4) ? c1[3 - j] : c0[7 - j];
        }
        s.zv = bf2f(pz[-(t0 + (n & 7))]);
    }
}

// computes 8 steps; returns this batch's output value for lane n (valid n<8):
// y(t0+n) * silu(z(t0+n))
__device__ __forceinline__ float comp2(
    const SB2& s, int n, float& h, float A2, float Dv)
{
    float yk = 0.f;
#pragma unroll
    for (int j = 0; j < 8; ++j) {
        const float dtv = s.dtv[j];
        const float dA = __builtin_amdgcn_exp2f(dtv * A2);
        h = fmaf(dA, h, dtv * s.uv[j] * s.Bv[j]);
        float pp = h * s.Cv[j];
        pp += __shfl_xor(pp, 1, 16);
        pp += __shfl_xor(pp, 2, 16);
        pp += __shfl_xor(pp, 4, 16);
        pp += __shfl_xor(pp, 8, 16);
        const float y = fmaf(s.uv[j], Dv, pp);
        yk = (n == j) ? y : yk;
    }
    return yk * (s.zv * fsigm(s.zv));
}

template <int DIR>
__global__ __launch_bounds__(256) void scan_pass2(
    const float* __restrict__ dtBCT, const unsigned short* __restrict__ ucT,
    const float* __restrict__ A_log, const float* __restrict__ D_skip,
    unsigned short* __restrict__ xzT,
    const float* __restrict__ Fb, const float* __restrict__ Pb)
{
    const int tid = threadIdx.x;
    const int n = tid & 15, g = tid >> 4;
    const int c   = blockIdx.x / NGRP;          // 0..NCHUNK-1
    const int grp = blockIdx.x - c * NGRP;
    const int ch = grp * 16 + g;
    const int b = ch / D_INNER, d = ch % D_INNER;

    const float A2 = -expf(A_log[d * D_STATE + n]) * LOG2E;
    const float Dv = D_skip[d];
    const long l0 = DIR ? (SEQ - 1 - c * CL) : (c * CL);
    const size_t base = (size_t)b * SEQ + l0;

    const unsigned short* pdt = xzT + (size_t)d * LDT + base;
    const unsigned short* pz  = xzT + (size_t)(D_INNER + d) * LDT + base;
    const unsigned short* pu  = ucT + (size_t)d * LDT + base;
    const float* pB = dtBCT + (size_t)(DT_RANK + n) * LDT + base;
    const float* pC = dtBCT + (size_t)(DT_RANK + D_STATE + n) * LDT + base;
    unsigned short* pout = xzT + (size_t)d * LDT + base;

    float h = 0.f;
    for (int cc = 0; cc < c; ++cc) {
        const size_t fi = ((size_t)cc * NCH + ch) * 16 + n;
        h = fmaf(Pb[fi], h, Fb[fi]);
    }

    SB2 sa, sb;
    load2<DIR>(sa, pdt, pu, pB, pC, pz, 0, n);
    for (int t0 = 0; t0 < CL; t0 += 32) {
        float y0, y1, y2, y3;
        load2<DIR>(sb, pdt, pu, pB, pC, pz, t0 + 8, n);
        y0 = comp2(sa, n, h, A2, Dv);
        load2<DIR>(sa, pdt, pu, pB, pC, pz, t0 + 16, n);
        y1 = comp2(sb, n, h, A2, Dv);
        load2<DIR>(sb, pdt, pu, pB, pC, pz, t0 + 24, n);
        y2 = comp2(sa, n, h, A2, Dv);
        if (t0 + 32 < CL)
            load2<DIR>(sa, pdt, pu, pB, pC, pz, t0 + 32, n);
        y3 = comp2(sb, n, h, A2, Dv);
        // flush 4 stores back-to-back: full 64B line dirtied promptly
        if (n < 8) {
            const long sgn = DIR ? -1 : 1;
            pout[sgn * (long)(t0 + n)]      = f2bf(y0);
            pout[sgn * (long)(t0 + 8 + n)]  = f2bf(y1);
            pout[sgn * (long)(t0 + 16 + n)] = f2bf(y2);
            pout[sgn * (long)(t0 + 24 + n)] = f2bf(y3);
        }
    }
}

// ---------------------------------------------------------------------------
// 64x64 LDS tile transpose: in [1536][LDT] bf16 -> out [NROWS][1536] bf16.
// ---------------------------------------------------------------------------
__global__ __launch_bounds__(256) void transpose_bf16(
    const unsigned short* __restrict__ in, unsigned short* __restrict__ out)
{
    __shared__ unsigned short tile[64][72];
    const int r0 = blockIdx.x * 64;
    const int d0 = blockIdx.y * 64;
    const int tid = threadIdx.x;
    {
        const int dd = tid >> 2;
        const int rq = (tid & 3) * 16;
        const size_t src = (size_t)(d0 + dd) * LDT + r0 + rq;
        *(us8*)&tile[dd][rq]     = *(const us8*)(in + src);
        *(us8*)&tile[dd][rq + 8] = *(const us8*)(in + src + 8);
    }
    __syncthreads();
    {
        const int rr = tid >> 2;
        const int dq = (tid & 3) * 16;
        us8 o0, o1;
#pragma unroll
        for (int i = 0; i < 8; ++i) {
            o0[i] = tile[dq + i][rr];
            o1[i] = tile[dq + 8 + i][rr];
        }
        const size_t dst = (size_t)(r0 + rr) * D_INNER + d0 + dq;
        *(us8*)(out + dst)     = o0;
        *(us8*)(out + dst + 8) = o1;
    }
}

// ---------------------------------------------------------------------------
// In-place: out = LN(out + x) * g + b
// ---------------------------------------------------------------------------
__global__ __launch_bounds__(256) void fuse_ln(
    float* __restrict__ out, const float* __restrict__ x,
    const float* __restrict__ g, const float* __restrict__ bta)
{
    const int row = blockIdx.x;
    const size_t base = (size_t)row * D_MODEL;
    float vals[3];
    float s = 0.f, s2 = 0.f;
#pragma unroll
    for (int i = 0; i < 3; ++i) {
        const int c = threadIdx.x + i * 256;
        const float v = out[base + c] + x[base + c];
        vals[i] = v;
        s += v;
        s2 += v * v;
    }
#pragma unroll
    for (int o = 32; o >= 1; o >>= 1) {
        s  += __shfl_xor(s, o, 64);
        s2 += __shfl_xor(s2, o, 64);
    }
    __shared__ float ls[4], ls2[4];
    const int wid = threadIdx.x >> 6;
    if ((threadIdx.x & 63) == 0) { ls[wid] = s; ls2[wid] = s2; }
    __syncthreads();
    s  = ls[0] + ls[1] + ls[2] + ls[3];
    s2 = ls2[0] + ls2[1] + ls2[2] + ls2[3];
    const float mu  = s * (1.f / D_MODEL);
    const float var = s2 * (1.f / D_MODEL) - mu * mu;
    const float inv = 1.f / sqrtf(var + 1e-12f);
#pragma unroll
    for (int i = 0; i < 3; ++i) {
        const int c = threadIdx.x + i * 256;
        out[base + c] = (vals[i] - mu) * inv * g[c] + bta[c];
    }
}

// ---------------------------------------------------------------------------
extern "C" void kernel_launch(void* const* d_in, const int* in_sizes, int n_in,
                              void* d_out, int out_size, void* d_ws, size_t ws_size,
                              hipStream_t stream)
{
    const float* x = (const float*)d_in[0];
    const float* ln_g = (const float*)d_in[19];
    const float* ln_b = (const float*)d_in[20];

    // workspace layout (~194 MB; T buffers padded to LDT to break 32KB L2 alias)
    float* dtBCT = (float*)d_ws;                                  // [80][LDT] fp32
    unsigned short* xzT = (unsigned short*)(dtBCT + (size_t)NDBC * LDT); // [3072][LDT]
    unsigned short* ucT = xzT + (size_t)NXZ * LDT;                // [1536][LDT]
    unsigned short* xbf = ucT + (size_t)D_INNER * LDT;            // [16384][768]
    unsigned short* wbf_in  = xbf + (size_t)NROWS * D_MODEL;
    unsigned short* wbf_out = wbf_in + (size_t)NXZ * D_MODEL;
    float* Fb = (float*)(wbf_out + (size_t)D_MODEL * D_INNER);
    float* Pb = Fb + (size_t)(NCHUNK - 1) * NCH * 16;
    const size_t needed = ((size_t)NDBC * LDT) * 4
        + ((size_t)NXZ * LDT + (size_t)D_INNER * LDT + (size_t)NROWS * D_MODEL
           + (size_t)NXZ * D_MODEL + (size_t)D_MODEL * D_INNER) * 2
        + (size_t)(NCHUNK - 1) * NCH * 16 * 4 * 2;
    if (ws_size < needed) return;

    float* outp = (float*)d_out;

    cast_f32_bf16<<<(NROWS * D_MODEL / 4 + 255) / 256, 256, 0, stream>>>(
        x, xbf, NROWS * D_MODEL / 4);

    for (int dir = 0; dir < 2; ++dir) {
        const float* in_w    = (const float*)d_in[1 + dir * 9 + 0];
        const float* conv_w  = (const float*)d_in[1 + dir * 9 + 1];
        const float* conv_b  = (const float*)d_in[1 + dir * 9 + 2];
        const float* xproj_w = (const float*)d_in[1 + dir * 9 + 3];
        const float* dt_w    = (const float*)d_in[1 + dir * 9 + 4];
        const float* dt_b    = (const float*)d_in[1 + dir * 9 + 5];
        const float* A_log   = (const float*)d_in[1 + dir * 9 + 6];
        const float* D_skip  = (const float*)d_in[1 + dir * 9 + 7];
        const float* out_w   = (const float*)d_in[1 + dir * 9 + 8];

        cast_f32_bf16<<<(NXZ * D_MODEL / 4 + 255) / 256, 256, 0, stream>>>(
            in_w, wbf_in, NXZ * D_MODEL / 4);
        cast_f32_bf16<<<(D_MODEL * D_INNER / 4 + 255) / 256, 256, 0, stream>>>(
            out_w, wbf_out, D_MODEL * D_INNER / 4);

        // xz_T = (x @ in_w^T)^T   [3072][LDT] bf16
        gemm_mfma_tr<<<dim3(NXZ / 128, NROWS / 128), 256, 0, stream>>>(
            xbf, D_MODEL, wbf_in, D_MODEL, xzT, D_MODEL);

        // uc_T = silu(conv(u_T))  [1536][LDT] bf16
        if (dir == 0)
            conv_t<0><<<NCH, 256, 0, stream>>>(xzT, conv_w, conv_b, ucT);
        else
            conv_t<1><<<NCH, 256, 0, stream>>>(xzT, conv_w, conv_b, ucT);

        // dtBC_T = xproj_w @ uc_T    [80][LDT] fp32
        gemm_nn<1, 0, 0><<<dim3(NROWS / 64, 2), 256, 0, stream>>>(
            xproj_w, D_INNER, ucT, (size_t)LDT, nullptr,
            dtBCT, (size_t)LDT, NDBC, D_INNER);

        // dt_T = softplus(dt_w @ dtBC_T[0:48] + dt_b)  -> overlay xz_T u-half
        gemm_nn<0, 1, 1><<<dim3(NROWS / 64, D_INNER / 64), 256, 0, stream>>>(
            dt_w, DT_RANK, dtBCT, (size_t)LDT, dt_b,
            xzT, (size_t)LDT, D_INNER, DT_RANK);

        // chunked scan
        if (dir == 0) {
            scan_pass1<0><<<(NCHUNK - 1) * NGRP, 256, 0, stream>>>(
                dtBCT, ucT, A_log, xzT, Fb, Pb);
            scan_pass2<0><<<NCHUNK * NGRP, 256, 0, stream>>>(
                dtBCT, ucT, A_log, D_skip, xzT, Fb, Pb);
        } else {
            scan_pass1<1><<<(NCHUNK - 1) * NGRP, 256, 0, stream>>>(
                dtBCT, ucT, A_log, xzT, Fb, Pb);
            scan_pass2<1><<<NCHUNK * NGRP, 256, 0, stream>>>(
                dtBCT, ucT, A_log, D_skip, xzT, Fb, Pb);
        }

        // y_T (xz_T u-half) -> y row-major into ucT... NO: ucT is padded now,
        // write row-major y into the xbf-adjacent scratch? ucT reuse is fine:
        // transpose reads xzT rows, writes dense [NROWS][D_INNER] into ucT
        // (interpreted dense; size NROWS*D_INNER < D_INNER*LDT). uc is dead.
        transpose_bf16<<<dim3(NROWS / 64, D_INNER / 64), 256, 0, stream>>>(
            xzT, ucT);

        // outp (+)= y @ out_w^T   [16384][768] fp32
        if (dir == 0)
            gemm_mfma<0><<<dim3(D_MODEL / 128, NROWS / 128), 256, 0, stream>>>(
                ucT, D_INNER, wbf_out, D_INNER, outp, D_MODEL, D_INNER);
        else
            gemm_mfma<1><<<dim3(D_MODEL / 128, NROWS / 128), 256, 0, stream>>>(
                ucT, D_INNER, wbf_out, D_INNER, outp, D_MODEL, D_INNER);
    }

    fuse_ln<<<NROWS, 256, 0, stream>>>(outp, x, ln_g, ln_b);
}

// Round 8
// 1318.820 us; speedup vs baseline: 4.1385x; 1.3989x over previous
//
#include <hip/hip_runtime.h>
#include <math.h>

#define D_MODEL 768
#define D_INNER 1536
#define D_STATE 16
#define DCONV 4
#define DT_RANK 48
#define BATCH 8
#define SEQ 2048
#define NROWS (BATCH * SEQ)          // 16384
#define NXZ (2 * D_INNER)            // 3072
#define NDBC (DT_RANK + 2 * D_STATE) // 80

#define NCHUNK 16
#define CL (SEQ / NCHUNK)            // 128 steps per chunk
#define NCH (BATCH * D_INNER)        // 12288 channels
#define DBLKS (D_INNER / 256)        // 6 blocks of 256 d-channels

#define LOG2E 1.4426950408889634f
#define LN2   0.6931471805599453f

typedef __attribute__((ext_vector_type(8))) short bh8;   // MFMA A/B frag
typedef __attribute__((ext_vector_type(4))) float f4;

__device__ __forceinline__ float bf2f(unsigned short u) {
    return __uint_as_float(((unsigned int)u) << 16);
}
__device__ __forceinline__ unsigned short f2bf(float f) {
    unsigned int x = __float_as_uint(f);
    return (unsigned short)((x + 0x7fffu + ((x >> 16) & 1u)) >> 16);
}
__device__ __forceinline__ float fsigm(float x) {
    return __builtin_amdgcn_rcpf(1.f + __builtin_amdgcn_exp2f(-x * LOG2E));
}

#define GLL16(gp, lp) __builtin_amdgcn_global_load_lds( \
    (const __attribute__((address_space(1))) void*)(gp), \
    (__attribute__((address_space(3))) void*)(lp), 16, 0, 0)

// ---------------------------------------------------------------------------
// bf16 MFMA GEMM (NT): C = A(MxK) @ W(NxK)^T. 128x128 tile, BK=32, 4 waves.
// TC_BF: C bf16 (else fp32). ACC: fp32 C += (fp32 only).
// ---------------------------------------------------------------------------
template <int TC_BF, int ACC>
__global__ __launch_bounds__(256) void gemm_mfma(
    const unsigned short* __restrict__ A, int lda,
    const unsigned short* __restrict__ W, int ldw,
    void* __restrict__ Cv, int ldc, int K)
{
    __shared__ unsigned short As[128 * 32];
    __shared__ unsigned short Bs[128 * 32];
    const int tid = threadIdx.x;
    const int w = tid >> 6;
    const int l = tid & 63;
    const int wr = w >> 1, wc = w & 1;
    const int tm0 = blockIdx.y * 128;
    const int tn0 = blockIdx.x * 128;

    const int srow = (w << 4) + (l >> 2);
    const int scol = (l & 3) * 8;
    unsigned short* ldsA0 = &As[(w << 4) * 32];
    unsigned short* ldsA1 = &As[(64 + (w << 4)) * 32];
    unsigned short* ldsB0 = &Bs[(w << 4) * 32];
    unsigned short* ldsB1 = &Bs[(64 + (w << 4)) * 32];
    const unsigned short* gA0 = A + (size_t)(tm0 + srow) * lda + scol;
    const unsigned short* gA1 = A + (size_t)(tm0 + 64 + srow) * lda + scol;
    const unsigned short* gB0 = W + (size_t)(tn0 + srow) * ldw + scol;
    const unsigned short* gB1 = W + (size_t)(tn0 + 64 + srow) * ldw + scol;

    const int aoff = ((wr << 6) + (l & 15)) * 32 + ((l >> 4) << 3);
    const int boff = ((wc << 6) + (l & 15)) * 32 + ((l >> 4) << 3);

    f4 acc[4][4];
#pragma unroll
    for (int i = 0; i < 4; ++i)
#pragma unroll
        for (int j = 0; j < 4; ++j) acc[i][j] = 0.f;

    for (int k0 = 0; k0 < K; k0 += 32) {
        GLL16(gA0 + k0, ldsA0);
        GLL16(gA1 + k0, ldsA1);
        GLL16(gB0 + k0, ldsB0);
        GLL16(gB1 + k0, ldsB1);
        __syncthreads();
        bh8 af[4], bf[4];
#pragma unroll
        for (int mi = 0; mi < 4; ++mi) af[mi] = *(const bh8*)&As[aoff + mi * 512];
#pragma unroll
        for (int ni = 0; ni < 4; ++ni) bf[ni] = *(const bh8*)&Bs[boff + ni * 512];
#pragma unroll
        for (int mi = 0; mi < 4; ++mi)
#pragma unroll
            for (int ni = 0; ni < 4; ++ni)
                acc[mi][ni] = __builtin_amdgcn_mfma_f32_16x16x32_bf16(
                    af[mi], bf[ni], acc[mi][ni], 0, 0, 0);
        __syncthreads();
    }

    const int crow0 = tm0 + (wr << 6) + ((l >> 4) << 2);
    const int ccol0 = tn0 + (wc << 6) + (l & 15);
#pragma unroll
    for (int mi = 0; mi < 4; ++mi)
#pragma unroll
        for (int ni = 0; ni < 4; ++ni)
#pragma unroll
            for (int r = 0; r < 4; ++r) {
                const size_t idx = (size_t)(crow0 + mi * 16 + r) * ldc
                                 + (ccol0 + ni * 16);
                const float v = acc[mi][ni][r];
                if (TC_BF) {
                    ((unsigned short*)Cv)[idx] = f2bf(v);
                } else {
                    float* C = (float*)Cv;
                    C[idx] = ACC ? (C[idx] + v) : v;
                }
            }
}

// ---------------------------------------------------------------------------
// fp32-accumulate vector GEMM: C = act(A @ W^T [+bias]).  TA_BF: A bf16.
// ACT 1: softplus. TC_BF: C bf16.
// ---------------------------------------------------------------------------
template <int TA_BF, int ACT, int TC_BF>
__global__ __launch_bounds__(256) void gemm_nt(
    const void* __restrict__ Av, int lda,
    const float* __restrict__ W, int ldw,
    const float* __restrict__ bias,
    void* __restrict__ Cv, int ldc,
    int M, int N, int K)
{
    __shared__ float As[16][68];
    __shared__ float Ws[16][68];
    const int tid = threadIdx.x;
    const int tx = tid & 15;
    const int ty = tid >> 4;
    const int tm0 = blockIdx.y * 64;
    const int tn0 = blockIdx.x * 64;
    const int r  = tid >> 2;
    const int kq = tid & 3;

    float acc[4][4];
#pragma unroll
    for (int i = 0; i < 4; ++i)
#pragma unroll
        for (int j = 0; j < 4; ++j) acc[i][j] = 0.f;

    for (int k0 = 0; k0 < K; k0 += 16) {
        float4 av = make_float4(0.f, 0.f, 0.f, 0.f);
        if (tm0 + r < M) {
            if (TA_BF) {
                const unsigned short* A = (const unsigned short*)Av;
                ushort4 t = *(const ushort4*)&A[(size_t)(tm0 + r) * lda + k0 + kq * 4];
                av = make_float4(bf2f(t.x), bf2f(t.y), bf2f(t.z), bf2f(t.w));
            } else {
                const float* A = (const float*)Av;
                av = *(const float4*)&A[(size_t)(tm0 + r) * lda + k0 + kq * 4];
            }
        }
        As[kq * 4 + 0][r] = av.x;
        As[kq * 4 + 1][r] = av.y;
        As[kq * 4 + 2][r] = av.z;
        As[kq * 4 + 3][r] = av.w;

        float4 wv = make_float4(0.f, 0.f, 0.f, 0.f);
        if (tn0 + r < N)
            wv = *(const float4*)&W[(size_t)(tn0 + r) * ldw + k0 + kq * 4];
        Ws[kq * 4 + 0][r] = wv.x;
        Ws[kq * 4 + 1][r] = wv.y;
        Ws[kq * 4 + 2][r] = wv.z;
        Ws[kq * 4 + 3][r] = wv.w;

        __syncthreads();
#pragma unroll
        for (int kk = 0; kk < 16; ++kk) {
            const float4 a = *(const float4*)&As[kk][ty * 4];
            const float4 b = *(const float4*)&Ws[kk][tx * 4];
            acc[0][0] += a.x * b.x; acc[0][1] += a.x * b.y; acc[0][2] += a.x * b.z; acc[0][3] += a.x * b.w;
            acc[1][0] += a.y * b.x; acc[1][1] += a.y * b.y; acc[1][2] += a.y * b.z; acc[1][3] += a.y * b.w;
            acc[2][0] += a.z * b.x; acc[2][1] += a.z * b.y; acc[2][2] += a.z * b.z; acc[2][3] += a.z * b.w;
            acc[3][0] += a.w * b.x; acc[3][1] += a.w * b.y; acc[3][2] += a.w * b.z; acc[3][3] += a.w * b.w;
        }
        __syncthreads();
    }

#pragma unroll
    for (int i = 0; i < 4; ++i) {
        const int m = tm0 + ty * 4 + i;
        if (m >= M) continue;
#pragma unroll
        for (int j = 0; j < 4; ++j) {
            const int n = tn0 + tx * 4 + j;
            if (n >= N) continue;
            float v = acc[i][j];
            if (ACT == 1) {
                v += bias[n];
                if (v <= 20.f)
                    v = __builtin_amdgcn_logf(1.f + __builtin_amdgcn_exp2f(v * LOG2E)) * LN2;
            }
            const size_t idx = (size_t)m * ldc + n;
            if (TC_BF) ((unsigned short*)Cv)[idx] = f2bf(v);
            else       ((float*)Cv)[idx] = v;
        }
    }
}

// ---------------------------------------------------------------------------
__global__ __launch_bounds__(256) void cast_f32_bf16(
    const float* __restrict__ in, unsigned short* __restrict__ out, int n4)
{
    const int i = blockIdx.x * 256 + threadIdx.x;
    if (i >= n4) return;
    const float4 v = ((const float4*)in)[i];
    ushort4 o;
    o.x = f2bf(v.x); o.y = f2bf(v.y); o.z = f2bf(v.z); o.w = f2bf(v.w);
    ((ushort4*)out)[i] = o;
}

// ---------------------------------------------------------------------------
// Causal depthwise conv1d + SiLU on bf16 (row-major). DIR=0 taps l-j; DIR=1 l+j.
// ---------------------------------------------------------------------------
template <int DIR>
__global__ __launch_bounds__(256) void conv_silu(
    const unsigned short* __restrict__ xz, const float* __restrict__ conv_w,
    const float* __restrict__ conv_b, unsigned short* __restrict__ uc)
{
    const int idx = blockIdx.x * 256 + threadIdx.x;
    if (idx >= NROWS * D_INNER) return;
    const int d = idx % D_INNER;
    const int row = idx / D_INNER;
    const int l = row % SEQ;

    float acc = conv_b[d];
#pragma unroll
    for (int j = 0; j < 4; ++j) {
        const int ll = DIR ? (l + j) : (l - j);
        if (ll >= 0 && ll < SEQ)
            acc = fmaf(bf2f(xz[(size_t)(row - l + ll) * NXZ + d]),
                       conv_w[d * 4 + (3 - j)], acc);
    }
    uc[idx] = f2bf(acc * fsigm(acc));
}

// ---------------------------------------------------------------------------
// Chunked selective scan, one THREAD per (channel, chunk): h[16] in registers,
// no cross-lane ops. Row-major streams: dt/u/z coalesce across d; B/C are
// block-uniform -> staged to LDS once per chunk, broadcast-read.
//
// scan1_d (chunks 0..NCHUNK-2): F = local final state (h0=0), Sdt = sum(dt).
// scan_comb: in-place prefix fold: Fb[c-1] <- H_start(c), P = exp2(A2*Sdt).
// scan2_d (all chunks): full scan from H_start, y*silu(z) overwrites dt.
// ---------------------------------------------------------------------------
template <int DIR>
__global__ __launch_bounds__(256) void scan1_d(
    const float* __restrict__ dtBC, const unsigned short* __restrict__ uc,
    const float* __restrict__ A_log, const unsigned short* __restrict__ xz,
    float* __restrict__ Fb, float* __restrict__ Sd)
{
    __shared__ float bs[CL][20];           // B tile, padded row (80B)
    const int tid = threadIdx.x;
    const int c    = blockIdx.x / (DBLKS * BATCH);
    const int rem  = blockIdx.x % (DBLKS * BATCH);
    const int b    = rem / DBLKS;
    const int dblk = rem % DBLKS;
    const int d = dblk * 256 + tid;
    const long l0 = DIR ? (SEQ - 1 - c * CL) : (c * CL);

    {   // stage B: 2 threads/row, 8 floats each
        const int rk = tid >> 1, half = tid & 1;
        const long l = DIR ? (l0 - rk) : (l0 + rk);
        const float* src = &dtBC[((size_t)b * SEQ + l) * NDBC + DT_RANK + half * 8];
        *(f4*)&bs[rk][half * 8]     = *(const f4*)src;
        *(f4*)&bs[rk][half * 8 + 4] = *(const f4*)(src + 4);
    }
    __syncthreads();

    float A2[16];
#pragma unroll
    for (int n = 0; n < 16; ++n)
        A2[n] = -expf(A_log[d * D_STATE + n]) * LOG2E;

    const unsigned short* pdt = xz + (size_t)b * SEQ * NXZ + d;
    const unsigned short* pu  = uc + (size_t)b * SEQ * D_INNER + d;

    float h[16];
#pragma unroll
    for (int n = 0; n < 16; ++n) h[n] = 0.f;
    float sdt = 0.f;

    float dt8a[8], u8a[8], dt8b[8], u8b[8];
    auto LOAD = [&](float* dt8, float* u8, int k0) {
#pragma unroll
        for (int j = 0; j < 8; ++j) {
            const long l = DIR ? (l0 - (k0 + j)) : (l0 + (k0 + j));
            dt8[j] = bf2f(pdt[l * NXZ]);
            u8[j]  = bf2f(pu[l * D_INNER]);
        }
    };
    auto COMP = [&](const float* dt8, const float* u8, int k0) {
#pragma unroll
        for (int j = 0; j < 8; ++j) {
            const float dt = dt8[j];
            const float dtu = dt * u8[j];
            sdt += dt;
            const int k = k0 + j;
#pragma unroll
            for (int q = 0; q < 4; ++q) {
                const f4 Bq = *(const f4*)&bs[k][q * 4];
#pragma unroll
                for (int e = 0; e < 4; ++e) {
                    const int n = q * 4 + e;
                    const float dA = __builtin_amdgcn_exp2f(dt * A2[n]);
                    h[n] = fmaf(dA, h[n], dtu * Bq[e]);
                }
            }
        }
    };
    LOAD(dt8a, u8a, 0);
    for (int k0 = 0; k0 < CL; k0 += 16) {
        LOAD(dt8b, u8b, k0 + 8);
        COMP(dt8a, u8a, k0);
        if (k0 + 16 < CL) LOAD(dt8a, u8a, k0 + 16);
        COMP(dt8b, u8b, k0 + 8);
    }

    const int ch = b * D_INNER + d;
    float* fdst = Fb + ((size_t)c * NCH + ch) * 16;
#pragma unroll
    for (int n = 0; n < 16; ++n) fdst[n] = h[n];
    Sd[(size_t)c * NCH + ch] = sdt;
}

__global__ __launch_bounds__(256) void scan_comb(
    float* __restrict__ Fb, const float* __restrict__ Sd,
    const float* __restrict__ A_log)
{
    const int i = blockIdx.x * 256 + threadIdx.x;   // ch*16+n
    const int ch = i >> 4, n = i & 15;
    const int d = ch % D_INNER;
    const float A2 = -expf(A_log[d * D_STATE + n]) * LOG2E;
    float h = Fb[i];                                 // F(0) = H_start(1)
    for (int cc = 1; cc < NCHUNK - 1; ++cc) {
        const float P = __builtin_amdgcn_exp2f(A2 * Sd[(size_t)cc * NCH + ch]);
        h = fmaf(P, h, Fb[(size_t)cc * (NCH * 16) + i]);
        Fb[(size_t)cc * (NCH * 16) + i] = h;         // H_start(cc+1)
    }
}

template <int DIR>
__global__ __launch_bounds__(256) void scan2_d(
    const float* __restrict__ dtBC, const unsigned short* __restrict__ uc,
    const float* __restrict__ A_log, const float* __restrict__ D_skip,
    unsigned short* __restrict__ xz, const float* __restrict__ Fb)
{
    __shared__ float bs[CL][36];           // B[0..16) C[16..32), padded row
    const int tid = threadIdx.x;
    const int c    = blockIdx.x / (DBLKS * BATCH);
    const int rem  = blockIdx.x % (DBLKS * BATCH);
    const int b    = rem / DBLKS;
    const int dblk = rem % DBLKS;
    const int d = dblk * 256 + tid;
    const long l0 = DIR ? (SEQ - 1 - c * CL) : (c * CL);

    {   // stage B+C: 2 threads/row, 16 floats each
        const int rk = tid >> 1, half = tid & 1;
        const long l = DIR ? (l0 - rk) : (l0 + rk);
        const float* src = &dtBC[((size_t)b * SEQ + l) * NDBC + DT_RANK + half * 16];
        *(f4*)&bs[rk][half * 16]      = *(const f4*)src;
        *(f4*)&bs[rk][half * 16 + 4]  = *(const f4*)(src + 4);
        *(f4*)&bs[rk][half * 16 + 8]  = *(const f4*)(src + 8);
        *(f4*)&bs[rk][half * 16 + 12] = *(const f4*)(src + 12);
    }
    __syncthreads();

    float A2[16];
#pragma unroll
    for (int n = 0; n < 16; ++n)
        A2[n] = -expf(A_log[d * D_STATE + n]) * LOG2E;
    const float Dv = D_skip[d];

    const unsigned short* pdt = xz + (size_t)b * SEQ * NXZ + d;
    const unsigned short* pz  = pdt + D_INNER;
    const unsigned short* pu  = uc + (size_t)b * SEQ * D_INNER + d;
    unsigned short* pout = xz + (size_t)b * SEQ * NXZ + d;

    const int ch = b * D_INNER + d;
    float h[16];
    if (c == 0) {
#pragma unroll
        for (int n = 0; n < 16; ++n) h[n] = 0.f;
    } else {
        const float* hsrc = Fb + ((size_t)(c - 1) * NCH + ch) * 16;
#pragma unroll
        for (int n = 0; n < 16; ++n) h[n] = hsrc[n];
    }

    float dt8a[8], u8a[8], z8a[8], dt8b[8], u8b[8], z8b[8];
    auto LOAD = [&](float* dt8, float* u8, float* z8, int k0) {
#pragma unroll
        for (int j = 0; j < 8; ++j) {
            const long l = DIR ? (l0 - (k0 + j)) : (l0 + (k0 + j));
            dt8[j] = bf2f(pdt[l * NXZ]);
            u8[j]  = bf2f(pu[l * D_INNER]);
            z8[j]  = bf2f(pz[l * NXZ]);
        }
    };
    auto COMP = [&](const float* dt8, const float* u8, const float* z8, int k0) {
#pragma unroll
        for (int j = 0; j < 8; ++j) {
            const float dt = dt8[j];
            const float dtu = dt * u8[j];
            float ya[4];
            ya[0] = u8[j] * Dv; ya[1] = 0.f; ya[2] = 0.f; ya[3] = 0.f;
            const int k = k0 + j;
#pragma unroll
            for (int q = 0; q < 4; ++q) {
                const f4 Bq = *(const f4*)&bs[k][q * 4];
                const f4 Cq = *(const f4*)&bs[k][16 + q * 4];
#pragma unroll
                for (int e = 0; e < 4; ++e) {
                    const int n = q * 4 + e;
                    const float dA = __builtin_amdgcn_exp2f(dt * A2[n]);
                    h[n] = fmaf(dA, h[n], dtu * Bq[e]);
                    ya[e] = fmaf(h[n], Cq[e], ya[e]);
                }
            }
            const float y = (ya[0] + ya[1]) + (ya[2] + ya[3]);
            const float zv = z8[j];
            const long l = DIR ? (l0 - k) : (l0 + k);
            pout[l * NXZ] = f2bf(y * (zv * fsigm(zv)));
        }
    };
    LOAD(dt8a, u8a, z8a, 0);
    for (int k0 = 0; k0 < CL; k0 += 16) {
        LOAD(dt8b, u8b, z8b, k0 + 8);
        COMP(dt8a, u8a, z8a, k0);
        if (k0 + 16 < CL) LOAD(dt8a, u8a, z8a, k0 + 16);
        COMP(dt8b, u8b, z8b, k0 + 8);
    }
}

// ---------------------------------------------------------------------------
// In-place: out = LN(out + x) * g + b
// ---------------------------------------------------------------------------
__global__ __launch_bounds__(256) void fuse_ln(
    float* __restrict__ out, const float* __restrict__ x,
    const float* __restrict__ g, const float* __restrict__ bta)
{
    const int row = blockIdx.x;
    const size_t base = (size_t)row * D_MODEL;
    float vals[3];
    float s = 0.f, s2 = 0.f;
#pragma unroll
    for (int i = 0; i < 3; ++i) {
        const int c = threadIdx.x + i * 256;
        const float v = out[base + c] + x[base + c];
        vals[i] = v;
        s += v;
        s2 += v * v;
    }
#pragma unroll
    for (int o = 32; o >= 1; o >>= 1) {
        s  += __shfl_xor(s, o, 64);
        s2 += __shfl_xor(s2, o, 64);
    }
    __shared__ float ls[4], ls2[4];
    const int wid = threadIdx.x >> 6;
    if ((threadIdx.x & 63) == 0) { ls[wid] = s; ls2[wid] = s2; }
    __syncthreads();
    s  = ls[0] + ls[1] + ls[2] + ls[3];
    s2 = ls2[0] + ls2[1] + ls2[2] + ls2[3];
    const float mu  = s * (1.f / D_MODEL);
    const float var = s2 * (1.f / D_MODEL) - mu * mu;
    const float inv = 1.f / sqrtf(var + 1e-12f);
#pragma unroll
    for (int i = 0; i < 3; ++i) {
        const int c = threadIdx.x + i * 256;
        out[base + c] = (vals[i] - mu) * inv * g[c] + bta[c];
    }
}

// ---------------------------------------------------------------------------
extern "C" void kernel_launch(void* const* d_in, const int* in_sizes, int n_in,
                              void* d_out, int out_size, void* d_ws, size_t ws_size,
                              hipStream_t stream)
{
    const float* x = (const float*)d_in[0];
    const float* ln_g = (const float*)d_in[19];
    const float* ln_b = (const float*)d_in[20];

    // workspace (~201 MB, all row-major)
    float* dtBC = (float*)d_ws;                                        //  5.2 MB
    unsigned short* xz  = (unsigned short*)(dtBC + (size_t)NROWS * NDBC); // 100.7 MB
    unsigned short* uc  = xz + (size_t)NROWS * NXZ;                    // 50.3 MB
    unsigned short* xbf = uc + (size_t)NROWS * D_INNER;                // 25.2 MB
    unsigned short* wbf_in  = xbf + (size_t)NROWS * D_MODEL;           //  4.7 MB
    unsigned short* wbf_out = wbf_in + (size_t)NXZ * D_MODEL;          //  2.4 MB
    float* Fb = (float*)(wbf_out + (size_t)D_MODEL * D_INNER);         // 11.8 MB
    float* Sd = Fb + (size_t)(NCHUNK - 1) * NCH * 16;                  //  0.74 MB
    const size_t needed = ((size_t)NROWS * NDBC) * 4
        + ((size_t)NROWS * NXZ + (size_t)NROWS * D_INNER + (size_t)NROWS * D_MODEL
           + (size_t)NXZ * D_MODEL + (size_t)D_MODEL * D_INNER) * 2
        + (size_t)(NCHUNK - 1) * NCH * 16 * 4
        + (size_t)(NCHUNK - 1) * NCH * 4;
    if (ws_size < needed) return;  // fail absmax cleanly instead of faulting

    float* outp = (float*)d_out;

    cast_f32_bf16<<<(NROWS * D_MODEL / 4 + 255) / 256, 256, 0, stream>>>(
        x, xbf, NROWS * D_MODEL / 4);

    for (int dir = 0; dir < 2; ++dir) {
        const float* in_w    = (const float*)d_in[1 + dir * 9 + 0];
        const float* conv_w  = (const float*)d_in[1 + dir * 9 + 1];
        const float* conv_b  = (const float*)d_in[1 + dir * 9 + 2];
        const float* xproj_w = (const float*)d_in[1 + dir * 9 + 3];
        const float* dt_w    = (const float*)d_in[1 + dir * 9 + 4];
        const float* dt_b    = (const float*)d_in[1 + dir * 9 + 5];
        const float* A_log   = (const float*)d_in[1 + dir * 9 + 6];
        const float* D_skip  = (const float*)d_in[1 + dir * 9 + 7];
        const float* out_w   = (const float*)d_in[1 + dir * 9 + 8];

        cast_f32_bf16<<<(NXZ * D_MODEL / 4 + 255) / 256, 256, 0, stream>>>(
            in_w, wbf_in, NXZ * D_MODEL / 4);
        cast_f32_bf16<<<(D_MODEL * D_INNER / 4 + 255) / 256, 256, 0, stream>>>(
            out_w, wbf_out, D_MODEL * D_INNER / 4);

        // xz = x @ in_w^T  (16384 x 3072, K=768)  MFMA -> bf16
        gemm_mfma<1, 0><<<dim3(NXZ / 128, NROWS / 128), 256, 0, stream>>>(
            xbf, D_MODEL, wbf_in, D_MODEL, xz, NXZ, D_MODEL);

        // uc = silu(conv(u) + b)
        if (dir == 0)
            conv_silu<0><<<(NROWS * D_INNER + 255) / 256, 256, 0, stream>>>(
                xz, conv_w, conv_b, uc);
        else
            conv_silu<1><<<(NROWS * D_INNER + 255) / 256, 256, 0, stream>>>(
                xz, conv_w, conv_b, uc);

        // dtBC = uc @ xproj_w^T   (16384 x 80, K=1536)
        gemm_nt<1, 0, 0><<<dim3((NDBC + 63) / 64, NROWS / 64), 256, 0, stream>>>(
            uc, D_INNER, xproj_w, D_INNER, nullptr, dtBC, NDBC, NROWS, NDBC, D_INNER);

        // dt = softplus(dtBC[:, :48] @ dt_w^T + dt_b) -> overlay xz u-half
        gemm_nt<0, 1, 1><<<dim3(D_INNER / 64, NROWS / 64), 256, 0, stream>>>(
            dtBC, NDBC, dt_w, DT_RANK, dt_b, xz, NXZ, NROWS, D_INNER, DT_RANK);

        // chunked scan: pass1 -> combine -> pass2
        if (dir == 0) {
            scan1_d<0><<<(NCHUNK - 1) * DBLKS * BATCH, 256, 0, stream>>>(
                dtBC, uc, A_log, xz, Fb, Sd);
            scan_comb<<<NCH * 16 / 256, 256, 0, stream>>>(Fb, Sd, A_log);
            scan2_d<0><<<NCHUNK * DBLKS * BATCH, 256, 0, stream>>>(
                dtBC, uc, A_log, D_skip, xz, Fb);
        } else {
            scan1_d<1><<<(NCHUNK - 1) * DBLKS * BATCH, 256, 0, stream>>>(
                dtBC, uc, A_log, xz, Fb, Sd);
            scan_comb<<<NCH * 16 / 256, 256, 0, stream>>>(Fb, Sd, A_log);
            scan2_d<1><<<NCHUNK * DBLKS * BATCH, 256, 0, stream>>>(
                dtBC, uc, A_log, D_skip, xz, Fb);
        }

        // outp (+)= y' @ out_w^T   (16384 x 768, K=1536)  MFMA -> fp32
        if (dir == 0)
            gemm_mfma<0, 0><<<dim3(D_MODEL / 128, NROWS / 128), 256, 0, stream>>>(
                xz, NXZ, wbf_out, D_INNER, outp, D_MODEL, D_INNER);
        else
            gemm_mfma<0, 1><<<dim3(D_MODEL / 128, NROWS / 128), 256, 0, stream>>>(
                xz, NXZ, wbf_out, D_INNER, outp, D_MODEL, D_INNER);
    }

    fuse_ln<<<NROWS, 256, 0, stream>>>(outp, x, ln_g, ln_b);
}

// Round 9
// 1103.352 us; speedup vs baseline: 4.9467x; 1.1953x over previous
//
#include <hip/hip_runtime.h>
#include <math.h>

#define D_MODEL 768
#define D_INNER 1536
#define D_STATE 16
#define DCONV 4
#define DT_RANK 48
#define BATCH 8
#define SEQ 2048
#define NROWS (BATCH * SEQ)          // 16384
#define NXZ (2 * D_INNER)            // 3072
#define NDBC (DT_RANK + 2 * D_STATE) // 80

#define NCHUNK 16
#define CL (SEQ / NCHUNK)            // 128 steps per chunk
#define NCH (BATCH * D_INNER)        // 12288 channels
#define DBLKS (D_INNER / 256)        // 6 blocks of 256 d-channels

#define LOG2E 1.4426950408889634f
#define LN2   0.6931471805599453f

typedef __attribute__((ext_vector_type(8))) short bh8;   // MFMA A/B frag
typedef __attribute__((ext_vector_type(4))) float f4;

__device__ __forceinline__ float bf2f(unsigned short u) {
    return __uint_as_float(((unsigned int)u) << 16);
}
__device__ __forceinline__ unsigned short f2bf(float f) {
    unsigned int x = __float_as_uint(f);
    return (unsigned short)((x + 0x7fffu + ((x >> 16) & 1u)) >> 16);
}
__device__ __forceinline__ float fsigm(float x) {
    return __builtin_amdgcn_rcpf(1.f + __builtin_amdgcn_exp2f(-x * LOG2E));
}

#define GLL16(gp, lp) __builtin_amdgcn_global_load_lds( \
    (const __attribute__((address_space(1))) void*)(gp), \
    (__attribute__((address_space(3))) void*)(lp), 16, 0, 0)

// ---------------------------------------------------------------------------
// bf16 MFMA GEMM (NT): C = A(MxK) @ W(NxK)^T. 128x128 tile, BK=32, 4 waves.
// TC_BF: C bf16. ACC: fp32 C +=. ACT 1: softplus(v + bias[n]) before store.
// ---------------------------------------------------------------------------
template <int TC_BF, int ACC, int ACT>
__global__ __launch_bounds__(256) void gemm_mfma(
    const unsigned short* __restrict__ A, int lda,
    const unsigned short* __restrict__ W, int ldw,
    const float* __restrict__ bias,
    void* __restrict__ Cv, int ldc, int K)
{
    __shared__ unsigned short As[128 * 32];
    __shared__ unsigned short Bs[128 * 32];
    const int tid = threadIdx.x;
    const int w = tid >> 6;
    const int l = tid & 63;
    const int wr = w >> 1, wc = w & 1;
    const int tm0 = blockIdx.y * 128;
    const int tn0 = blockIdx.x * 128;

    const int srow = (w << 4) + (l >> 2);
    const int scol = (l & 3) * 8;
    unsigned short* ldsA0 = &As[(w << 4) * 32];
    unsigned short* ldsA1 = &As[(64 + (w << 4)) * 32];
    unsigned short* ldsB0 = &Bs[(w << 4) * 32];
    unsigned short* ldsB1 = &Bs[(64 + (w << 4)) * 32];
    const unsigned short* gA0 = A + (size_t)(tm0 + srow) * lda + scol;
    const unsigned short* gA1 = A + (size_t)(tm0 + 64 + srow) * lda + scol;
    const unsigned short* gB0 = W + (size_t)(tn0 + srow) * ldw + scol;
    const unsigned short* gB1 = W + (size_t)(tn0 + 64 + srow) * ldw + scol;

    const int aoff = ((wr << 6) + (l & 15)) * 32 + ((l >> 4) << 3);
    const int boff = ((wc << 6) + (l & 15)) * 32 + ((l >> 4) << 3);

    f4 acc[4][4];
#pragma unroll
    for (int i = 0; i < 4; ++i)
#pragma unroll
        for (int j = 0; j < 4; ++j) acc[i][j] = 0.f;

    for (int k0 = 0; k0 < K; k0 += 32) {
        GLL16(gA0 + k0, ldsA0);
        GLL16(gA1 + k0, ldsA1);
        GLL16(gB0 + k0, ldsB0);
        GLL16(gB1 + k0, ldsB1);
        __syncthreads();
        bh8 af[4], bf[4];
#pragma unroll
        for (int mi = 0; mi < 4; ++mi) af[mi] = *(const bh8*)&As[aoff + mi * 512];
#pragma unroll
        for (int ni = 0; ni < 4; ++ni) bf[ni] = *(const bh8*)&Bs[boff + ni * 512];
#pragma unroll
        for (int mi = 0; mi < 4; ++mi)
#pragma unroll
            for (int ni = 0; ni < 4; ++ni)
                acc[mi][ni] = __builtin_amdgcn_mfma_f32_16x16x32_bf16(
                    af[mi], bf[ni], acc[mi][ni], 0, 0, 0);
        __syncthreads();
    }

    const int crow0 = tm0 + (wr << 6) + ((l >> 4) << 2);
    const int ccol0 = tn0 + (wc << 6) + (l & 15);
#pragma unroll
    for (int mi = 0; mi < 4; ++mi)
#pragma unroll
        for (int ni = 0; ni < 4; ++ni)
#pragma unroll
            for (int r = 0; r < 4; ++r) {
                const int n = ccol0 + ni * 16;
                const size_t idx = (size_t)(crow0 + mi * 16 + r) * ldc + n;
                float v = acc[mi][ni][r];
                if (ACT == 1) {
                    v += bias[n];
                    if (v <= 20.f)
                        v = __builtin_amdgcn_logf(1.f + __builtin_amdgcn_exp2f(v * LOG2E)) * LN2;
                }
                if (TC_BF) {
                    ((unsigned short*)Cv)[idx] = f2bf(v);
                } else {
                    float* C = (float*)Cv;
                    C[idx] = ACC ? (C[idx] + v) : v;
                }
            }
}

// ---------------------------------------------------------------------------
// x_proj MFMA: M=NROWS, N=128 (80 valid), K=1536. Dual epilogue:
//   fp32 dtBC[m][n] for n<80  (scan B/C + dt-rank)
//   bf16 dtR [m][n] for n<64  (dt-rank(48) | B(16), input of dt GEMM)
// Weight rows 80..127 of Wp are garbage; their outputs are discarded.
// ---------------------------------------------------------------------------
__global__ __launch_bounds__(256) void gemm_mfma_xp(
    const unsigned short* __restrict__ A, int lda,
    const unsigned short* __restrict__ Wp,
    float* __restrict__ dtBC, unsigned short* __restrict__ dtR, int K)
{
    __shared__ unsigned short As[128 * 32];
    __shared__ unsigned short Bs[128 * 32];
    const int tid = threadIdx.x;
    const int w = tid >> 6;
    const int l = tid & 63;
    const int wr = w >> 1, wc = w & 1;
    const int tm0 = blockIdx.y * 128;

    const int srow = (w << 4) + (l >> 2);
    const int scol = (l & 3) * 8;
    unsigned short* ldsA0 = &As[(w << 4) * 32];
    unsigned short* ldsA1 = &As[(64 + (w << 4)) * 32];
    unsigned short* ldsB0 = &Bs[(w << 4) * 32];
    unsigned short* ldsB1 = &Bs[(64 + (w << 4)) * 32];
    const unsigned short* gA0 = A + (size_t)(tm0 + srow) * lda + scol;
    const unsigned short* gA1 = A + (size_t)(tm0 + 64 + srow) * lda + scol;
    const unsigned short* gB0 = Wp + (size_t)srow * lda + scol;
    const unsigned short* gB1 = Wp + (size_t)(64 + srow) * lda + scol;

    const int aoff = ((wr << 6) + (l & 15)) * 32 + ((l >> 4) << 3);
    const int boff = ((wc << 6) + (l & 15)) * 32 + ((l >> 4) << 3);

    f4 acc[4][4];
#pragma unroll
    for (int i = 0; i < 4; ++i)
#pragma unroll
        for (int j = 0; j < 4; ++j) acc[i][j] = 0.f;

    for (int k0 = 0; k0 < K; k0 += 32) {
        GLL16(gA0 + k0, ldsA0);
        GLL16(gA1 + k0, ldsA1);
        GLL16(gB0 + k0, ldsB0);
        GLL16(gB1 + k0, ldsB1);
        __syncthreads();
        bh8 af[4], bf[4];
#pragma unroll
        for (int mi = 0; mi < 4; ++mi) af[mi] = *(const bh8*)&As[aoff + mi * 512];
#pragma unroll
        for (int ni = 0; ni < 4; ++ni) bf[ni] = *(const bh8*)&Bs[boff + ni * 512];
#pragma unroll
        for (int mi = 0; mi < 4; ++mi)
#pragma unroll
            for (int ni = 0; ni < 4; ++ni)
                acc[mi][ni] = __builtin_amdgcn_mfma_f32_16x16x32_bf16(
                    af[mi], bf[ni], acc[mi][ni], 0, 0, 0);
        __syncthreads();
    }

    const int crow0 = tm0 + (wr << 6) + ((l >> 4) << 2);
    const int ccol0 = (wc << 6) + (l & 15);
#pragma unroll
    for (int mi = 0; mi < 4; ++mi)
#pragma unroll
        for (int ni = 0; ni < 4; ++ni) {
            const int n = ccol0 + ni * 16;
            if (n >= 80) continue;
#pragma unroll
            for (int r = 0; r < 4; ++r) {
                const int m = crow0 + mi * 16 + r;
                const float v = acc[mi][ni][r];
                dtBC[(size_t)m * NDBC + n] = v;
                if (n < 64) dtR[(size_t)m * 64 + n] = f2bf(v);
            }
        }
}

// ---------------------------------------------------------------------------
__global__ __launch_bounds__(256) void cast_f32_bf16(
    const float* __restrict__ in, unsigned short* __restrict__ out, int n4)
{
    const int i = blockIdx.x * 256 + threadIdx.x;
    if (i >= n4) return;
    const float4 v = ((const float4*)in)[i];
    ushort4 o;
    o.x = f2bf(v.x); o.y = f2bf(v.y); o.z = f2bf(v.z); o.w = f2bf(v.w);
    ((ushort4*)out)[i] = o;
}

// dt_w [1536][48] fp32 -> padded [1536][64] bf16 (cols 48..63 = 0)
__global__ __launch_bounds__(256) void cast_dtw(
    const float* __restrict__ in, unsigned short* __restrict__ out)
{
    const int i = blockIdx.x * 256 + threadIdx.x;
    if (i >= D_INNER * 64) return;
    const int d = i >> 6, k = i & 63;
    out[i] = (k < DT_RANK) ? f2bf(in[d * DT_RANK + k]) : (unsigned short)0;
}

// ---------------------------------------------------------------------------
// Causal depthwise conv1d + SiLU on bf16 (row-major). DIR=0 taps l-j; DIR=1 l+j.
// ---------------------------------------------------------------------------
template <int DIR>
__global__ __launch_bounds__(256) void conv_silu(
    const unsigned short* __restrict__ xz, const float* __restrict__ conv_w,
    const float* __restrict__ conv_b, unsigned short* __restrict__ uc)
{
    const int idx = blockIdx.x * 256 + threadIdx.x;
    if (idx >= NROWS * D_INNER) return;
    const int d = idx % D_INNER;
    const int row = idx / D_INNER;
    const int l = row % SEQ;

    float acc = conv_b[d];
#pragma unroll
    for (int j = 0; j < 4; ++j) {
        const int ll = DIR ? (l + j) : (l - j);
        if (ll >= 0 && ll < SEQ)
            acc = fmaf(bf2f(xz[(size_t)(row - l + ll) * NXZ + d]),
                       conv_w[d * 4 + (3 - j)], acc);
    }
    uc[idx] = f2bf(acc * fsigm(acc));
}

// ---------------------------------------------------------------------------
// Chunked selective scan, one THREAD per (channel, chunk): h[16] in registers.
// scan1_d: F = local final state (h0=0), Sdt = sum(dt).
// scan_comb: prefix fold Fb[c-1] <- H_start(c) via P = exp2(A2*Sdt).
// scan2_d: full scan from H_start, y*silu(z) overwrites dt in xz.
// ---------------------------------------------------------------------------
template <int DIR>
__global__ __launch_bounds__(256) void scan1_d(
    const float* __restrict__ dtBC, const unsigned short* __restrict__ uc,
    const float* __restrict__ A_log, const unsigned short* __restrict__ xz,
    float* __restrict__ Fb, float* __restrict__ Sd)
{
    __shared__ float bs[CL][20];
    const int tid = threadIdx.x;
    const int c    = blockIdx.x / (DBLKS * BATCH);
    const int rem  = blockIdx.x % (DBLKS * BATCH);
    const int b    = rem / DBLKS;
    const int dblk = rem % DBLKS;
    const int d = dblk * 256 + tid;
    const long l0 = DIR ? (SEQ - 1 - c * CL) : (c * CL);

    {
        const int rk = tid >> 1, half = tid & 1;
        const long l = DIR ? (l0 - rk) : (l0 + rk);
        const float* src = &dtBC[((size_t)b * SEQ + l) * NDBC + DT_RANK + half * 8];
        *(f4*)&bs[rk][half * 8]     = *(const f4*)src;
        *(f4*)&bs[rk][half * 8 + 4] = *(const f4*)(src + 4);
    }
    __syncthreads();

    float A2[16];
#pragma unroll
    for (int n = 0; n < 16; ++n)
        A2[n] = -expf(A_log[d * D_STATE + n]) * LOG2E;

    const unsigned short* pdt = xz + (size_t)b * SEQ * NXZ + d;
    const unsigned short* pu  = uc + (size_t)b * SEQ * D_INNER + d;

    float h[16];
#pragma unroll
    for (int n = 0; n < 16; ++n) h[n] = 0.f;
    float sdt = 0.f;

    float dt8a[8], u8a[8], dt8b[8], u8b[8];
    auto LOAD = [&](float* dt8, float* u8, int k0) {
#pragma unroll
        for (int j = 0; j < 8; ++j) {
            const long l = DIR ? (l0 - (k0 + j)) : (l0 + (k0 + j));
            dt8[j] = bf2f(pdt[l * NXZ]);
            u8[j]  = bf2f(pu[l * D_INNER]);
        }
    };
    auto COMP = [&](const float* dt8, const float* u8, int k0) {
#pragma unroll
        for (int j = 0; j < 8; ++j) {
            const float dt = dt8[j];
            const float dtu = dt * u8[j];
            sdt += dt;
            const int k = k0 + j;
#pragma unroll
            for (int q = 0; q < 4; ++q) {
                const f4 Bq = *(const f4*)&bs[k][q * 4];
#pragma unroll
                for (int e = 0; e < 4; ++e) {
                    const int n = q * 4 + e;
                    const float dA = __builtin_amdgcn_exp2f(dt * A2[n]);
                    h[n] = fmaf(dA, h[n], dtu * Bq[e]);
                }
            }
        }
    };
    LOAD(dt8a, u8a, 0);
    for (int k0 = 0; k0 < CL; k0 += 16) {
        LOAD(dt8b, u8b, k0 + 8);
        COMP(dt8a, u8a, k0);
        if (k0 + 16 < CL) LOAD(dt8a, u8a, k0 + 16);
        COMP(dt8b, u8b, k0 + 8);
    }

    const int ch = b * D_INNER + d;
    float* fdst = Fb + ((size_t)c * NCH + ch) * 16;
#pragma unroll
    for (int n = 0; n < 16; ++n) fdst[n] = h[n];
    Sd[(size_t)c * NCH + ch] = sdt;
}

__global__ __launch_bounds__(256) void scan_comb(
    float* __restrict__ Fb, const float* __restrict__ Sd,
    const float* __restrict__ A_log)
{
    const int i = blockIdx.x * 256 + threadIdx.x;   // ch*16+n
    const int ch = i >> 4, n = i & 15;
    const int d = ch % D_INNER;
    const float A2 = -expf(A_log[d * D_STATE + n]) * LOG2E;
    float h = Fb[i];
    for (int cc = 1; cc < NCHUNK - 1; ++cc) {
        const float P = __builtin_amdgcn_exp2f(A2 * Sd[(size_t)cc * NCH + ch]);
        h = fmaf(P, h, Fb[(size_t)cc * (NCH * 16) + i]);
        Fb[(size_t)cc * (NCH * 16) + i] = h;
    }
}

template <int DIR>
__global__ __launch_bounds__(256) void scan2_d(
    const float* __restrict__ dtBC, const unsigned short* __restrict__ uc,
    const float* __restrict__ A_log, const float* __restrict__ D_skip,
    unsigned short* __restrict__ xz, const float* __restrict__ Fb)
{
    __shared__ float bs[CL][36];
    const int tid = threadIdx.x;
    const int c    = blockIdx.x / (DBLKS * BATCH);
    const int rem  = blockIdx.x % (DBLKS * BATCH);
    const int b    = rem / DBLKS;
    const int dblk = rem % DBLKS;
    const int d = dblk * 256 + tid;
    const long l0 = DIR ? (SEQ - 1 - c * CL) : (c * CL);

    {
        const int rk = tid >> 1, half = tid & 1;
        const long l = DIR ? (l0 - rk) : (l0 + rk);
        const float* src = &dtBC[((size_t)b * SEQ + l) * NDBC + DT_RANK + half * 16];
        *(f4*)&bs[rk][half * 16]      = *(const f4*)src;
        *(f4*)&bs[rk][half * 16 + 4]  = *(const f4*)(src + 4);
        *(f4*)&bs[rk][half * 16 + 8]  = *(const f4*)(src + 8);
        *(f4*)&bs[rk][half * 16 + 12] = *(const f4*)(src + 12);
    }
    __syncthreads();

    float A2[16];
#pragma unroll
    for (int n = 0; n < 16; ++n)
        A2[n] = -expf(A_log[d * D_STATE + n]) * LOG2E;
    const float Dv = D_skip[d];

    const unsigned short* pdt = xz + (size_t)b * SEQ * NXZ + d;
    const unsigned short* pz  = pdt + D_INNER;
    const unsigned short* pu  = uc + (size_t)b * SEQ * D_INNER + d;
    unsigned short* pout = xz + (size_t)b * SEQ * NXZ + d;

    const int ch = b * D_INNER + d;
    float h[16];
    if (c == 0) {
#pragma unroll
        for (int n = 0; n < 16; ++n) h[n] = 0.f;
    } else {
        const float* hsrc = Fb + ((size_t)(c - 1) * NCH + ch) * 16;
#pragma unroll
        for (int n = 0; n < 16; ++n) h[n] = hsrc[n];
    }

    float dt8a[8], u8a[8], z8a[8], dt8b[8], u8b[8], z8b[8];
    auto LOAD = [&](float* dt8, float* u8, float* z8, int k0) {
#pragma unroll
        for (int j = 0; j < 8; ++j) {
            const long l = DIR ? (l0 - (k0 + j)) : (l0 + (k0 + j));
            dt8[j] = bf2f(pdt[l * NXZ]);
            u8[j]  = bf2f(pu[l * D_INNER]);
            z8[j]  = bf2f(pz[l * NXZ]);
        }
    };
    auto COMP = [&](const float* dt8, const float* u8, const float* z8, int k0) {
#pragma unroll
        for (int j = 0; j < 8; ++j) {
            const float dt = dt8[j];
            const float dtu = dt * u8[j];
            float ya[4];
            ya[0] = u8[j] * Dv; ya[1] = 0.f; ya[2] = 0.f; ya[3] = 0.f;
            const int k = k0 + j;
#pragma unroll
            for (int q = 0; q < 4; ++q) {
                const f4 Bq = *(const f4*)&bs[k][q * 4];
                const f4 Cq = *(const f4*)&bs[k][16 + q * 4];
#pragma unroll
                for (int e = 0; e < 4; ++e) {
                    const int n = q * 4 + e;
                    const float dA = __builtin_amdgcn_exp2f(dt * A2[n]);
                    h[n] = fmaf(dA, h[n], dtu * Bq[e]);
                    ya[e] = fmaf(h[n], Cq[e], ya[e]);
                }
            }
            const float y = (ya[0] + ya[1]) + (ya[2] + ya[3]);
            const float zv = z8[j];
            const long l = DIR ? (l0 - k) : (l0 + k);
            pout[l * NXZ] = f2bf(y * (zv * fsigm(zv)));
        }
    };
    LOAD(dt8a, u8a, z8a, 0);
    for (int k0 = 0; k0 < CL; k0 += 16) {
        LOAD(dt8b, u8b, z8b, k0 + 8);
        COMP(dt8a, u8a, z8a, k0);
        if (k0 + 16 < CL) LOAD(dt8a, u8a, z8a, k0 + 16);
        COMP(dt8b, u8b, z8b, k0 + 8);
    }
}

// ---------------------------------------------------------------------------
// In-place: out = LN(out + x) * g + b
// ---------------------------------------------------------------------------
__global__ __launch_bounds__(256) void fuse_ln(
    float* __restrict__ out, const float* __restrict__ x,
    const float* __restrict__ g, const float* __restrict__ bta)
{
    const int row = blockIdx.x;
    const size_t base = (size_t)row * D_MODEL;
    float vals[3];
    float s = 0.f, s2 = 0.f;
#pragma unroll
    for (int i = 0; i < 3; ++i) {
        const int c = threadIdx.x + i * 256;
        const float v = out[base + c] + x[base + c];
        vals[i] = v;
        s += v;
        s2 += v * v;
    }
#pragma unroll
    for (int o = 32; o >= 1; o >>= 1) {
        s  += __shfl_xor(s, o, 64);
        s2 += __shfl_xor(s2, o, 64);
    }
    __shared__ float ls[4], ls2[4];
    const int wid = threadIdx.x >> 6;
    if ((threadIdx.x & 63) == 0) { ls[wid] = s; ls2[wid] = s2; }
    __syncthreads();
    s  = ls[0] + ls[1] + ls[2] + ls[3];
    s2 = ls2[0] + ls2[1] + ls2[2] + ls2[3];
    const float mu  = s * (1.f / D_MODEL);
    const float var = s2 * (1.f / D_MODEL) - mu * mu;
    const float inv = 1.f / sqrtf(var + 1e-12f);
#pragma unroll
    for (int i = 0; i < 3; ++i) {
        const int c = threadIdx.x + i * 256;
        out[base + c] = (vals[i] - mu) * inv * g[c] + bta[c];
    }
}

// ---------------------------------------------------------------------------
extern "C" void kernel_launch(void* const* d_in, const int* in_sizes, int n_in,
                              void* d_out, int out_size, void* d_ws, size_t ws_size,
                              hipStream_t stream)
{
    const float* x = (const float*)d_in[0];
    const float* ln_g = (const float*)d_in[19];
    const float* ln_b = (const float*)d_in[20];

    // workspace (~207 MB, all row-major)
    float* dtBC = (float*)d_ws;                                        //  5.2 MB
    unsigned short* xz  = (unsigned short*)(dtBC + (size_t)NROWS * NDBC); // 100.7 MB
    unsigned short* uc  = xz + (size_t)NROWS * NXZ;                    // 50.3 MB
    unsigned short* xbf = uc + (size_t)NROWS * D_INNER;                // 25.2 MB
    unsigned short* wbf_in  = xbf + (size_t)NROWS * D_MODEL;           //  4.7 MB
    unsigned short* wbf_out = wbf_in + (size_t)NXZ * D_MODEL;          //  2.4 MB
    unsigned short* wbf_xp  = wbf_out + (size_t)D_MODEL * D_INNER;     //  0.4 MB [128][1536]
    unsigned short* dtw_pad = wbf_xp + (size_t)128 * D_INNER;          //  0.2 MB [1536][64]
    unsigned short* dtR     = dtw_pad + (size_t)D_INNER * 64;          //  2.1 MB [16384][64]
    float* Fb = (float*)(dtR + (size_t)NROWS * 64);                    // 11.8 MB
    float* Sd = Fb + (size_t)(NCHUNK - 1) * NCH * 16;                  //  0.74 MB
    const size_t needed = ((size_t)NROWS * NDBC) * 4
        + ((size_t)NROWS * NXZ + (size_t)NROWS * D_INNER + (size_t)NROWS * D_MODEL
           + (size_t)NXZ * D_MODEL + (size_t)D_MODEL * D_INNER
           + (size_t)128 * D_INNER + (size_t)D_INNER * 64 + (size_t)NROWS * 64) * 2
        + (size_t)(NCHUNK - 1) * NCH * 16 * 4
        + (size_t)(NCHUNK - 1) * NCH * 4;
    if (ws_size < needed) return;  // fail absmax cleanly instead of faulting

    float* outp = (float*)d_out;

    cast_f32_bf16<<<(NROWS * D_MODEL / 4 + 255) / 256, 256, 0, stream>>>(
        x, xbf, NROWS * D_MODEL / 4);

    for (int dir = 0; dir < 2; ++dir) {
        const float* in_w    = (const float*)d_in[1 + dir * 9 + 0];
        const float* conv_w  = (const float*)d_in[1 + dir * 9 + 1];
        const float* conv_b  = (const float*)d_in[1 + dir * 9 + 2];
        const float* xproj_w = (const float*)d_in[1 + dir * 9 + 3];
        const float* dt_w    = (const float*)d_in[1 + dir * 9 + 4];
        const float* dt_b    = (const float*)d_in[1 + dir * 9 + 5];
        const float* A_log   = (const float*)d_in[1 + dir * 9 + 6];
        const float* D_skip  = (const float*)d_in[1 + dir * 9 + 7];
        const float* out_w   = (const float*)d_in[1 + dir * 9 + 8];

        cast_f32_bf16<<<(NXZ * D_MODEL / 4 + 255) / 256, 256, 0, stream>>>(
            in_w, wbf_in, NXZ * D_MODEL / 4);
        cast_f32_bf16<<<(D_MODEL * D_INNER / 4 + 255) / 256, 256, 0, stream>>>(
            out_w, wbf_out, D_MODEL * D_INNER / 4);
        cast_f32_bf16<<<(NDBC * D_INNER / 4 + 255) / 256, 256, 0, stream>>>(
            xproj_w, wbf_xp, NDBC * D_INNER / 4);
        cast_dtw<<<(D_INNER * 64 + 255) / 256, 256, 0, stream>>>(dt_w, dtw_pad);

        // xz = x @ in_w^T  (16384 x 3072, K=768)  MFMA -> bf16
        gemm_mfma<1, 0, 0><<<dim3(NXZ / 128, NROWS / 128), 256, 0, stream>>>(
            xbf, D_MODEL, wbf_in, D_MODEL, nullptr, xz, NXZ, D_MODEL);

        // uc = silu(conv(u) + b)
        if (dir == 0)
            conv_silu<0><<<(NROWS * D_INNER + 255) / 256, 256, 0, stream>>>(
                xz, conv_w, conv_b, uc);
        else
            conv_silu<1><<<(NROWS * D_INNER + 255) / 256, 256, 0, stream>>>(
                xz, conv_w, conv_b, uc);

        // x_proj MFMA: dtBC fp32 [16384][80] + dtR bf16 [16384][64]
        gemm_mfma_xp<<<dim3(1, NROWS / 128), 256, 0, stream>>>(
            uc, D_INNER, wbf_xp, dtBC, dtR, D_INNER);

        // dt = softplus(dtR @ dtw_pad^T + dt_b)  (K=64) -> overlay xz u-half
        gemm_mfma<1, 0, 1><<<dim3(D_INNER / 128, NROWS / 128), 256, 0, stream>>>(
            dtR, 64, dtw_pad, 64, dt_b, xz, NXZ, 64);

        // chunked scan: pass1 -> combine -> pass2
        if (dir == 0) {
            scan1_d<0><<<(NCHUNK - 1) * DBLKS * BATCH, 256, 0, stream>>>(
                dtBC, uc, A_log, xz, Fb, Sd);
            scan_comb<<<NCH * 16 / 256, 256, 0, stream>>>(Fb, Sd, A_log);
            scan2_d<0><<<NCHUNK * DBLKS * BATCH, 256, 0, stream>>>(
                dtBC, uc, A_log, D_skip, xz, Fb);
        } else {
            scan1_d<1><<<(NCHUNK - 1) * DBLKS * BATCH, 256, 0, stream>>>(
                dtBC, uc, A_log, xz, Fb, Sd);
            scan_comb<<<NCH * 16 / 256, 256, 0, stream>>>(Fb, Sd, A_log);
            scan2_d<1><<<NCHUNK * DBLKS * BATCH, 256, 0, stream>>>(
                dtBC, uc, A_log, D_skip, xz, Fb);
        }

        // outp (+)= y' @ out_w^T   (16384 x 768, K=1536)  MFMA -> fp32
        if (dir == 0)
            gemm_mfma<0, 0, 0><<<dim3(D_MODEL / 128, NROWS / 128), 256, 0, stream>>>(
                xz, NXZ, wbf_out, D_INNER, nullptr, outp, D_MODEL, D_INNER);
        else
            gemm_mfma<0, 1, 0><<<dim3(D_MODEL / 128, NROWS / 128), 256, 0, stream>>>(
                xz, NXZ, wbf_out, D_INNER, nullptr, outp, D_MODEL, D_INNER);
    }

    fuse_ln<<<NROWS, 256, 0, stream>>>(outp, x, ln_g, ln_b);
}

// Round 10
// 987.382 us; speedup vs baseline: 5.5277x; 1.1175x over previous
//
#include <hip/hip_runtime.h>
#include <math.h>

#define D_MODEL 768
#define D_INNER 1536
#define D_STATE 16
#define DCONV 4
#define DT_RANK 48
#define BATCH 8
#define SEQ 2048
#define NROWS (BATCH * SEQ)          // 16384
#define NXZ (2 * D_INNER)            // 3072
#define NDBC (DT_RANK + 2 * D_STATE) // 80

#define NCHUNK 16
#define CL (SEQ / NCHUNK)            // 128 steps per chunk
#define NCH (BATCH * D_INNER)        // 12288 channels
#define DBLKS (D_INNER / 256)        // 6 blocks of 256 d-channels

#define LOG2E 1.4426950408889634f
#define LN2   0.6931471805599453f

typedef __attribute__((ext_vector_type(8))) short bh8;   // MFMA A/B frag
typedef __attribute__((ext_vector_type(4))) float f4;
typedef __attribute__((ext_vector_type(8))) unsigned short us8;

__device__ __forceinline__ float bf2f(unsigned short u) {
    return __uint_as_float(((unsigned int)u) << 16);
}
__device__ __forceinline__ unsigned short f2bf(float f) {
    unsigned int x = __float_as_uint(f);
    return (unsigned short)((x + 0x7fffu + ((x >> 16) & 1u)) >> 16);
}
__device__ __forceinline__ float fsigm(float x) {
    return __builtin_amdgcn_rcpf(1.f + __builtin_amdgcn_exp2f(-x * LOG2E));
}

#define GLL16(gp, lp) __builtin_amdgcn_global_load_lds( \
    (const __attribute__((address_space(1))) void*)(gp), \
    (__attribute__((address_space(3))) void*)(lp), 16, 0, 0)

// ---------------------------------------------------------------------------
// bf16 MFMA GEMM (NT): C = A(MxK) @ W(NxK)^T. 128x128 tile, BK=32, 4 waves.
// TC_BF: C bf16. ACC: fp32 C +=. ACT 1: softplus(v + bias[n]) before store.
// ---------------------------------------------------------------------------
template <int TC_BF, int ACC, int ACT>
__global__ __launch_bounds__(256) void gemm_mfma(
    const unsigned short* __restrict__ A, int lda,
    const unsigned short* __restrict__ W, int ldw,
    const float* __restrict__ bias,
    void* __restrict__ Cv, int ldc, int K)
{
    __shared__ unsigned short As[128 * 32];
    __shared__ unsigned short Bs[128 * 32];
    const int tid = threadIdx.x;
    const int w = tid >> 6;
    const int l = tid & 63;
    const int wr = w >> 1, wc = w & 1;
    const int tm0 = blockIdx.y * 128;
    const int tn0 = blockIdx.x * 128;

    const int srow = (w << 4) + (l >> 2);
    const int scol = (l & 3) * 8;
    unsigned short* ldsA0 = &As[(w << 4) * 32];
    unsigned short* ldsA1 = &As[(64 + (w << 4)) * 32];
    unsigned short* ldsB0 = &Bs[(w << 4) * 32];
    unsigned short* ldsB1 = &Bs[(64 + (w << 4)) * 32];
    const unsigned short* gA0 = A + (size_t)(tm0 + srow) * lda + scol;
    const unsigned short* gA1 = A + (size_t)(tm0 + 64 + srow) * lda + scol;
    const unsigned short* gB0 = W + (size_t)(tn0 + srow) * ldw + scol;
    const unsigned short* gB1 = W + (size_t)(tn0 + 64 + srow) * ldw + scol;

    const int aoff = ((wr << 6) + (l & 15)) * 32 + ((l >> 4) << 3);
    const int boff = ((wc << 6) + (l & 15)) * 32 + ((l >> 4) << 3);

    f4 acc[4][4];
#pragma unroll
    for (int i = 0; i < 4; ++i)
#pragma unroll
        for (int j = 0; j < 4; ++j) acc[i][j] = 0.f;

    for (int k0 = 0; k0 < K; k0 += 32) {
        GLL16(gA0 + k0, ldsA0);
        GLL16(gA1 + k0, ldsA1);
        GLL16(gB0 + k0, ldsB0);
        GLL16(gB1 + k0, ldsB1);
        __syncthreads();
        bh8 af[4], bf[4];
#pragma unroll
        for (int mi = 0; mi < 4; ++mi) af[mi] = *(const bh8*)&As[aoff + mi * 512];
#pragma unroll
        for (int ni = 0; ni < 4; ++ni) bf[ni] = *(const bh8*)&Bs[boff + ni * 512];
#pragma unroll
        for (int mi = 0; mi < 4; ++mi)
#pragma unroll
            for (int ni = 0; ni < 4; ++ni)
                acc[mi][ni] = __builtin_amdgcn_mfma_f32_16x16x32_bf16(
                    af[mi], bf[ni], acc[mi][ni], 0, 0, 0);
        __syncthreads();
    }

    const int crow0 = tm0 + (wr << 6) + ((l >> 4) << 2);
    const int ccol0 = tn0 + (wc << 6) + (l & 15);
#pragma unroll
    for (int mi = 0; mi < 4; ++mi)
#pragma unroll
        for (int ni = 0; ni < 4; ++ni)
#pragma unroll
            for (int r = 0; r < 4; ++r) {
                const int n = ccol0 + ni * 16;
                const size_t idx = (size_t)(crow0 + mi * 16 + r) * ldc + n;
                float v = acc[mi][ni][r];
                if (ACT == 1) {
                    v += bias[n];
                    if (v <= 20.f)
                        v = __builtin_amdgcn_logf(1.f + __builtin_amdgcn_exp2f(v * LOG2E)) * LN2;
                }
                if (TC_BF) {
                    ((unsigned short*)Cv)[idx] = f2bf(v);
                } else {
                    float* C = (float*)Cv;
                    C[idx] = ACC ? (C[idx] + v) : v;
                }
            }
}

// ---------------------------------------------------------------------------
// x_proj MFMA: M=NROWS, N=128 (80 valid), K=1536. Dual epilogue:
//   fp32 dtBC[m][n] for n<80  (scan B/C + dt-rank)
//   bf16 dtR [m][n] for n<64  (dt-rank(48) | B(16), input of dt GEMM)
// ---------------------------------------------------------------------------
__global__ __launch_bounds__(256) void gemm_mfma_xp(
    const unsigned short* __restrict__ A, int lda,
    const unsigned short* __restrict__ Wp,
    float* __restrict__ dtBC, unsigned short* __restrict__ dtR, int K)
{
    __shared__ unsigned short As[128 * 32];
    __shared__ unsigned short Bs[128 * 32];
    const int tid = threadIdx.x;
    const int w = tid >> 6;
    const int l = tid & 63;
    const int wr = w >> 1, wc = w & 1;
    const int tm0 = blockIdx.y * 128;

    const int srow = (w << 4) + (l >> 2);
    const int scol = (l & 3) * 8;
    unsigned short* ldsA0 = &As[(w << 4) * 32];
    unsigned short* ldsA1 = &As[(64 + (w << 4)) * 32];
    unsigned short* ldsB0 = &Bs[(w << 4) * 32];
    unsigned short* ldsB1 = &Bs[(64 + (w << 4)) * 32];
    const unsigned short* gA0 = A + (size_t)(tm0 + srow) * lda + scol;
    const unsigned short* gA1 = A + (size_t)(tm0 + 64 + srow) * lda + scol;
    const unsigned short* gB0 = Wp + (size_t)srow * lda + scol;
    const unsigned short* gB1 = Wp + (size_t)(64 + srow) * lda + scol;

    const int aoff = ((wr << 6) + (l & 15)) * 32 + ((l >> 4) << 3);
    const int boff = ((wc << 6) + (l & 15)) * 32 + ((l >> 4) << 3);

    f4 acc[4][4];
#pragma unroll
    for (int i = 0; i < 4; ++i)
#pragma unroll
        for (int j = 0; j < 4; ++j) acc[i][j] = 0.f;

    for (int k0 = 0; k0 < K; k0 += 32) {
        GLL16(gA0 + k0, ldsA0);
        GLL16(gA1 + k0, ldsA1);
        GLL16(gB0 + k0, ldsB0);
        GLL16(gB1 + k0, ldsB1);
        __syncthreads();
        bh8 af[4], bf[4];
#pragma unroll
        for (int mi = 0; mi < 4; ++mi) af[mi] = *(const bh8*)&As[aoff + mi * 512];
#pragma unroll
        for (int ni = 0; ni < 4; ++ni) bf[ni] = *(const bh8*)&Bs[boff + ni * 512];
#pragma unroll
        for (int mi = 0; mi < 4; ++mi)
#pragma unroll
            for (int ni = 0; ni < 4; ++ni)
                acc[mi][ni] = __builtin_amdgcn_mfma_f32_16x16x32_bf16(
                    af[mi], bf[ni], acc[mi][ni], 0, 0, 0);
        __syncthreads();
    }

    const int crow0 = tm0 + (wr << 6) + ((l >> 4) << 2);
    const int ccol0 = (wc << 6) + (l & 15);
#pragma unroll
    for (int mi = 0; mi < 4; ++mi)
#pragma unroll
        for (int ni = 0; ni < 4; ++ni) {
            const int n = ccol0 + ni * 16;
            if (n >= 80) continue;
#pragma unroll
            for (int r = 0; r < 4; ++r) {
                const int m = crow0 + mi * 16 + r;
                const float v = acc[mi][ni][r];
                dtBC[(size_t)m * NDBC + n] = v;
                if (n < 64) dtR[(size_t)m * 64 + n] = f2bf(v);
            }
        }
}

// ---------------------------------------------------------------------------
__global__ __launch_bounds__(256) void cast_f32_bf16(
    const float* __restrict__ in, unsigned short* __restrict__ out, int n4)
{
    const int i = blockIdx.x * 256 + threadIdx.x;
    if (i >= n4) return;
    const float4 v = ((const float4*)in)[i];
    ushort4 o;
    o.x = f2bf(v.x); o.y = f2bf(v.y); o.z = f2bf(v.z); o.w = f2bf(v.w);
    ((ushort4*)out)[i] = o;
}

// dt_w [1536][48] fp32 -> padded [1536][64] bf16 (cols 48..63 = 0)
__global__ __launch_bounds__(256) void cast_dtw(
    const float* __restrict__ in, unsigned short* __restrict__ out)
{
    const int i = blockIdx.x * 256 + threadIdx.x;
    if (i >= D_INNER * 64) return;
    const int d = i >> 6, k = i & 63;
    out[i] = (k < DT_RANK) ? f2bf(in[d * DT_RANK + k]) : (unsigned short)0;
}

// ---------------------------------------------------------------------------
// Causal depthwise conv1d + SiLU, 8 channels/thread (us8 vector loads).
// DIR=0 taps l-j; DIR=1 taps l+j; weight w[3-j] both ways.
// ---------------------------------------------------------------------------
template <int DIR>
__global__ __launch_bounds__(256) void conv_silu8(
    const unsigned short* __restrict__ xz, const float* __restrict__ conv_w,
    const float* __restrict__ conv_b, unsigned short* __restrict__ uc)
{
    const int idx = blockIdx.x * 256 + threadIdx.x;   // over NROWS * 192
    const int row = idx / 192;
    const int dp  = (idx - row * 192) * 8;
    const int l = row & (SEQ - 1);

    f4 cw[8];
#pragma unroll
    for (int i = 0; i < 8; ++i)
        cw[i] = *(const f4*)&conv_w[(dp + i) * 4];

    float acc[8];
    {
        const f4 b0 = *(const f4*)&conv_b[dp];
        const f4 b1 = *(const f4*)&conv_b[dp + 4];
#pragma unroll
        for (int i = 0; i < 4; ++i) { acc[i] = b0[i]; acc[4 + i] = b1[i]; }
    }

#pragma unroll
    for (int j = 0; j < 4; ++j) {
        const int ll = DIR ? (l + j) : (l - j);
        if (ll >= 0 && ll < SEQ) {
            const us8 v = *(const us8*)&xz[((long)row + (ll - l)) * NXZ + dp];
#pragma unroll
            for (int i = 0; i < 8; ++i)
                acc[i] = fmaf(bf2f(v[i]), cw[i][3 - j], acc[i]);
        }
    }
    us8 o;
#pragma unroll
    for (int i = 0; i < 8; ++i)
        o[i] = f2bf(acc[i] * fsigm(acc[i]));
    *(us8*)&uc[(size_t)row * D_INNER + dp] = o;
}

// ---------------------------------------------------------------------------
// Chunked selective scan, one THREAD per (channel, chunk): h[16] in registers.
// scan1_d: F = local final state (h0=0), Sdt = sum(dt).
// scan_comb: prefix fold Fb[c-1] <- H_start(c) via P = exp2(A2*Sdt).
// scan2_d: full scan from H_start, y*silu(z) overwrites dt in xz.
// ---------------------------------------------------------------------------
template <int DIR>
__global__ __launch_bounds__(256) void scan1_d(
    const float* __restrict__ dtBC, const unsigned short* __restrict__ uc,
    const float* __restrict__ A_log, const unsigned short* __restrict__ xz,
    float* __restrict__ Fb, float* __restrict__ Sd)
{
    __shared__ float bs[CL][20];
    const int tid = threadIdx.x;
    const int c    = blockIdx.x / (DBLKS * BATCH);
    const int rem  = blockIdx.x % (DBLKS * BATCH);
    const int b    = rem / DBLKS;
    const int dblk = rem % DBLKS;
    const int d = dblk * 256 + tid;
    const long l0 = DIR ? (SEQ - 1 - c * CL) : (c * CL);

    {
        const int rk = tid >> 1, half = tid & 1;
        const long l = DIR ? (l0 - rk) : (l0 + rk);
        const float* src = &dtBC[((size_t)b * SEQ + l) * NDBC + DT_RANK + half * 8];
        *(f4*)&bs[rk][half * 8]     = *(const f4*)src;
        *(f4*)&bs[rk][half * 8 + 4] = *(const f4*)(src + 4);
    }
    __syncthreads();

    float A2[16];
#pragma unroll
    for (int n = 0; n < 16; ++n)
        A2[n] = -expf(A_log[d * D_STATE + n]) * LOG2E;

    const unsigned short* pdt = xz + (size_t)b * SEQ * NXZ + d;
    const unsigned short* pu  = uc + (size_t)b * SEQ * D_INNER + d;

    float h[16];
#pragma unroll
    for (int n = 0; n < 16; ++n) h[n] = 0.f;
    float sdt = 0.f;

    float dt8a[8], u8a[8], dt8b[8], u8b[8];
    auto LOAD = [&](float* dt8, float* u8, int k0) {
#pragma unroll
        for (int j = 0; j < 8; ++j) {
            const long l = DIR ? (l0 - (k0 + j)) : (l0 + (k0 + j));
            dt8[j] = bf2f(pdt[l * NXZ]);
            u8[j]  = bf2f(pu[l * D_INNER]);
        }
    };
    auto COMP = [&](const float* dt8, const float* u8, int k0) {
#pragma unroll
        for (int j = 0; j < 8; ++j) {
            const float dt = dt8[j];
            const float dtu = dt * u8[j];
            sdt += dt;
            const int k = k0 + j;
#pragma unroll
            for (int q = 0; q < 4; ++q) {
                const f4 Bq = *(const f4*)&bs[k][q * 4];
#pragma unroll
                for (int e = 0; e < 4; ++e) {
                    const int n = q * 4 + e;
                    const float dA = __builtin_amdgcn_exp2f(dt * A2[n]);
                    h[n] = fmaf(dA, h[n], dtu * Bq[e]);
                }
            }
        }
    };
    LOAD(dt8a, u8a, 0);
    for (int k0 = 0; k0 < CL; k0 += 16) {
        LOAD(dt8b, u8b, k0 + 8);
        COMP(dt8a, u8a, k0);
        if (k0 + 16 < CL) LOAD(dt8a, u8a, k0 + 16);
        COMP(dt8b, u8b, k0 + 8);
    }

    const int ch = b * D_INNER + d;
    float* fdst = Fb + ((size_t)c * NCH + ch) * 16;
#pragma unroll
    for (int n = 0; n < 16; ++n) fdst[n] = h[n];
    Sd[(size_t)c * NCH + ch] = sdt;
}

__global__ __launch_bounds__(256) void scan_comb(
    float* __restrict__ Fb, const float* __restrict__ Sd,
    const float* __restrict__ A_log)
{
    const int i = blockIdx.x * 256 + threadIdx.x;   // ch*16+n
    const int ch = i >> 4, n = i & 15;
    const int d = ch % D_INNER;
    const float A2 = -expf(A_log[d * D_STATE + n]) * LOG2E;
    float h = Fb[i];
    for (int cc = 1; cc < NCHUNK - 1; ++cc) {
        const float P = __builtin_amdgcn_exp2f(A2 * Sd[(size_t)cc * NCH + ch]);
        h = fmaf(P, h, Fb[(size_t)cc * (NCH * 16) + i]);
        Fb[(size_t)cc * (NCH * 16) + i] = h;
    }
}

template <int DIR>
__global__ __launch_bounds__(256) void scan2_d(
    const float* __restrict__ dtBC, const unsigned short* __restrict__ uc,
    const float* __restrict__ A_log, const float* __restrict__ D_skip,
    unsigned short* __restrict__ xz, const float* __restrict__ Fb)
{
    __shared__ float bs[CL][36];
    const int tid = threadIdx.x;
    const int c    = blockIdx.x / (DBLKS * BATCH);
    const int rem  = blockIdx.x % (DBLKS * BATCH);
    const int b    = rem / DBLKS;
    const int dblk = rem % DBLKS;
    const int d = dblk * 256 + tid;
    const long l0 = DIR ? (SEQ - 1 - c * CL) : (c * CL);

    {
        const int rk = tid >> 1, half = tid & 1;
        const long l = DIR ? (l0 - rk) : (l0 + rk);
        const float* src = &dtBC[((size_t)b * SEQ + l) * NDBC + DT_RANK + half * 16];
        *(f4*)&bs[rk][half * 16]      = *(const f4*)src;
        *(f4*)&bs[rk][half * 16 + 4]  = *(const f4*)(src + 4);
        *(f4*)&bs[rk][half * 16 + 8]  = *(const f4*)(src + 8);
        *(f4*)&bs[rk][half * 16 + 12] = *(const f4*)(src + 12);
    }
    __syncthreads();

    float A2[16];
#pragma unroll
    for (int n = 0; n < 16; ++n)
        A2[n] = -expf(A_log[d * D_STATE + n]) * LOG2E;
    const float Dv = D_skip[d];

    const unsigned short* pdt = xz + (size_t)b * SEQ * NXZ + d;
    const unsigned short* pz  = pdt + D_INNER;
    const unsigned short* pu  = uc + (size_t)b * SEQ * D_INNER + d;
    unsigned short* pout = xz + (size_t)b * SEQ * NXZ + d;

    const int ch = b * D_INNER + d;
    float h[16];
    if (c == 0) {
#pragma unroll
        for (int n = 0; n < 16; ++n) h[n] = 0.f;
    } else {
        const float* hsrc = Fb + ((size_t)(c - 1) * NCH + ch) * 16;
#pragma unroll
        for (int n = 0; n < 16; ++n) h[n] = hsrc[n];
    }

    float dt8a[8], u8a[8], z8a[8], dt8b[8], u8b[8], z8b[8];
    auto LOAD = [&](float* dt8, float* u8, float* z8, int k0) {
#pragma unroll
        for (int j = 0; j < 8; ++j) {
            const long l = DIR ? (l0 - (k0 + j)) : (l0 + (k0 + j));
            dt8[j] = bf2f(pdt[l * NXZ]);
            u8[j]  = bf2f(pu[l * D_INNER]);
            z8[j]  = bf2f(pz[l * NXZ]);
        }
    };
    auto COMP = [&](const float* dt8, const float* u8, const float* z8, int k0) {
#pragma unroll
        for (int j = 0; j < 8; ++j) {
            const float dt = dt8[j];
            const float dtu = dt * u8[j];
            float ya[4];
            ya[0] = u8[j] * Dv; ya[1] = 0.f; ya[2] = 0.f; ya[3] = 0.f;
            const int k = k0 + j;
#pragma unroll
            for (int q = 0; q < 4; ++q) {
                const f4 Bq = *(const f4*)&bs[k][q * 4];
                const f4 Cq = *(const f4*)&bs[k][16 + q * 4];
#pragma unroll
                for (int e = 0; e < 4; ++e) {
                    const int n = q * 4 + e;
                    const float dA = __builtin_amdgcn_exp2f(dt * A2[n]);
                    h[n] = fmaf(dA, h[n], dtu * Bq[e]);
                    ya[e] = fmaf(h[n], Cq[e], ya[e]);
                }
            }
            const float y = (ya[0] + ya[1]) + (ya[2] + ya[3]);
            const float zv = z8[j];
            const long l = DIR ? (l0 - k) : (l0 + k);
            pout[l * NXZ] = f2bf(y * (zv * fsigm(zv)));
        }
    };
    LOAD(dt8a, u8a, z8a, 0);
    for (int k0 = 0; k0 < CL; k0 += 16) {
        LOAD(dt8b, u8b, z8b, k0 + 8);
        COMP(dt8a, u8a, z8a, k0);
        if (k0 + 16 < CL) LOAD(dt8a, u8a, z8a, k0 + 16);
        COMP(dt8b, u8b, z8b, k0 + 8);
    }
}

// ---------------------------------------------------------------------------
// In-place: out = LN(out + x) * g + b
// ---------------------------------------------------------------------------
__global__ __launch_bounds__(256) void fuse_ln(
    float* __restrict__ out, const float* __restrict__ x,
    const float* __restrict__ g, const float* __restrict__ bta)
{
    const int row = blockIdx.x;
    const size_t base = (size_t)row * D_MODEL;
    float vals[3];
    float s = 0.f, s2 = 0.f;
#pragma unroll
    for (int i = 0; i < 3; ++i) {
        const int c = threadIdx.x + i * 256;
        const float v = out[base + c] + x[base + c];
        vals[i] = v;
        s += v;
        s2 += v * v;
    }
#pragma unroll
    for (int o = 32; o >= 1; o >>= 1) {
        s  += __shfl_xor(s, o, 64);
        s2 += __shfl_xor(s2, o, 64);
    }
    __shared__ float ls[4], ls2[4];
    const int wid = threadIdx.x >> 6;
    if ((threadIdx.x & 63) == 0) { ls[wid] = s; ls2[wid] = s2; }
    __syncthreads();
    s  = ls[0] + ls[1] + ls[2] + ls[3];
    s2 = ls2[0] + ls2[1] + ls2[2] + ls2[3];
    const float mu  = s * (1.f / D_MODEL);
    const float var = s2 * (1.f / D_MODEL) - mu * mu;
    const float inv = 1.f / sqrtf(var + 1e-12f);
#pragma unroll
    for (int i = 0; i < 3; ++i) {
        const int c = threadIdx.x + i * 256;
        out[base + c] = (vals[i] - mu) * inv * g[c] + bta[c];
    }
}

// ---------------------------------------------------------------------------
extern "C" void kernel_launch(void* const* d_in, const int* in_sizes, int n_in,
                              void* d_out, int out_size, void* d_ws, size_t ws_size,
                              hipStream_t stream)
{
    const float* x = (const float*)d_in[0];
    const float* ln_g = (const float*)d_in[19];
    const float* ln_b = (const float*)d_in[20];

    // workspace (~207 MB, all row-major)
    float* dtBC = (float*)d_ws;                                        //  5.2 MB
    unsigned short* xz  = (unsigned short*)(dtBC + (size_t)NROWS * NDBC); // 100.7 MB
    unsigned short* uc  = xz + (size_t)NROWS * NXZ;                    // 50.3 MB
    unsigned short* xbf = uc + (size_t)NROWS * D_INNER;                // 25.2 MB
    unsigned short* wbf_in  = xbf + (size_t)NROWS * D_MODEL;           //  4.7 MB
    unsigned short* wbf_out = wbf_in + (size_t)NXZ * D_MODEL;          //  2.4 MB
    unsigned short* wbf_xp  = wbf_out + (size_t)D_MODEL * D_INNER;     //  0.4 MB [128][1536]
    unsigned short* dtw_pad = wbf_xp + (size_t)128 * D_INNER;          //  0.2 MB [1536][64]
    unsigned short* dtR     = dtw_pad + (size_t)D_INNER * 64;          //  2.1 MB [16384][64]
    float* Fb = (float*)(dtR + (size_t)NROWS * 64);                    // 11.8 MB
    float* Sd = Fb + (size_t)(NCHUNK - 1) * NCH * 16;                  //  0.74 MB
    const size_t needed = ((size_t)NROWS * NDBC) * 4
        + ((size_t)NROWS * NXZ + (size_t)NROWS * D_INNER + (size_t)NROWS * D_MODEL
           + (size_t)NXZ * D_MODEL + (size_t)D_MODEL * D_INNER
           + (size_t)128 * D_INNER + (size_t)D_INNER * 64 + (size_t)NROWS * 64) * 2
        + (size_t)(NCHUNK - 1) * NCH * 16 * 4
        + (size_t)(NCHUNK - 1) * NCH * 4;
    if (ws_size < needed) return;  // fail absmax cleanly instead of faulting

    float* outp = (float*)d_out;

    cast_f32_bf16<<<(NROWS * D_MODEL / 4 + 255) / 256, 256, 0, stream>>>(
        x, xbf, NROWS * D_MODEL / 4);

    for (int dir = 0; dir < 2; ++dir) {
        const float* in_w    = (const float*)d_in[1 + dir * 9 + 0];
        const float* conv_w  = (const float*)d_in[1 + dir * 9 + 1];
        const float* conv_b  = (const float*)d_in[1 + dir * 9 + 2];
        const float* xproj_w = (const float*)d_in[1 + dir * 9 + 3];
        const float* dt_w    = (const float*)d_in[1 + dir * 9 + 4];
        const float* dt_b    = (const float*)d_in[1 + dir * 9 + 5];
        const float* A_log   = (const float*)d_in[1 + dir * 9 + 6];
        const float* D_skip  = (const float*)d_in[1 + dir * 9 + 7];
        const float* out_w   = (const float*)d_in[1 + dir * 9 + 8];

        cast_f32_bf16<<<(NXZ * D_MODEL / 4 + 255) / 256, 256, 0, stream>>>(
            in_w, wbf_in, NXZ * D_MODEL / 4);
        cast_f32_bf16<<<(D_MODEL * D_INNER / 4 + 255) / 256, 256, 0, stream>>>(
            out_w, wbf_out, D_MODEL * D_INNER / 4);
        cast_f32_bf16<<<(NDBC * D_INNER / 4 + 255) / 256, 256, 0, stream>>>(
            xproj_w, wbf_xp, NDBC * D_INNER / 4);
        cast_dtw<<<(D_INNER * 64 + 255) / 256, 256, 0, stream>>>(dt_w, dtw_pad);

        // xz = x @ in_w^T  (16384 x 3072, K=768)  MFMA -> bf16
        gemm_mfma<1, 0, 0><<<dim3(NXZ / 128, NROWS / 128), 256, 0, stream>>>(
            xbf, D_MODEL, wbf_in, D_MODEL, nullptr, xz, NXZ, D_MODEL);

        // uc = silu(conv(u) + b), 8 channels/thread
        if (dir == 0)
            conv_silu8<0><<<NROWS * 192 / 256, 256, 0, stream>>>(
                xz, conv_w, conv_b, uc);
        else
            conv_silu8<1><<<NROWS * 192 / 256, 256, 0, stream>>>(
                xz, conv_w, conv_b, uc);

        // x_proj MFMA: dtBC fp32 [16384][80] + dtR bf16 [16384][64]
        gemm_mfma_xp<<<dim3(1, NROWS / 128), 256, 0, stream>>>(
            uc, D_INNER, wbf_xp, dtBC, dtR, D_INNER);

        // dt = softplus(dtR @ dtw_pad^T + dt_b)  (K=64) -> overlay xz u-half
        gemm_mfma<1, 0, 1><<<dim3(D_INNER / 128, NROWS / 128), 256, 0, stream>>>(
            dtR, 64, dtw_pad, 64, dt_b, xz, NXZ, 64);

        // chunked scan: pass1 -> combine -> pass2
        if (dir == 0) {
            scan1_d<0><<<(NCHUNK - 1) * DBLKS * BATCH, 256, 0, stream>>>(
                dtBC, uc, A_log, xz, Fb, Sd);
            scan_comb<<<NCH * 16 / 256, 256, 0, stream>>>(Fb, Sd, A_log);
            scan2_d<0><<<NCHUNK * DBLKS * BATCH, 256, 0, stream>>>(
                dtBC, uc, A_log, D_skip, xz, Fb);
        } else {
            scan1_d<1><<<(NCHUNK - 1) * DBLKS * BATCH, 256, 0, stream>>>(
                dtBC, uc, A_log, xz, Fb, Sd);
            scan_comb<<<NCH * 16 / 256, 256, 0, stream>>>(Fb, Sd, A_log);
            scan2_d<1><<<NCHUNK * DBLKS * BATCH, 256, 0, stream>>>(
                dtBC, uc, A_log, D_skip, xz, Fb);
        }

        // outp (+)= y' @ out_w^T   (16384 x 768, K=1536)  MFMA -> fp32
        if (dir == 0)
            gemm_mfma<0, 0, 0><<<dim3(D_MODEL / 128, NROWS / 128), 256, 0, stream>>>(
                xz, NXZ, wbf_out, D_INNER, nullptr, outp, D_MODEL, D_INNER);
        else
            gemm_mfma<0, 1, 0><<<dim3(D_MODEL / 128, NROWS / 128), 256, 0, stream>>>(
                xz, NXZ, wbf_out, D_INNER, nullptr, outp, D_MODEL, D_INNER);
    }

    fuse_ln<<<NROWS, 256, 0, stream>>>(outp, x, ln_g, ln_b);
}

// Round 11
// 951.716 us; speedup vs baseline: 5.7349x; 1.0375x over previous
//
#include <hip/hip_runtime.h>
#include <math.h>

#define D_MODEL 768
#define D_INNER 1536
#define D_STATE 16
#define DCONV 4
#define DT_RANK 48
#define BATCH 8
#define SEQ 2048
#define NROWS (BATCH * SEQ)          // 16384
#define NXZ (2 * D_INNER)            // 3072
#define NDBC (DT_RANK + 2 * D_STATE) // 80

#define NCHUNK 16
#define CL (SEQ / NCHUNK)            // 128 steps per chunk
#define NCH (BATCH * D_INNER)        // 12288 channels
#define DBLKS (D_INNER / 256)        // 6 blocks of 256 d-channels
#define KSEG (D_INNER / 4)           // 384: x_proj split-K segment
#define NP ((size_t)NROWS * NDBC)    // partial-plane stride

#define LOG2E 1.4426950408889634f
#define LN2   0.6931471805599453f

typedef __attribute__((ext_vector_type(8))) short bh8;   // MFMA A/B frag
typedef __attribute__((ext_vector_type(4))) float f4;
typedef __attribute__((ext_vector_type(8))) unsigned short us8;

__device__ __forceinline__ float bf2f(unsigned short u) {
    return __uint_as_float(((unsigned int)u) << 16);
}
__device__ __forceinline__ unsigned short f2bf(float f) {
    unsigned int x = __float_as_uint(f);
    return (unsigned short)((x + 0x7fffu + ((x >> 16) & 1u)) >> 16);
}
__device__ __forceinline__ float fsigm(float x) {
    return __builtin_amdgcn_rcpf(1.f + __builtin_amdgcn_exp2f(-x * LOG2E));
}

#define GLL16(gp, lp) __builtin_amdgcn_global_load_lds( \
    (const __attribute__((address_space(1))) void*)(gp), \
    (__attribute__((address_space(3))) void*)(lp), 16, 0, 0)

// XCD-aware bijective block swizzle (nwg % 8 == 0): launched block wid on
// XCD wid%8 executes work (wid%8)*nwg/8 + wid/8 -> contiguous work per XCD.
__device__ __forceinline__ void xcd_swizzle(int& bx, int& by) {
    const int nwg = gridDim.x * gridDim.y;
    const int wid = blockIdx.y * gridDim.x + blockIdx.x;
    const int work = (wid & 7) * (nwg >> 3) + (wid >> 3);
    bx = work % gridDim.x;
    by = work / gridDim.x;
}

// ---------------------------------------------------------------------------
// bf16 MFMA GEMM (NT): C = A(MxK) @ W(NxK)^T. 128x128 tile, BK=32, 4 waves.
// TC_BF: C bf16. ACC: fp32 C +=. ACT 1: softplus(v + bias[n]) before store.
// ---------------------------------------------------------------------------
template <int TC_BF, int ACC, int ACT>
__global__ __launch_bounds__(256) void gemm_mfma(
    const unsigned short* __restrict__ A, int lda,
    const unsigned short* __restrict__ W, int ldw,
    const float* __restrict__ bias,
    void* __restrict__ Cv, int ldc, int K)
{
    __shared__ unsigned short As[128 * 32];
    __shared__ unsigned short Bs[128 * 32];
    int bx, by;
    xcd_swizzle(bx, by);
    const int tid = threadIdx.x;
    const int w = tid >> 6;
    const int l = tid & 63;
    const int wr = w >> 1, wc = w & 1;
    const int tm0 = by * 128;
    const int tn0 = bx * 128;

    const int srow = (w << 4) + (l >> 2);
    const int scol = (l & 3) * 8;
    unsigned short* ldsA0 = &As[(w << 4) * 32];
    unsigned short* ldsA1 = &As[(64 + (w << 4)) * 32];
    unsigned short* ldsB0 = &Bs[(w << 4) * 32];
    unsigned short* ldsB1 = &Bs[(64 + (w << 4)) * 32];
    const unsigned short* gA0 = A + (size_t)(tm0 + srow) * lda + scol;
    const unsigned short* gA1 = A + (size_t)(tm0 + 64 + srow) * lda + scol;
    const unsigned short* gB0 = W + (size_t)(tn0 + srow) * ldw + scol;
    const unsigned short* gB1 = W + (size_t)(tn0 + 64 + srow) * ldw + scol;

    const int aoff = ((wr << 6) + (l & 15)) * 32 + ((l >> 4) << 3);
    const int boff = ((wc << 6) + (l & 15)) * 32 + ((l >> 4) << 3);

    f4 acc[4][4];
#pragma unroll
    for (int i = 0; i < 4; ++i)
#pragma unroll
        for (int j = 0; j < 4; ++j) acc[i][j] = 0.f;

    for (int k0 = 0; k0 < K; k0 += 32) {
        GLL16(gA0 + k0, ldsA0);
        GLL16(gA1 + k0, ldsA1);
        GLL16(gB0 + k0, ldsB0);
        GLL16(gB1 + k0, ldsB1);
        __syncthreads();
        bh8 af[4], bf[4];
#pragma unroll
        for (int mi = 0; mi < 4; ++mi) af[mi] = *(const bh8*)&As[aoff + mi * 512];
#pragma unroll
        for (int ni = 0; ni < 4; ++ni) bf[ni] = *(const bh8*)&Bs[boff + ni * 512];
#pragma unroll
        for (int mi = 0; mi < 4; ++mi)
#pragma unroll
            for (int ni = 0; ni < 4; ++ni)
                acc[mi][ni] = __builtin_amdgcn_mfma_f32_16x16x32_bf16(
                    af[mi], bf[ni], acc[mi][ni], 0, 0, 0);
        __syncthreads();
    }

    const int crow0 = tm0 + (wr << 6) + ((l >> 4) << 2);
    const int ccol0 = tn0 + (wc << 6) + (l & 15);
#pragma unroll
    for (int mi = 0; mi < 4; ++mi)
#pragma unroll
        for (int ni = 0; ni < 4; ++ni)
#pragma unroll
            for (int r = 0; r < 4; ++r) {
                const int n = ccol0 + ni * 16;
                const size_t idx = (size_t)(crow0 + mi * 16 + r) * ldc + n;
                float v = acc[mi][ni][r];
                if (ACT == 1) {
                    v += bias[n];
                    if (v <= 20.f)
                        v = __builtin_amdgcn_logf(1.f + __builtin_amdgcn_exp2f(v * LOG2E)) * LN2;
                }
                if (TC_BF) {
                    ((unsigned short*)Cv)[idx] = f2bf(v);
                } else {
                    float* C = (float*)Cv;
                    C[idx] = ACC ? (C[idx] + v) : v;
                }
            }
}

// ---------------------------------------------------------------------------
// x_proj MFMA, split-K x4: grid (4, NROWS/128). Block (kseg, row-tile)
// computes partial over k in [kseg*KSEG, (kseg+1)*KSEG) and stores fp32
// partials Pp[kseg][m][n] (n<80). xp_reduce sums them.
// ---------------------------------------------------------------------------
__global__ __launch_bounds__(256) void gemm_mfma_xp(
    const unsigned short* __restrict__ A, int lda,
    const unsigned short* __restrict__ Wp,
    float* __restrict__ Pp)
{
    __shared__ unsigned short As[128 * 32];
    __shared__ unsigned short Bs[128 * 32];
    int bx, by;
    xcd_swizzle(bx, by);
    const int tid = threadIdx.x;
    const int w = tid >> 6;
    const int l = tid & 63;
    const int wr = w >> 1, wc = w & 1;
    const int tm0 = by * 128;
    const int kbeg = bx * KSEG;

    const int srow = (w << 4) + (l >> 2);
    const int scol = (l & 3) * 8;
    unsigned short* ldsA0 = &As[(w << 4) * 32];
    unsigned short* ldsA1 = &As[(64 + (w << 4)) * 32];
    unsigned short* ldsB0 = &Bs[(w << 4) * 32];
    unsigned short* ldsB1 = &Bs[(64 + (w << 4)) * 32];
    const unsigned short* gA0 = A + (size_t)(tm0 + srow) * lda + scol;
    const unsigned short* gA1 = A + (size_t)(tm0 + 64 + srow) * lda + scol;
    const unsigned short* gB0 = Wp + (size_t)srow * lda + scol;
    const unsigned short* gB1 = Wp + (size_t)(64 + srow) * lda + scol;

    const int aoff = ((wr << 6) + (l & 15)) * 32 + ((l >> 4) << 3);
    const int boff = ((wc << 6) + (l & 15)) * 32 + ((l >> 4) << 3);

    f4 acc[4][4];
#pragma unroll
    for (int i = 0; i < 4; ++i)
#pragma unroll
        for (int j = 0; j < 4; ++j) acc[i][j] = 0.f;

    for (int k0 = kbeg; k0 < kbeg + KSEG; k0 += 32) {
        GLL16(gA0 + k0, ldsA0);
        GLL16(gA1 + k0, ldsA1);
        GLL16(gB0 + k0, ldsB0);
        GLL16(gB1 + k0, ldsB1);
        __syncthreads();
        bh8 af[4], bf[4];
#pragma unroll
        for (int mi = 0; mi < 4; ++mi) af[mi] = *(const bh8*)&As[aoff + mi * 512];
#pragma unroll
        for (int ni = 0; ni < 4; ++ni) bf[ni] = *(const bh8*)&Bs[boff + ni * 512];
#pragma unroll
        for (int mi = 0; mi < 4; ++mi)
#pragma unroll
            for (int ni = 0; ni < 4; ++ni)
                acc[mi][ni] = __builtin_amdgcn_mfma_f32_16x16x32_bf16(
                    af[mi], bf[ni], acc[mi][ni], 0, 0, 0);
        __syncthreads();
    }

    const int crow0 = tm0 + (wr << 6) + ((l >> 4) << 2);
    const int ccol0 = (wc << 6) + (l & 15);
    float* pdst = Pp + (size_t)bx * NP;
#pragma unroll
    for (int mi = 0; mi < 4; ++mi)
#pragma unroll
        for (int ni = 0; ni < 4; ++ni) {
            const int n = ccol0 + ni * 16;
            if (n >= 80) continue;
#pragma unroll
            for (int r = 0; r < 4; ++r) {
                const int m = crow0 + mi * 16 + r;
                pdst[(size_t)m * NDBC + n] = acc[mi][ni][r];
            }
        }
}

// sum 4 split-K partials -> dtBC fp32; cols<64 also -> dtR bf16
__global__ __launch_bounds__(256) void xp_reduce(
    const float* __restrict__ Pp, float* __restrict__ dtBC,
    unsigned short* __restrict__ dtR)
{
    const size_t i = (size_t)blockIdx.x * 256 + threadIdx.x;  // < NROWS*80
    const float s = (Pp[i] + Pp[i + NP]) + (Pp[i + 2 * NP] + Pp[i + 3 * NP]);
    dtBC[i] = s;
    const int n = (int)(i % NDBC);
    if (n < 64) {
        const size_t m = i / NDBC;
        dtR[m * 64 + n] = f2bf(s);
    }
}

// ---------------------------------------------------------------------------
__global__ __launch_bounds__(256) void cast_f32_bf16(
    const float* __restrict__ in, unsigned short* __restrict__ out, int n4)
{
    const int i = blockIdx.x * 256 + threadIdx.x;
    if (i >= n4) return;
    const float4 v = ((const float4*)in)[i];
    ushort4 o;
    o.x = f2bf(v.x); o.y = f2bf(v.y); o.z = f2bf(v.z); o.w = f2bf(v.w);
    ((ushort4*)out)[i] = o;
}

// dt_w [1536][48] fp32 -> padded [1536][64] bf16 (cols 48..63 = 0)
__global__ __launch_bounds__(256) void cast_dtw(
    const float* __restrict__ in, unsigned short* __restrict__ out)
{
    const int i = blockIdx.x * 256 + threadIdx.x;
    if (i >= D_INNER * 64) return;
    const int d = i >> 6, k = i & 63;
    out[i] = (k < DT_RANK) ? f2bf(in[d * DT_RANK + k]) : (unsigned short)0;
}

// ---------------------------------------------------------------------------
// Causal depthwise conv1d + SiLU, 8 channels/thread (us8 vector loads).
// ---------------------------------------------------------------------------
template <int DIR>
__global__ __launch_bounds__(256) void conv_silu8(
    const unsigned short* __restrict__ xz, const float* __restrict__ conv_w,
    const float* __restrict__ conv_b, unsigned short* __restrict__ uc)
{
    const int idx = blockIdx.x * 256 + threadIdx.x;   // over NROWS * 192
    const int row = idx / 192;
    const int dp  = (idx - row * 192) * 8;
    const int l = row & (SEQ - 1);

    f4 cw[8];
#pragma unroll
    for (int i = 0; i < 8; ++i)
        cw[i] = *(const f4*)&conv_w[(dp + i) * 4];

    float acc[8];
    {
        const f4 b0 = *(const f4*)&conv_b[dp];
        const f4 b1 = *(const f4*)&conv_b[dp + 4];
#pragma unroll
        for (int i = 0; i < 4; ++i) { acc[i] = b0[i]; acc[4 + i] = b1[i]; }
    }

#pragma unroll
    for (int j = 0; j < 4; ++j) {
        const int ll = DIR ? (l + j) : (l - j);
        if (ll >= 0 && ll < SEQ) {
            const us8 v = *(const us8*)&xz[((long)row + (ll - l)) * NXZ + dp];
#pragma unroll
            for (int i = 0; i < 8; ++i)
                acc[i] = fmaf(bf2f(v[i]), cw[i][3 - j], acc[i]);
        }
    }
    us8 o;
#pragma unroll
    for (int i = 0; i < 8; ++i)
        o[i] = f2bf(acc[i] * fsigm(acc[i]));
    *(us8*)&uc[(size_t)row * D_INNER + dp] = o;
}

// ---------------------------------------------------------------------------
// Chunked selective scan, one THREAD per (channel, chunk): h[16] in registers.
// ---------------------------------------------------------------------------
template <int DIR>
__global__ __launch_bounds__(256) void scan1_d(
    const float* __restrict__ dtBC, const unsigned short* __restrict__ uc,
    const float* __restrict__ A_log, const unsigned short* __restrict__ xz,
    float* __restrict__ Fb, float* __restrict__ Sd)
{
    __shared__ float bs[CL][20];
    const int tid = threadIdx.x;
    const int c    = blockIdx.x / (DBLKS * BATCH);
    const int rem  = blockIdx.x % (DBLKS * BATCH);
    const int b    = rem / DBLKS;
    const int dblk = rem % DBLKS;
    const int d = dblk * 256 + tid;
    const long l0 = DIR ? (SEQ - 1 - c * CL) : (c * CL);

    {
        const int rk = tid >> 1, half = tid & 1;
        const long l = DIR ? (l0 - rk) : (l0 + rk);
        const float* src = &dtBC[((size_t)b * SEQ + l) * NDBC + DT_RANK + half * 8];
        *(f4*)&bs[rk][half * 8]     = *(const f4*)src;
        *(f4*)&bs[rk][half * 8 + 4] = *(const f4*)(src + 4);
    }
    __syncthreads();

    float A2[16];
#pragma unroll
    for (int n = 0; n < 16; ++n)
        A2[n] = -expf(A_log[d * D_STATE + n]) * LOG2E;

    const unsigned short* pdt = xz + (size_t)b * SEQ * NXZ + d;
    const unsigned short* pu  = uc + (size_t)b * SEQ * D_INNER + d;

    float h[16];
#pragma unroll
    for (int n = 0; n < 16; ++n) h[n] = 0.f;
    float sdt = 0.f;

    float dt8a[8], u8a[8], dt8b[8], u8b[8];
    auto LOAD = [&](float* dt8, float* u8, int k0) {
#pragma unroll
        for (int j = 0; j < 8; ++j) {
            const long l = DIR ? (l0 - (k0 + j)) : (l0 + (k0 + j));
            dt8[j] = bf2f(pdt[l * NXZ]);
            u8[j]  = bf2f(pu[l * D_INNER]);
        }
    };
    auto COMP = [&](const float* dt8, const float* u8, int k0) {
#pragma unroll
        for (int j = 0; j < 8; ++j) {
            const float dt = dt8[j];
            const float dtu = dt * u8[j];
            sdt += dt;
            const int k = k0 + j;
#pragma unroll
            for (int q = 0; q < 4; ++q) {
                const f4 Bq = *(const f4*)&bs[k][q * 4];
#pragma unroll
                for (int e = 0; e < 4; ++e) {
                    const int n = q * 4 + e;
                    const float dA = __builtin_amdgcn_exp2f(dt * A2[n]);
                    h[n] = fmaf(dA, h[n], dtu * Bq[e]);
                }
            }
        }
    };
    LOAD(dt8a, u8a, 0);
    for (int k0 = 0; k0 < CL; k0 += 16) {
        LOAD(dt8b, u8b, k0 + 8);
        COMP(dt8a, u8a, k0);
        if (k0 + 16 < CL) LOAD(dt8a, u8a, k0 + 16);
        COMP(dt8b, u8b, k0 + 8);
    }

    const int ch = b * D_INNER + d;
    float* fdst = Fb + ((size_t)c * NCH + ch) * 16;
#pragma unroll
    for (int n = 0; n < 16; ++n) fdst[n] = h[n];
    Sd[(size_t)c * NCH + ch] = sdt;
}

__global__ __launch_bounds__(256) void scan_comb(
    float* __restrict__ Fb, const float* __restrict__ Sd,
    const float* __restrict__ A_log)
{
    const int i = blockIdx.x * 256 + threadIdx.x;   // ch*16+n
    const int ch = i >> 4, n = i & 15;
    const int d = ch % D_INNER;
    const float A2 = -expf(A_log[d * D_STATE + n]) * LOG2E;
    float h = Fb[i];
    for (int cc = 1; cc < NCHUNK - 1; ++cc) {
        const float P = __builtin_amdgcn_exp2f(A2 * Sd[(size_t)cc * NCH + ch]);
        h = fmaf(P, h, Fb[(size_t)cc * (NCH * 16) + i]);
        Fb[(size_t)cc * (NCH * 16) + i] = h;
    }
}

template <int DIR>
__global__ __launch_bounds__(256) void scan2_d(
    const float* __restrict__ dtBC, const unsigned short* __restrict__ uc,
    const float* __restrict__ A_log, const float* __restrict__ D_skip,
    unsigned short* __restrict__ xz, const float* __restrict__ Fb)
{
    __shared__ float bs[CL][36];
    const int tid = threadIdx.x;
    const int c    = blockIdx.x / (DBLKS * BATCH);
    const int rem  = blockIdx.x % (DBLKS * BATCH);
    const int b    = rem / DBLKS;
    const int dblk = rem % DBLKS;
    const int d = dblk * 256 + tid;
    const long l0 = DIR ? (SEQ - 1 - c * CL) : (c * CL);

    {
        const int rk = tid >> 1, half = tid & 1;
        const long l = DIR ? (l0 - rk) : (l0 + rk);
        const float* src = &dtBC[((size_t)b * SEQ + l) * NDBC + DT_RANK + half * 16];
        *(f4*)&bs[rk][half * 16]      = *(const f4*)src;
        *(f4*)&bs[rk][half * 16 + 4]  = *(const f4*)(src + 4);
        *(f4*)&bs[rk][half * 16 + 8]  = *(const f4*)(src + 8);
        *(f4*)&bs[rk][half * 16 + 12] = *(const f4*)(src + 12);
    }
    __syncthreads();

    float A2[16];
#pragma unroll
    for (int n = 0; n < 16; ++n)
        A2[n] = -expf(A_log[d * D_STATE + n]) * LOG2E;
    const float Dv = D_skip[d];

    const unsigned short* pdt = xz + (size_t)b * SEQ * NXZ + d;
    const unsigned short* pz  = pdt + D_INNER;
    const unsigned short* pu  = uc + (size_t)b * SEQ * D_INNER + d;
    unsigned short* pout = xz + (size_t)b * SEQ * NXZ + d;

    const int ch = b * D_INNER + d;
    float h[16];
    if (c == 0) {
#pragma unroll
        for (int n = 0; n < 16; ++n) h[n] = 0.f;
    } else {
        const float* hsrc = Fb + ((size_t)(c - 1) * NCH + ch) * 16;
#pragma unroll
        for (int n = 0; n < 16; ++n) h[n] = hsrc[n];
    }

    float dt8a[8], u8a[8], z8a[8], dt8b[8], u8b[8], z8b[8];
    auto LOAD = [&](float* dt8, float* u8, float* z8, int k0) {
#pragma unroll
        for (int j = 0; j < 8; ++j) {
            const long l = DIR ? (l0 - (k0 + j)) : (l0 + (k0 + j));
            dt8[j] = bf2f(pdt[l * NXZ]);
            u8[j]  = bf2f(pu[l * D_INNER]);
            z8[j]  = bf2f(pz[l * NXZ]);
        }
    };
    auto COMP = [&](const float* dt8, const float* u8, const float* z8, int k0) {
#pragma unroll
        for (int j = 0; j < 8; ++j) {
            const float dt = dt8[j];
            const float dtu = dt * u8[j];
            float ya[4];
            ya[0] = u8[j] * Dv; ya[1] = 0.f; ya[2] = 0.f; ya[3] = 0.f;
            const int k = k0 + j;
#pragma unroll
            for (int q = 0; q < 4; ++q) {
                const f4 Bq = *(const f4*)&bs[k][q * 4];
                const f4 Cq = *(const f4*)&bs[k][16 + q * 4];
#pragma unroll
                for (int e = 0; e < 4; ++e) {
                    const int n = q * 4 + e;
                    const float dA = __builtin_amdgcn_exp2f(dt * A2[n]);
                    h[n] = fmaf(dA, h[n], dtu * Bq[e]);
                    ya[e] = fmaf(h[n], Cq[e], ya[e]);
                }
            }
            const float y = (ya[0] + ya[1]) + (ya[2] + ya[3]);
            const float zv = z8[j];
            const long l = DIR ? (l0 - k) : (l0 + k);
            pout[l * NXZ] = f2bf(y * (zv * fsigm(zv)));
        }
    };
    LOAD(dt8a, u8a, z8a, 0);
    for (int k0 = 0; k0 < CL; k0 += 16) {
        LOAD(dt8b, u8b, z8b, k0 + 8);
        COMP(dt8a, u8a, z8a, k0);
        if (k0 + 16 < CL) LOAD(dt8a, u8a, z8a, k0 + 16);
        COMP(dt8b, u8b, z8b, k0 + 8);
    }
}

// ---------------------------------------------------------------------------
// In-place: out = LN(out + x) * g + b
// ---------------------------------------------------------------------------
__global__ __launch_bounds__(256) void fuse_ln(
    float* __restrict__ out, const float* __restrict__ x,
    const float* __restrict__ g, const float* __restrict__ bta)
{
    const int row = blockIdx.x;
    const size_t base = (size_t)row * D_MODEL;
    float vals[3];
    float s = 0.f, s2 = 0.f;
#pragma unroll
    for (int i = 0; i < 3; ++i) {
        const int c = threadIdx.x + i * 256;
        const float v = out[base + c] + x[base + c];
        vals[i] = v;
        s += v;
        s2 += v * v;
    }
#pragma unroll
    for (int o = 32; o >= 1; o >>= 1) {
        s  += __shfl_xor(s, o, 64);
        s2 += __shfl_xor(s2, o, 64);
    }
    __shared__ float ls[4], ls2[4];
    const int wid = threadIdx.x >> 6;
    if ((threadIdx.x & 63) == 0) { ls[wid] = s; ls2[wid] = s2; }
    __syncthreads();
    s  = ls[0] + ls[1] + ls[2] + ls[3];
    s2 = ls2[0] + ls2[1] + ls2[2] + ls2[3];
    const float mu  = s * (1.f / D_MODEL);
    const float var = s2 * (1.f / D_MODEL) - mu * mu;
    const float inv = 1.f / sqrtf(var + 1e-12f);
#pragma unroll
    for (int i = 0; i < 3; ++i) {
        const int c = threadIdx.x + i * 256;
        out[base + c] = (vals[i] - mu) * inv * g[c] + bta[c];
    }
}

// ---------------------------------------------------------------------------
extern "C" void kernel_launch(void* const* d_in, const int* in_sizes, int n_in,
                              void* d_out, int out_size, void* d_ws, size_t ws_size,
                              hipStream_t stream)
{
    const float* x = (const float*)d_in[0];
    const float* ln_g = (const float*)d_in[19];
    const float* ln_b = (const float*)d_in[20];

    // workspace (~228 MB, all row-major)
    float* dtBC = (float*)d_ws;                                        //  5.2 MB
    unsigned short* xz  = (unsigned short*)(dtBC + (size_t)NROWS * NDBC); // 100.7 MB
    unsigned short* uc  = xz + (size_t)NROWS * NXZ;                    // 50.3 MB
    unsigned short* xbf = uc + (size_t)NROWS * D_INNER;                // 25.2 MB
    unsigned short* wbf_in  = xbf + (size_t)NROWS * D_MODEL;           //  4.7 MB
    unsigned short* wbf_out = wbf_in + (size_t)NXZ * D_MODEL;          //  2.4 MB
    unsigned short* wbf_xp  = wbf_out + (size_t)D_MODEL * D_INNER;     //  0.4 MB [128][1536]
    unsigned short* dtw_pad = wbf_xp + (size_t)128 * D_INNER;          //  0.2 MB [1536][64]
    unsigned short* dtR     = dtw_pad + (size_t)D_INNER * 64;          //  2.1 MB [16384][64]
    float* Fb = (float*)(dtR + (size_t)NROWS * 64);                    // 11.8 MB
    float* Sd = Fb + (size_t)(NCHUNK - 1) * NCH * 16;                  //  0.74 MB
    float* Pp = Sd + (size_t)(NCHUNK - 1) * NCH;                       // 21.0 MB [4][NROWS][80]
    const size_t needed = ((size_t)NROWS * NDBC) * 4
        + ((size_t)NROWS * NXZ + (size_t)NROWS * D_INNER + (size_t)NROWS * D_MODEL
           + (size_t)NXZ * D_MODEL + (size_t)D_MODEL * D_INNER
           + (size_t)128 * D_INNER + (size_t)D_INNER * 64 + (size_t)NROWS * 64) * 2
        + (size_t)(NCHUNK - 1) * NCH * 16 * 4
        + (size_t)(NCHUNK - 1) * NCH * 4
        + 4 * NP * 4;
    if (ws_size < needed) return;  // fail absmax cleanly instead of faulting

    float* outp = (float*)d_out;

    cast_f32_bf16<<<(NROWS * D_MODEL / 4 + 255) / 256, 256, 0, stream>>>(
        x, xbf, NROWS * D_MODEL / 4);

    for (int dir = 0; dir < 2; ++dir) {
        const float* in_w    = (const float*)d_in[1 + dir * 9 + 0];
        const float* conv_w  = (const float*)d_in[1 + dir * 9 + 1];
        const float* conv_b  = (const float*)d_in[1 + dir * 9 + 2];
        const float* xproj_w = (const float*)d_in[1 + dir * 9 + 3];
        const float* dt_w    = (const float*)d_in[1 + dir * 9 + 4];
        const float* dt_b    = (const float*)d_in[1 + dir * 9 + 5];
        const float* A_log   = (const float*)d_in[1 + dir * 9 + 6];
        const float* D_skip  = (const float*)d_in[1 + dir * 9 + 7];
        const float* out_w   = (const float*)d_in[1 + dir * 9 + 8];

        cast_f32_bf16<<<(NXZ * D_MODEL / 4 + 255) / 256, 256, 0, stream>>>(
            in_w, wbf_in, NXZ * D_MODEL / 4);
        cast_f32_bf16<<<(D_MODEL * D_INNER / 4 + 255) / 256, 256, 0, stream>>>(
            out_w, wbf_out, D_MODEL * D_INNER / 4);
        cast_f32_bf16<<<(NDBC * D_INNER / 4 + 255) / 256, 256, 0, stream>>>(
            xproj_w, wbf_xp, NDBC * D_INNER / 4);
        cast_dtw<<<(D_INNER * 64 + 255) / 256, 256, 0, stream>>>(dt_w, dtw_pad);

        // xz = x @ in_w^T  (16384 x 3072, K=768)  MFMA -> bf16
        gemm_mfma<1, 0, 0><<<dim3(NXZ / 128, NROWS / 128), 256, 0, stream>>>(
            xbf, D_MODEL, wbf_in, D_MODEL, nullptr, xz, NXZ, D_MODEL);

        // uc = silu(conv(u) + b), 8 channels/thread
        if (dir == 0)
            conv_silu8<0><<<NROWS * 192 / 256, 256, 0, stream>>>(
                xz, conv_w, conv_b, uc);
        else
            conv_silu8<1><<<NROWS * 192 / 256, 256, 0, stream>>>(
                xz, conv_w, conv_b, uc);

        // x_proj split-K x4 -> partials -> reduce (dtBC fp32 + dtR bf16)
        gemm_mfma_xp<<<dim3(4, NROWS / 128), 256, 0, stream>>>(
            uc, D_INNER, wbf_xp, Pp);
        xp_reduce<<<(int)(NP / 256), 256, 0, stream>>>(Pp, dtBC, dtR);

        // dt = softplus(dtR @ dtw_pad^T + dt_b)  (K=64) -> overlay xz u-half
        gemm_mfma<1, 0, 1><<<dim3(D_INNER / 128, NROWS / 128), 256, 0, stream>>>(
            dtR, 64, dtw_pad, 64, dt_b, xz, NXZ, 64);

        // chunked scan: pass1 -> combine -> pass2
        if (dir == 0) {
            scan1_d<0><<<(NCHUNK - 1) * DBLKS * BATCH, 256, 0, stream>>>(
                dtBC, uc, A_log, xz, Fb, Sd);
            scan_comb<<<NCH * 16 / 256, 256, 0, stream>>>(Fb, Sd, A_log);
            scan2_d<0><<<NCHUNK * DBLKS * BATCH, 256, 0, stream>>>(
                dtBC, uc, A_log, D_skip, xz, Fb);
        } else {
            scan1_d<1><<<(NCHUNK - 1) * DBLKS * BATCH, 256, 0, stream>>>(
                dtBC, uc, A_log, xz, Fb, Sd);
            scan_comb<<<NCH * 16 / 256, 256, 0, stream>>>(Fb, Sd, A_log);
            scan2_d<1><<<NCHUNK * DBLKS * BATCH, 256, 0, stream>>>(
                dtBC, uc, A_log, D_skip, xz, Fb);
        }

        // outp (+)= y' @ out_w^T   (16384 x 768, K=1536)  MFMA -> fp32
        if (dir == 0)
            gemm_mfma<0, 0, 0><<<dim3(D_MODEL / 128, NROWS / 128), 256, 0, stream>>>(
                xz, NXZ, wbf_out, D_INNER, nullptr, outp, D_MODEL, D_INNER);
        else
            gemm_mfma<0, 1, 0><<<dim3(D_MODEL / 128, NROWS / 128), 256, 0, stream>>>(
                xz, NXZ, wbf_out, D_INNER, nullptr, outp, D_MODEL, D_INNER);
    }

    fuse_ln<<<NROWS, 256, 0, stream>>>(outp, x, ln_g, ln_b);
}